// Round 15
// baseline (613.934 us; speedup 1.0000x reference)
//
#include <hip/hip_runtime.h>
#include <hip/hip_bf16.h>
#include <math.h>
#include <stdint.h>

#define EPS 1e-5f
#define LEAK 0.01f
#define NEG_INF (-3.402823e38f)

typedef __attribute__((ext_vector_type(8))) short short8v;
typedef __attribute__((ext_vector_type(4))) float f32x4;

__device__ __forceinline__ float sigm(float x){ return 1.0f/(1.0f + __expf(-x)); }
__device__ __forceinline__ float tanhf_(float x){ return 1.0f - 2.0f/(__expf(2.0f*x)+1.0f); }
__device__ __forceinline__ float bnl(float a, float sc, float sh){
    float v = fmaf(a, sc, sh);
    return v < 0.0f ? LEAK*v : v;
}
__device__ __forceinline__ unsigned short f2bf(float f){
    __hip_bfloat16 h = __float2bfloat16(f);
    return *reinterpret_cast<unsigned short*>(&h);
}
__device__ __forceinline__ float bf2f(unsigned short u){
    return __uint_as_float(((unsigned)u) << 16);
}

// ---------- conv weight pack: w[3][3][CIN][COUT] f32 -> wp[(9*CIN)/8][COUT][8] bf16 ----------
__global__ __launch_bounds__(256) void pack_k(const float* __restrict__ w,
                                              unsigned short* __restrict__ wp,
                                              int CIN, int COUT){
    int t = blockIdx.x*256 + threadIdx.x;
    int total = 9*CIN*COUT;
    if (t >= total) return;
    int cout = t % COUT, k = t / COUT;
    float v = w[(size_t)k*COUT + cout];
    wp[(size_t)(k>>3)*COUT*8 + (size_t)cout*8 + (k&7)] = f2bf(v);
}

// ---------- LSTM weight pack: src[K][512] f32 -> dst[(K/8)][512][8] bf16 ----------
__global__ __launch_bounds__(256) void packW_k(const float* __restrict__ src,
                                               unsigned short* __restrict__ dst, int K){
    int t = blockIdx.x*256 + threadIdx.x;
    if (t < K*512){
        int k = t >> 9, col = t & 511;
        dst[(size_t)(k>>3)*4096 + col*8 + (k&7)] = f2bf(src[(size_t)k*512 + col]);
    }
}

// ---------- Wout pack: Wout[128][37] f32 -> WoT[37][128] bf16 ----------
__global__ __launch_bounds__(256) void packWoT_k(const float* __restrict__ src,
                                                 unsigned short* __restrict__ dst){
    int t = blockIdx.x*256 + threadIdx.x;
    if (t < 37*128){
        int n = t >> 7, k = t & 127;
        dst[t] = f2bf(src[k*37 + n]);
    }
}

// ---------- BN fold ----------
__global__ void bn_k(const float* __restrict__ cb, const float* __restrict__ g,
                     const float* __restrict__ bb, const float* __restrict__ mm,
                     const float* __restrict__ mv, float* __restrict__ sc,
                     float* __restrict__ sh, int n){
    int t = threadIdx.x;
    if (t < n){
        float s = g[t]*rsqrtf(mv[t]+EPS);
        sc[t] = s;
        sh[t] = fmaf(cb[t]-mm[t], s, bb[t]);
    }
}

// ---------- conv block 0: thread = one pooled px, all 64 couts; weights in LDS ----------
__global__ __launch_bounds__(256) void conv0_k(
    const float* __restrict__ x, const float* __restrict__ w,
    const float* __restrict__ bsc, const float* __restrict__ bsh,
    unsigned short* __restrict__ out, int bbase, int total)
{
    __shared__ float wv[576];
    __shared__ float scs[64], shs[64];
    const int tid = threadIdx.x;
    for (int i=tid;i<576;i+=256) wv[i] = w[i];
    if (tid < 64){ scs[tid]=bsc[tid]; shs[tid]=bsh[tid]; }
    __syncthreads();
    const int id = blockIdx.x*256 + tid;
    if (id >= total) return;
    const int px = id % 90; int r = id / 90; const int py = r % 30; const int b0 = r / 30;
    const float* xb = x + (size_t)(bbase+b0)*10800;
    float p[4][4];
    const int y0 = 2*py-1, xx0 = 2*px-1;
#pragma unroll
    for (int rr=0;rr<4;rr++){
        int yy=y0+rr;
#pragma unroll
        for (int cc=0;cc<4;cc++){
            int xc=xx0+cc;
            p[rr][cc] = (yy>=0&&yy<60&&xc>=0&&xc<180)? xb[yy*180+xc] : 0.f;
        }
    }
    unsigned short* ob = out + (size_t)id*64;
#pragma unroll
    for (int cg=0;cg<8;cg++){
        short8v o8;
#pragma unroll
        for (int j=0;j<8;j++){
            const int co = cg*8+j;
            float s00=0.f,s01=0.f,s10=0.f,s11=0.f;
#pragma unroll
            for (int ky=0;ky<3;ky++)
#pragma unroll
            for (int kx=0;kx<3;kx++){
                float wt = wv[(ky*3+kx)*64+co];
                s00 = fmaf(p[ky][kx],     wt, s00);
                s01 = fmaf(p[ky][kx+1],   wt, s01);
                s10 = fmaf(p[ky+1][kx],   wt, s10);
                s11 = fmaf(p[ky+1][kx+1], wt, s11);
            }
            float sc=scs[co], sh=shs[co];
            float m = fmaxf(fmaxf(bnl(s00,sc,sh),bnl(s01,sc,sh)),
                            fmaxf(bnl(s10,sc,sh),bnl(s11,sc,sh)));
            o8[j] = (short)f2bf(m);
        }
        *(short8v*)&ob[cg*8] = o8;
    }
}

// ---------- MFMA fused conv+BN+leaky+pool: cout-split waves, low LDS redundancy ----------
// Tile: 8 rows x 16 cols. 4 waves = 2 row-groups(4 rows) x 2 cout-halves.
// Per wave-iter: 8 JIT A-loads, 8 ds_read_b128 (own cout-half), 32 MFMA.
template<int CIN,int COUT,int H,int W>
__global__ __launch_bounds__(256,4) void convmf_k(
    const unsigned short* __restrict__ in, const unsigned short* __restrict__ wp,
    const float* __restrict__ bsc, const float* __restrict__ bsh,
    unsigned short* __restrict__ out)
{
    constexpr int PH=(H+1)/2, PW=(W+1)/2;
    constexpr int HALVES = CIN/64;
    constexpr int NIT = 9*HALVES;          // BK=64 iterations
    constexpr int COUTW = COUT/2;
    constexpr int NREP = COUTW/16;
    constexpr int CH = (64*COUT)/(256*8);  // 16B chunks per thread per K-tile
    __shared__ alignas(16) unsigned short wls[2][64*COUT];

    const int tid = threadIdx.x;
    const int lane = tid & 63;
    const int wv = tid >> 6;
    const int wn  = wv & 1;                // cout-half
    const int wmr = wv >> 1;               // row-group (4 rows)
    const int l15 = lane & 15, l4 = lane >> 4;
    const int x0 = blockIdx.x*16, y0 = blockIdx.y*8;
    const int b = blockIdx.z;
    const unsigned short* inb = in + (size_t)b*H*W*CIN;

    // hoisted addressing: rows j=0..5 -> gy=y0+4*wmr-1+j, cols kx=0..2 -> gx=x0+l15+kx-1
    int rowoff[6]; bool rowok[6];
#pragma unroll
    for (int j=0;j<6;j++){
        int gy = y0 + 4*wmr - 1 + j;
        rowok[j] = (unsigned)gy < (unsigned)H;
        rowoff[j] = (rowok[j] ? gy : 0) * (W*CIN);
    }
    int coloff[3]; bool colok[3];
#pragma unroll
    for (int kx=0;kx<3;kx++){
        int gx = x0 + l15 + kx - 1;
        colok[kx] = (unsigned)gx < (unsigned)W;
        coloff[kx] = (colok[kx] ? gx : 0) * CIN;
    }

    f32x4 acc[4][NREP];    // [row][nf]
#pragma unroll
    for (int m=0;m<4;m++)
#pragma unroll
    for (int n=0;n<NREP;n++) acc[m][n] = f32x4{0.f,0.f,0.f,0.f};

    // W staging: direct global->LDS DMA, 16B/lane, linear (wave-uniform dest base)
    auto stageB = [&](int it, int buf){
        const unsigned short* src = wp + (size_t)(it*8)*(COUT*8);
#pragma unroll
        for (int i=0;i<CH;i++){
            const unsigned short* g = src + (size_t)(tid + i*256)*8;
            unsigned short* l = &wls[buf][((tid & ~63) + i*256)*8];
            __builtin_amdgcn_global_load_lds(
                (const __attribute__((address_space(1))) unsigned int*)(uintptr_t)g,
                (__attribute__((address_space(3))) unsigned int*)(uintptr_t)l,
                16, 0, 0);
        }
    };

    stageB(0, 0);
    __syncthreads();

    for (int it=0; it<NIT; ++it){
        if (it+1 < NIT) stageB(it+1, (it+1)&1);
        // JIT A-load for this K-tile
        const int tap = it / HALVES;
        const int khalf = it - tap*HALVES;
        const int ky = tap/3, kx = tap - ky*3;
        const int cin0 = khalf*64 + l4*8;
        const short8v z8 = short8v{0,0,0,0,0,0,0,0};
        short8v a[4][2];
#pragma unroll
        for (int rf=0;rf<4;rf++){
            const int j = rf + ky;
            const bool ok = rowok[j] && colok[kx];
            const unsigned short* p = inb + rowoff[j] + coloff[kx] + cin0;
#pragma unroll
            for (int ks=0;ks<2;ks++){
                short8v v = *(const short8v*)(p + ks*32);
                a[rf][ks] = ok ? v : z8;
            }
        }
        const unsigned short* wb = &wls[it&1][0];
#pragma unroll
        for (int ks=0; ks<2; ++ks){
#pragma unroll
            for (int nf=0; nf<NREP; ++nf){
                short8v bfr = *(const short8v*)&wb[((ks*4+l4)*COUT + wn*COUTW + nf*16 + l15)*8];
#pragma unroll
                for (int rf=0; rf<4; ++rf)
                    acc[rf][nf] = __builtin_amdgcn_mfma_f32_16x16x32_bf16(a[rf][ks], bfr, acc[rf][nf],0,0,0);
            }
        }
        __syncthreads();
    }

    // epilogue: BN + leaky + 2x2 SAME maxpool + bf16 store
#pragma unroll
    for (int prl=0; prl<2; ++prl){
        const int pr = (y0>>1) + 2*wmr + prl;
        if (pr >= PH) continue;
        const bool r1 = (y0 + 4*wmr + 2*prl + 1) < H;
        unsigned short* ob = out + ((size_t)b*PH + pr)*PW*COUT;
#pragma unroll
        for (int nf=0; nf<NREP; ++nf){
            const int co = wn*COUTW + nf*16 + l15;
            const float scv = bsc[co], shv = bsh[co];
            f32x4 e = acc[2*prl][nf], o = acc[2*prl+1][nf];
#pragma unroll
            for (int pp=0; pp<2; ++pp){
                const int pc = (x0>>1) + l4*2 + pp;
                if (pc >= PW) continue;
                const int oddcol = x0 + l4*4 + 2*pp + 1;
                float m = bnl(e[2*pp], scv, shv);
                if (oddcol < W) m = fmaxf(m, bnl(e[2*pp+1], scv, shv));
                if (r1){
                    m = fmaxf(m, bnl(o[2*pp], scv, shv));
                    if (oddcol < W) m = fmaxf(m, bnl(o[2*pp+1], scv, shv));
                }
                ob[(size_t)pc*COUT + co] = f2bf(m);
            }
        }
    }
}

// ---------- MFMA row-GEMM: out[3072][512] = A @ W + bias ----------
template<int K, int MODE>
__global__ __launch_bounds__(256) void gemmrow_k(
    const unsigned short* __restrict__ A, const unsigned short* __restrict__ wp,
    const float* __restrict__ bias, float* __restrict__ out)
{
    constexpr int NS = K/32;
    __shared__ alignas(16) unsigned short wls[2][16384];
    const int tid = threadIdx.x, lane = tid & 63, w = tid >> 6;
    const int l15 = lane & 15, l4 = lane >> 4;
    const int r0 = blockIdx.x*64;

    f32x4 acc[4][8];
#pragma unroll
    for (int m=0;m<4;m++)
#pragma unroll
    for (int n=0;n<8;n++) acc[m][n] = f32x4{0.f,0.f,0.f,0.f};

    auto stage = [&](int s, int buf){
        const unsigned short* src = wp + (size_t)s*16384;
#pragma unroll
        for (int i=0;i<8;i++){
            int e = (tid + i*256)*8;
            *(short8v*)&wls[buf][e] = *(const short8v*)&src[e];
        }
    };
    stage(0,0);
    __syncthreads();

    for (int s=0;s<NS;++s){
        const int k0 = s*32 + l4*8;
        short8v af[4];
#pragma unroll
        for (int mf=0;mf<4;++mf){
            const int row = r0 + mf*16 + l15;
            size_t idx;
            if constexpr (MODE == 0){
                const int b = row & 255, t = row >> 8;
                idx = (size_t)b*3072 + (k0>>6)*768 + t*64 + (k0&63);
            } else {
                idx = (size_t)row*K + k0;
            }
            af[mf] = *(const short8v*)&A[idx];
        }
        if (s+1 < NS) stage(s+1,(s+1)&1);
        const unsigned short* wb = &wls[s&1][0];
#pragma unroll
        for (int nf=0;nf<8;++nf){
            const int col = w*128 + nf*16 + l15;
            short8v bfr = *(const short8v*)&wb[(l4*512 + col)*8];
#pragma unroll
            for (int mf=0;mf<4;++mf)
                acc[mf][nf] = __builtin_amdgcn_mfma_f32_16x16x32_bf16(af[mf], bfr, acc[mf][nf], 0,0,0);
        }
        __syncthreads();
    }
#pragma unroll
    for (int nf=0;nf<8;++nf){
        const int col = w*128 + nf*16 + l15;
        const float bv = bias[col];
#pragma unroll
        for (int mf=0;mf<4;++mf){
#pragma unroll
            for (int j=0;j<4;++j){
                const int row = r0 + mf*16 + l4*4 + j;
                out[(size_t)row*512 + col] = acc[mf][nf][j] + bv;
            }
        }
    }
}

// ---------- layer-0 LSTM: Wh0 LDS-resident, 256 blocks x 1 batch ----------
__global__ __launch_bounds__(512) void lstm0_k(
    const float* __restrict__ xp, const unsigned short* __restrict__ wh0p,
    unsigned short* __restrict__ h0g)
{
    __shared__ alignas(16) unsigned short wl[65536];   // 128 KB
    __shared__ alignas(16) float hb[128];
    __shared__ float zs[512];
    const int col = threadIdx.x;
    const int b = blockIdx.x;
#pragma unroll
    for (int i=0;i<16;i++){
        int e = (col + i*512)*8;
        *(short8v*)&wl[e] = *(const short8v*)&wh0p[e];
    }
    if (col < 128) hb[col] = 0.f;
    float c0 = 0.f;
    __syncthreads();

    for (int t=0;t<12;t++){
        float acc = xp[((size_t)t*256 + b)*512 + col];
#pragma unroll 4
        for (int kg=0;kg<16;kg++){
            short8v w8 = *(const short8v*)&wl[(kg*512 + col)*8];
            float4 hlo = *(const float4*)&hb[kg*8];
            float4 hhi = *(const float4*)&hb[kg*8+4];
            acc = fmaf(bf2f((unsigned short)w8[0]), hlo.x, acc);
            acc = fmaf(bf2f((unsigned short)w8[1]), hlo.y, acc);
            acc = fmaf(bf2f((unsigned short)w8[2]), hlo.z, acc);
            acc = fmaf(bf2f((unsigned short)w8[3]), hlo.w, acc);
            acc = fmaf(bf2f((unsigned short)w8[4]), hhi.x, acc);
            acc = fmaf(bf2f((unsigned short)w8[5]), hhi.y, acc);
            acc = fmaf(bf2f((unsigned short)w8[6]), hhi.z, acc);
            acc = fmaf(bf2f((unsigned short)w8[7]), hhi.w, acc);
        }
        zs[col] = acc;
        __syncthreads();
        if (col < 128){
            float zi=zs[col], zj=zs[128+col], zf=zs[256+col], zo=zs[384+col];
            c0 = c0*sigm(zf+1.f) + sigm(zi)*tanhf_(zj);
            float h = tanhf_(c0)*sigm(zo);
            hb[col] = h;
            h0g[((size_t)t*256 + b)*128 + col] = f2bf(h);
        }
        __syncthreads();
    }
}

// ---------- layer-1 LSTM + projection: Wh1 LDS-resident, 256 blocks x 1 batch ----------
__global__ __launch_bounds__(512) void lstm1_k(
    const float* __restrict__ zp1, const unsigned short* __restrict__ wh1p,
    const unsigned short* __restrict__ woT, const float* __restrict__ bout,
    float* __restrict__ out)
{
    __shared__ alignas(16) unsigned short wl[65536];   // 128 KB
    __shared__ alignas(16) float hb[128];
    __shared__ float zs[512];
    __shared__ float red[37][8];
    const int col = threadIdx.x;
    const int b = blockIdx.x;
#pragma unroll
    for (int i=0;i<16;i++){
        int e = (col + i*512)*8;
        *(short8v*)&wl[e] = *(const short8v*)&wh1p[e];
    }
    if (col < 128) hb[col] = 0.f;
    float c1 = 0.f;
    __syncthreads();

    for (int t=0;t<12;t++){
        float acc = zp1[((size_t)t*256 + b)*512 + col];
#pragma unroll 4
        for (int kg=0;kg<16;kg++){
            short8v w8 = *(const short8v*)&wl[(kg*512 + col)*8];
            float4 hlo = *(const float4*)&hb[kg*8];
            float4 hhi = *(const float4*)&hb[kg*8+4];
            acc = fmaf(bf2f((unsigned short)w8[0]), hlo.x, acc);
            acc = fmaf(bf2f((unsigned short)w8[1]), hlo.y, acc);
            acc = fmaf(bf2f((unsigned short)w8[2]), hlo.z, acc);
            acc = fmaf(bf2f((unsigned short)w8[3]), hlo.w, acc);
            acc = fmaf(bf2f((unsigned short)w8[4]), hhi.x, acc);
            acc = fmaf(bf2f((unsigned short)w8[5]), hhi.y, acc);
            acc = fmaf(bf2f((unsigned short)w8[6]), hhi.z, acc);
            acc = fmaf(bf2f((unsigned short)w8[7]), hhi.w, acc);
        }
        zs[col] = acc;
        __syncthreads();
        if (col < 128){
            float zi=zs[col], zj=zs[128+col], zf=zs[256+col], zo=zs[384+col];
            c1 = c1*sigm(zf+1.f) + sigm(zi)*tanhf_(zj);
            hb[col] = tanhf_(c1)*sigm(zo);
        }
        __syncthreads();
        if (col < 296){
            const int n = col >> 3, q = col & 7;
            float p0 = 0.f;
#pragma unroll
            for (int kk=0;kk<16;kk++){
                float wv2 = bf2f(woT[n*128 + q*16 + kk]);
                p0 = fmaf(hb[q*16+kk], wv2, p0);
            }
            red[n][q] = p0;
        }
        __syncthreads();
        if (col < 37){
            float s0 = bout[col];
#pragma unroll
            for (int q=0;q<8;q++) s0 += red[col][q];
            out[((size_t)t*256 + b)*37 + col] = s0;
        }
        __syncthreads();
    }
}

extern "C" void kernel_launch(void* const* d_in, const int* in_sizes, int n_in,
                              void* d_out, int out_size, void* d_ws, size_t ws_size,
                              hipStream_t stream) {
    const float* x = (const float*)d_in[0];
    const float *w_[4], *cb_[4], *g_[4], *bb_[4], *mm_[4], *mv_[4];
    for (int i=0;i<4;i++){
        w_[i]  = (const float*)d_in[1+6*i];
        cb_[i] = (const float*)d_in[2+6*i];
        g_[i]  = (const float*)d_in[3+6*i];
        bb_[i] = (const float*)d_in[4+6*i];
        mm_[i] = (const float*)d_in[5+6*i];
        mv_[i] = (const float*)d_in[6+6*i];
    }
    const float* lW0  = (const float*)d_in[25];
    const float* lb0  = (const float*)d_in[26];
    const float* lW1  = (const float*)d_in[27];
    const float* lb1  = (const float*)d_in[28];
    const float* Wout = (const float*)d_in[29];
    const float* bout = (const float*)d_in[30];
    float* out = (float*)d_out;

    const size_t fixed = 6291456ull + 6291456 + 4096 + 1572864 + 786432
                       + 147456 + 294912 + 147456
                       + 262144 + 131072 + 131072 + 131072 + 9472;
    int Bc = 256;
    while (Bc > 8 && fixed + (size_t)Bc*565504 > ws_size) Bc >>= 1;

    char* cur = (char*)d_ws;
    float* XP  = (float*)cur;                    cur += 6291456;
    float* ZP1 = (float*)cur;                    cur += 6291456;
    float* bns = (float*)cur;                    cur += 4096;
    unsigned short* F    = (unsigned short*)cur; cur += 1572864;
    unsigned short* h0g  = (unsigned short*)cur; cur += 786432;
    unsigned short* Wp1  = (unsigned short*)cur; cur += 147456;
    unsigned short* Wp2  = (unsigned short*)cur; cur += 294912;
    unsigned short* Wp3  = (unsigned short*)cur; cur += 147456;
    unsigned short* Wx0p = (unsigned short*)cur; cur += 262144;
    unsigned short* Wh0p = (unsigned short*)cur; cur += 131072;
    unsigned short* Wx1p = (unsigned short*)cur; cur += 131072;
    unsigned short* Wh1p = (unsigned short*)cur; cur += 131072;
    unsigned short* WoT  = (unsigned short*)cur; cur += 9472;
    unsigned short* A    = (unsigned short*)cur; cur += (size_t)Bc*345600;
    unsigned short* Bb   = (unsigned short*)cur; cur += (size_t)Bc*172800;
    unsigned short* C    = (unsigned short*)cur;

    pack_k<<<(9*64*128+255)/256, 256, 0, stream>>>(w_[1], Wp1, 64, 128);
    pack_k<<<(9*128*128+255)/256, 256, 0, stream>>>(w_[2], Wp2, 128, 128);
    pack_k<<<(9*128*64+255)/256, 256, 0, stream>>>(w_[3], Wp3, 128, 64);
    packW_k<<<512, 256, 0, stream>>>(lW0,           Wx0p, 256);
    packW_k<<<256, 256, 0, stream>>>(lW0 + 256*512, Wh0p, 128);
    packW_k<<<256, 256, 0, stream>>>(lW1,           Wx1p, 128);
    packW_k<<<256, 256, 0, stream>>>(lW1 + 128*512, Wh1p, 128);
    packWoT_k<<<19, 256, 0, stream>>>(Wout, WoT);
    bn_k<<<1,128,0,stream>>>(cb_[1],g_[1],bb_[1],mm_[1],mv_[1], bns+0,   bns+128, 128);
    bn_k<<<1,128,0,stream>>>(cb_[2],g_[2],bb_[2],mm_[2],mv_[2], bns+256, bns+384, 128);
    bn_k<<<1,64 ,0,stream>>>(cb_[3],g_[3],bb_[3],mm_[3],mv_[3], bns+512, bns+576, 64);
    bn_k<<<1,64 ,0,stream>>>(cb_[0],g_[0],bb_[0],mm_[0],mv_[0], bns+640, bns+704, 64);

    const int nc = 256 / Bc;
    for (int bc=0; bc<nc; bc++){
        int bbase = bc*Bc;
        conv0_k<<<(Bc*2700+255)/256, 256, 0, stream>>>(x, w_[0], bns+640, bns+704, A, bbase, Bc*2700);
        convmf_k<64,128,30,90><<<dim3(6,4,Bc), 256, 0, stream>>>(A, Wp1, bns+0, bns+128, Bb);
        convmf_k<128,128,15,45><<<dim3(3,2,Bc), 256, 0, stream>>>(Bb, Wp2, bns+256, bns+384, C);
        convmf_k<128,64,8,23><<<dim3(2,1,Bc), 256, 0, stream>>>(C, Wp3, bns+512, bns+576,
                                                                F + (size_t)bbase*3072);
    }
    gemmrow_k<256,0><<<48, 256, 0, stream>>>(F, Wx0p, lb0, XP);
    lstm0_k<<<256, 512, 0, stream>>>(XP, Wh0p, h0g);
    gemmrow_k<128,1><<<48, 256, 0, stream>>>(h0g, Wx1p, lb1, ZP1);
    lstm1_k<<<256, 512, 0, stream>>>(ZP1, Wh1p, WoT, bout, out);
}

// Round 16
// 576.016 us; speedup vs baseline: 1.0658x; 1.0658x over previous
//
#include <hip/hip_runtime.h>
#include <hip/hip_bf16.h>
#include <math.h>
#include <stdint.h>

#define EPS 1e-5f
#define LEAK 0.01f
#define NEG_INF (-3.402823e38f)

typedef __attribute__((ext_vector_type(8))) short short8v;
typedef __attribute__((ext_vector_type(4))) float f32x4;

__device__ __forceinline__ float sigm(float x){ return 1.0f/(1.0f + __expf(-x)); }
__device__ __forceinline__ float tanhf_(float x){ return 1.0f - 2.0f/(__expf(2.0f*x)+1.0f); }
__device__ __forceinline__ float bnl(float a, float sc, float sh){
    float v = fmaf(a, sc, sh);
    return v < 0.0f ? LEAK*v : v;
}
__device__ __forceinline__ unsigned short f2bf(float f){
    __hip_bfloat16 h = __float2bfloat16(f);
    return *reinterpret_cast<unsigned short*>(&h);
}
__device__ __forceinline__ float bf2f(unsigned short u){
    return __uint_as_float(((unsigned)u) << 16);
}

// ---------- conv weight pack: w[3][3][CIN][COUT] f32 -> wp[(9*CIN)/8][COUT][8] bf16 ----------
__global__ __launch_bounds__(256) void pack_k(const float* __restrict__ w,
                                              unsigned short* __restrict__ wp,
                                              int CIN, int COUT){
    int t = blockIdx.x*256 + threadIdx.x;
    int total = 9*CIN*COUT;
    if (t >= total) return;
    int cout = t % COUT, k = t / COUT;
    float v = w[(size_t)k*COUT + cout];
    wp[(size_t)(k>>3)*COUT*8 + (size_t)cout*8 + (k&7)] = f2bf(v);
}

// ---------- LSTM weight pack: src[K][512] f32 -> dst[(K/8)][512][8] bf16 ----------
__global__ __launch_bounds__(256) void packW_k(const float* __restrict__ src,
                                               unsigned short* __restrict__ dst, int K){
    int t = blockIdx.x*256 + threadIdx.x;
    if (t < K*512){
        int k = t >> 9, col = t & 511;
        dst[(size_t)(k>>3)*4096 + col*8 + (k&7)] = f2bf(src[(size_t)k*512 + col]);
    }
}

// ---------- Wout pack: Wout[128][37] f32 -> WoT[37][128] bf16 ----------
__global__ __launch_bounds__(256) void packWoT_k(const float* __restrict__ src,
                                                 unsigned short* __restrict__ dst){
    int t = blockIdx.x*256 + threadIdx.x;
    if (t < 37*128){
        int n = t >> 7, k = t & 127;
        dst[t] = f2bf(src[k*37 + n]);
    }
}

// ---------- BN fold ----------
__global__ void bn_k(const float* __restrict__ cb, const float* __restrict__ g,
                     const float* __restrict__ bb, const float* __restrict__ mm,
                     const float* __restrict__ mv, float* __restrict__ sc,
                     float* __restrict__ sh, int n){
    int t = threadIdx.x;
    if (t < n){
        float s = g[t]*rsqrtf(mv[t]+EPS);
        sc[t] = s;
        sh[t] = fmaf(cb[t]-mm[t], s, bb[t]);
    }
}

// ---------- conv block 0: thread = one pooled px, all 64 couts; weights in LDS ----------
__global__ __launch_bounds__(256) void conv0_k(
    const float* __restrict__ x, const float* __restrict__ w,
    const float* __restrict__ bsc, const float* __restrict__ bsh,
    unsigned short* __restrict__ out, int bbase, int total)
{
    __shared__ float wv[576];
    __shared__ float scs[64], shs[64];
    const int tid = threadIdx.x;
    for (int i=tid;i<576;i+=256) wv[i] = w[i];
    if (tid < 64){ scs[tid]=bsc[tid]; shs[tid]=bsh[tid]; }
    __syncthreads();
    const int id = blockIdx.x*256 + tid;
    if (id >= total) return;
    const int px = id % 90; int r = id / 90; const int py = r % 30; const int b0 = r / 30;
    const float* xb = x + (size_t)(bbase+b0)*10800;
    float p[4][4];
    const int y0 = 2*py-1, xx0 = 2*px-1;
#pragma unroll
    for (int rr=0;rr<4;rr++){
        int yy=y0+rr;
#pragma unroll
        for (int cc=0;cc<4;cc++){
            int xc=xx0+cc;
            p[rr][cc] = (yy>=0&&yy<60&&xc>=0&&xc<180)? xb[yy*180+xc] : 0.f;
        }
    }
    unsigned short* ob = out + (size_t)id*64;
#pragma unroll
    for (int cg=0;cg<8;cg++){
        short8v o8;
#pragma unroll
        for (int j=0;j<8;j++){
            const int co = cg*8+j;
            float s00=0.f,s01=0.f,s10=0.f,s11=0.f;
#pragma unroll
            for (int ky=0;ky<3;ky++)
#pragma unroll
            for (int kx=0;kx<3;kx++){
                float wt = wv[(ky*3+kx)*64+co];
                s00 = fmaf(p[ky][kx],     wt, s00);
                s01 = fmaf(p[ky][kx+1],   wt, s01);
                s10 = fmaf(p[ky+1][kx],   wt, s10);
                s11 = fmaf(p[ky+1][kx+1], wt, s11);
            }
            float sc=scs[co], sh=shs[co];
            float m = fmaxf(fmaxf(bnl(s00,sc,sh),bnl(s01,sc,sh)),
                            fmaxf(bnl(s10,sc,sh),bnl(s11,sc,sh)));
            o8[j] = (short)f2bf(m);
        }
        *(short8v*)&ob[cg*8] = o8;
    }
}

// ---------- MFMA fused conv+BN+leaky+pool: cout-split waves, low LDS redundancy ----------
// Tile: 8 rows x 16 cols. 4 waves = 2 row-groups(4 rows) x 2 cout-halves.
// Per wave-iter: 8 JIT A-loads, 8 ds_read_b128 (own cout-half), 32 MFMA.
// (256,3): 170-reg cap avoids the (256,4) spill seen in r15.
template<int CIN,int COUT,int H,int W>
__global__ __launch_bounds__(256,3) void convmf_k(
    const unsigned short* __restrict__ in, const unsigned short* __restrict__ wp,
    const float* __restrict__ bsc, const float* __restrict__ bsh,
    unsigned short* __restrict__ out)
{
    constexpr int PH=(H+1)/2, PW=(W+1)/2;
    constexpr int HALVES = CIN/64;
    constexpr int NIT = 9*HALVES;          // BK=64 iterations
    constexpr int COUTW = COUT/2;
    constexpr int NREP = COUTW/16;
    constexpr int CH = (64*COUT)/(256*8);  // 16B chunks per thread per K-tile
    __shared__ alignas(16) unsigned short wls[2][64*COUT];

    const int tid = threadIdx.x;
    const int lane = tid & 63;
    const int wv = tid >> 6;
    const int wn  = wv & 1;                // cout-half
    const int wmr = wv >> 1;               // row-group (4 rows)
    const int l15 = lane & 15, l4 = lane >> 4;
    const int x0 = blockIdx.x*16, y0 = blockIdx.y*8;
    const int b = blockIdx.z;
    const unsigned short* inb = in + (size_t)b*H*W*CIN;

    // hoisted addressing: rows j=0..5 -> gy=y0+4*wmr-1+j, cols kx=0..2 -> gx=x0+l15+kx-1
    int rowoff[6]; bool rowok[6];
#pragma unroll
    for (int j=0;j<6;j++){
        int gy = y0 + 4*wmr - 1 + j;
        rowok[j] = (unsigned)gy < (unsigned)H;
        rowoff[j] = (rowok[j] ? gy : 0) * (W*CIN);
    }
    int coloff[3]; bool colok[3];
#pragma unroll
    for (int kx=0;kx<3;kx++){
        int gx = x0 + l15 + kx - 1;
        colok[kx] = (unsigned)gx < (unsigned)W;
        coloff[kx] = (colok[kx] ? gx : 0) * CIN;
    }

    f32x4 acc[4][NREP];    // [row][nf]
#pragma unroll
    for (int m=0;m<4;m++)
#pragma unroll
    for (int n=0;n<NREP;n++) acc[m][n] = f32x4{0.f,0.f,0.f,0.f};

    // W staging: direct global->LDS DMA, 16B/lane, linear (wave-uniform dest base)
    auto stageB = [&](int it, int buf){
        const unsigned short* src = wp + (size_t)(it*8)*(COUT*8);
#pragma unroll
        for (int i=0;i<CH;i++){
            const unsigned short* g = src + (size_t)(tid + i*256)*8;
            unsigned short* l = &wls[buf][((tid & ~63) + i*256)*8];
            __builtin_amdgcn_global_load_lds(
                (const __attribute__((address_space(1))) unsigned int*)(uintptr_t)g,
                (__attribute__((address_space(3))) unsigned int*)(uintptr_t)l,
                16, 0, 0);
        }
    };

    stageB(0, 0);
    __syncthreads();

    for (int it=0; it<NIT; ++it){
        if (it+1 < NIT) stageB(it+1, (it+1)&1);
        // JIT A-load for this K-tile
        const int tap = it / HALVES;
        const int khalf = it - tap*HALVES;
        const int ky = tap/3, kx = tap - ky*3;
        const int cin0 = khalf*64 + l4*8;
        const short8v z8 = short8v{0,0,0,0,0,0,0,0};
        short8v a[4][2];
#pragma unroll
        for (int rf=0;rf<4;rf++){
            const int j = rf + ky;
            const bool ok = rowok[j] && colok[kx];
            const unsigned short* p = inb + rowoff[j] + coloff[kx] + cin0;
#pragma unroll
            for (int ks=0;ks<2;ks++){
                short8v v = *(const short8v*)(p + ks*32);
                a[rf][ks] = ok ? v : z8;
            }
        }
        const unsigned short* wb = &wls[it&1][0];
#pragma unroll
        for (int ks=0; ks<2; ++ks){
#pragma unroll
            for (int nf=0; nf<NREP; ++nf){
                short8v bfr = *(const short8v*)&wb[((ks*4+l4)*COUT + wn*COUTW + nf*16 + l15)*8];
#pragma unroll
                for (int rf=0; rf<4; ++rf)
                    acc[rf][nf] = __builtin_amdgcn_mfma_f32_16x16x32_bf16(a[rf][ks], bfr, acc[rf][nf],0,0,0);
            }
        }
        __syncthreads();
    }

    // epilogue: BN + leaky + 2x2 SAME maxpool + bf16 store
#pragma unroll
    for (int prl=0; prl<2; ++prl){
        const int pr = (y0>>1) + 2*wmr + prl;
        if (pr >= PH) continue;
        const bool r1 = (y0 + 4*wmr + 2*prl + 1) < H;
        unsigned short* ob = out + ((size_t)b*PH + pr)*PW*COUT;
#pragma unroll
        for (int nf=0; nf<NREP; ++nf){
            const int co = wn*COUTW + nf*16 + l15;
            const float scv = bsc[co], shv = bsh[co];
            f32x4 e = acc[2*prl][nf], o = acc[2*prl+1][nf];
#pragma unroll
            for (int pp=0; pp<2; ++pp){
                const int pc = (x0>>1) + l4*2 + pp;
                if (pc >= PW) continue;
                const int oddcol = x0 + l4*4 + 2*pp + 1;
                float m = bnl(e[2*pp], scv, shv);
                if (oddcol < W) m = fmaxf(m, bnl(e[2*pp+1], scv, shv));
                if (r1){
                    m = fmaxf(m, bnl(o[2*pp], scv, shv));
                    if (oddcol < W) m = fmaxf(m, bnl(o[2*pp+1], scv, shv));
                }
                ob[(size_t)pc*COUT + co] = f2bf(m);
            }
        }
    }
}

// ---------- MFMA row-GEMM: out[3072][512] = A @ W + bias ----------
template<int K, int MODE>
__global__ __launch_bounds__(256) void gemmrow_k(
    const unsigned short* __restrict__ A, const unsigned short* __restrict__ wp,
    const float* __restrict__ bias, float* __restrict__ out)
{
    constexpr int NS = K/32;
    __shared__ alignas(16) unsigned short wls[2][16384];
    const int tid = threadIdx.x, lane = tid & 63, w = tid >> 6;
    const int l15 = lane & 15, l4 = lane >> 4;
    const int r0 = blockIdx.x*64;

    f32x4 acc[4][8];
#pragma unroll
    for (int m=0;m<4;m++)
#pragma unroll
    for (int n=0;n<8;n++) acc[m][n] = f32x4{0.f,0.f,0.f,0.f};

    auto stage = [&](int s, int buf){
        const unsigned short* src = wp + (size_t)s*16384;
#pragma unroll
        for (int i=0;i<8;i++){
            int e = (tid + i*256)*8;
            *(short8v*)&wls[buf][e] = *(const short8v*)&src[e];
        }
    };
    stage(0,0);
    __syncthreads();

    for (int s=0;s<NS;++s){
        const int k0 = s*32 + l4*8;
        short8v af[4];
#pragma unroll
        for (int mf=0;mf<4;++mf){
            const int row = r0 + mf*16 + l15;
            size_t idx;
            if constexpr (MODE == 0){
                const int b = row & 255, t = row >> 8;
                idx = (size_t)b*3072 + (k0>>6)*768 + t*64 + (k0&63);
            } else {
                idx = (size_t)row*K + k0;
            }
            af[mf] = *(const short8v*)&A[idx];
        }
        if (s+1 < NS) stage(s+1,(s+1)&1);
        const unsigned short* wb = &wls[s&1][0];
#pragma unroll
        for (int nf=0;nf<8;++nf){
            const int col = w*128 + nf*16 + l15;
            short8v bfr = *(const short8v*)&wb[(l4*512 + col)*8];
#pragma unroll
            for (int mf=0;mf<4;++mf)
                acc[mf][nf] = __builtin_amdgcn_mfma_f32_16x16x32_bf16(af[mf], bfr, acc[mf][nf], 0,0,0);
        }
        __syncthreads();
    }
#pragma unroll
    for (int nf=0;nf<8;++nf){
        const int col = w*128 + nf*16 + l15;
        const float bv = bias[col];
#pragma unroll
        for (int mf=0;mf<4;++mf){
#pragma unroll
            for (int j=0;j<4;++j){
                const int row = r0 + mf*16 + l4*4 + j;
                out[(size_t)row*512 + col] = acc[mf][nf][j] + bv;
            }
        }
    }
}

// ---------- layer-0 LSTM: Wh0 LDS-resident, 256 blocks x 1 batch ----------
__global__ __launch_bounds__(512) void lstm0_k(
    const float* __restrict__ xp, const unsigned short* __restrict__ wh0p,
    unsigned short* __restrict__ h0g)
{
    __shared__ alignas(16) unsigned short wl[65536];   // 128 KB
    __shared__ alignas(16) float hb[128];
    __shared__ float zs[512];
    const int col = threadIdx.x;
    const int b = blockIdx.x;
#pragma unroll
    for (int i=0;i<16;i++){
        int e = (col + i*512)*8;
        *(short8v*)&wl[e] = *(const short8v*)&wh0p[e];
    }
    if (col < 128) hb[col] = 0.f;
    float c0 = 0.f;
    __syncthreads();

    for (int t=0;t<12;t++){
        float acc = xp[((size_t)t*256 + b)*512 + col];
#pragma unroll 4
        for (int kg=0;kg<16;kg++){
            short8v w8 = *(const short8v*)&wl[(kg*512 + col)*8];
            float4 hlo = *(const float4*)&hb[kg*8];
            float4 hhi = *(const float4*)&hb[kg*8+4];
            acc = fmaf(bf2f((unsigned short)w8[0]), hlo.x, acc);
            acc = fmaf(bf2f((unsigned short)w8[1]), hlo.y, acc);
            acc = fmaf(bf2f((unsigned short)w8[2]), hlo.z, acc);
            acc = fmaf(bf2f((unsigned short)w8[3]), hlo.w, acc);
            acc = fmaf(bf2f((unsigned short)w8[4]), hhi.x, acc);
            acc = fmaf(bf2f((unsigned short)w8[5]), hhi.y, acc);
            acc = fmaf(bf2f((unsigned short)w8[6]), hhi.z, acc);
            acc = fmaf(bf2f((unsigned short)w8[7]), hhi.w, acc);
        }
        zs[col] = acc;
        __syncthreads();
        if (col < 128){
            float zi=zs[col], zj=zs[128+col], zf=zs[256+col], zo=zs[384+col];
            c0 = c0*sigm(zf+1.f) + sigm(zi)*tanhf_(zj);
            float h = tanhf_(c0)*sigm(zo);
            hb[col] = h;
            h0g[((size_t)t*256 + b)*128 + col] = f2bf(h);
        }
        __syncthreads();
    }
}

// ---------- layer-1 LSTM + projection: Wh1 LDS-resident, 256 blocks x 1 batch ----------
__global__ __launch_bounds__(512) void lstm1_k(
    const float* __restrict__ zp1, const unsigned short* __restrict__ wh1p,
    const unsigned short* __restrict__ woT, const float* __restrict__ bout,
    float* __restrict__ out)
{
    __shared__ alignas(16) unsigned short wl[65536];   // 128 KB
    __shared__ alignas(16) float hb[128];
    __shared__ float zs[512];
    __shared__ float red[37][8];
    const int col = threadIdx.x;
    const int b = blockIdx.x;
#pragma unroll
    for (int i=0;i<16;i++){
        int e = (col + i*512)*8;
        *(short8v*)&wl[e] = *(const short8v*)&wh1p[e];
    }
    if (col < 128) hb[col] = 0.f;
    float c1 = 0.f;
    __syncthreads();

    for (int t=0;t<12;t++){
        float acc = zp1[((size_t)t*256 + b)*512 + col];
#pragma unroll 4
        for (int kg=0;kg<16;kg++){
            short8v w8 = *(const short8v*)&wl[(kg*512 + col)*8];
            float4 hlo = *(const float4*)&hb[kg*8];
            float4 hhi = *(const float4*)&hb[kg*8+4];
            acc = fmaf(bf2f((unsigned short)w8[0]), hlo.x, acc);
            acc = fmaf(bf2f((unsigned short)w8[1]), hlo.y, acc);
            acc = fmaf(bf2f((unsigned short)w8[2]), hlo.z, acc);
            acc = fmaf(bf2f((unsigned short)w8[3]), hlo.w, acc);
            acc = fmaf(bf2f((unsigned short)w8[4]), hhi.x, acc);
            acc = fmaf(bf2f((unsigned short)w8[5]), hhi.y, acc);
            acc = fmaf(bf2f((unsigned short)w8[6]), hhi.z, acc);
            acc = fmaf(bf2f((unsigned short)w8[7]), hhi.w, acc);
        }
        zs[col] = acc;
        __syncthreads();
        if (col < 128){
            float zi=zs[col], zj=zs[128+col], zf=zs[256+col], zo=zs[384+col];
            c1 = c1*sigm(zf+1.f) + sigm(zi)*tanhf_(zj);
            hb[col] = tanhf_(c1)*sigm(zo);
        }
        __syncthreads();
        if (col < 296){
            const int n = col >> 3, q = col & 7;
            float p0 = 0.f;
#pragma unroll
            for (int kk=0;kk<16;kk++){
                float wv2 = bf2f(woT[n*128 + q*16 + kk]);
                p0 = fmaf(hb[q*16+kk], wv2, p0);
            }
            red[n][q] = p0;
        }
        __syncthreads();
        if (col < 37){
            float s0 = bout[col];
#pragma unroll
            for (int q=0;q<8;q++) s0 += red[col][q];
            out[((size_t)t*256 + b)*37 + col] = s0;
        }
        __syncthreads();
    }
}

extern "C" void kernel_launch(void* const* d_in, const int* in_sizes, int n_in,
                              void* d_out, int out_size, void* d_ws, size_t ws_size,
                              hipStream_t stream) {
    const float* x = (const float*)d_in[0];
    const float *w_[4], *cb_[4], *g_[4], *bb_[4], *mm_[4], *mv_[4];
    for (int i=0;i<4;i++){
        w_[i]  = (const float*)d_in[1+6*i];
        cb_[i] = (const float*)d_in[2+6*i];
        g_[i]  = (const float*)d_in[3+6*i];
        bb_[i] = (const float*)d_in[4+6*i];
        mm_[i] = (const float*)d_in[5+6*i];
        mv_[i] = (const float*)d_in[6+6*i];
    }
    const float* lW0  = (const float*)d_in[25];
    const float* lb0  = (const float*)d_in[26];
    const float* lW1  = (const float*)d_in[27];
    const float* lb1  = (const float*)d_in[28];
    const float* Wout = (const float*)d_in[29];
    const float* bout = (const float*)d_in[30];
    float* out = (float*)d_out;

    const size_t fixed = 6291456ull + 6291456 + 4096 + 1572864 + 786432
                       + 147456 + 294912 + 147456
                       + 262144 + 131072 + 131072 + 131072 + 9472;
    int Bc = 256;
    while (Bc > 8 && fixed + (size_t)Bc*565504 > ws_size) Bc >>= 1;

    char* cur = (char*)d_ws;
    float* XP  = (float*)cur;                    cur += 6291456;
    float* ZP1 = (float*)cur;                    cur += 6291456;
    float* bns = (float*)cur;                    cur += 4096;
    unsigned short* F    = (unsigned short*)cur; cur += 1572864;
    unsigned short* h0g  = (unsigned short*)cur; cur += 786432;
    unsigned short* Wp1  = (unsigned short*)cur; cur += 147456;
    unsigned short* Wp2  = (unsigned short*)cur; cur += 294912;
    unsigned short* Wp3  = (unsigned short*)cur; cur += 147456;
    unsigned short* Wx0p = (unsigned short*)cur; cur += 262144;
    unsigned short* Wh0p = (unsigned short*)cur; cur += 131072;
    unsigned short* Wx1p = (unsigned short*)cur; cur += 131072;
    unsigned short* Wh1p = (unsigned short*)cur; cur += 131072;
    unsigned short* WoT  = (unsigned short*)cur; cur += 9472;
    unsigned short* A    = (unsigned short*)cur; cur += (size_t)Bc*345600;
    unsigned short* Bb   = (unsigned short*)cur; cur += (size_t)Bc*172800;
    unsigned short* C    = (unsigned short*)cur;

    pack_k<<<(9*64*128+255)/256, 256, 0, stream>>>(w_[1], Wp1, 64, 128);
    pack_k<<<(9*128*128+255)/256, 256, 0, stream>>>(w_[2], Wp2, 128, 128);
    pack_k<<<(9*128*64+255)/256, 256, 0, stream>>>(w_[3], Wp3, 128, 64);
    packW_k<<<512, 256, 0, stream>>>(lW0,           Wx0p, 256);
    packW_k<<<256, 256, 0, stream>>>(lW0 + 256*512, Wh0p, 128);
    packW_k<<<256, 256, 0, stream>>>(lW1,           Wx1p, 128);
    packW_k<<<256, 256, 0, stream>>>(lW1 + 128*512, Wh1p, 128);
    packWoT_k<<<19, 256, 0, stream>>>(Wout, WoT);
    bn_k<<<1,128,0,stream>>>(cb_[1],g_[1],bb_[1],mm_[1],mv_[1], bns+0,   bns+128, 128);
    bn_k<<<1,128,0,stream>>>(cb_[2],g_[2],bb_[2],mm_[2],mv_[2], bns+256, bns+384, 128);
    bn_k<<<1,64 ,0,stream>>>(cb_[3],g_[3],bb_[3],mm_[3],mv_[3], bns+512, bns+576, 64);
    bn_k<<<1,64 ,0,stream>>>(cb_[0],g_[0],bb_[0],mm_[0],mv_[0], bns+640, bns+704, 64);

    const int nc = 256 / Bc;
    for (int bc=0; bc<nc; bc++){
        int bbase = bc*Bc;
        conv0_k<<<(Bc*2700+255)/256, 256, 0, stream>>>(x, w_[0], bns+640, bns+704, A, bbase, Bc*2700);
        convmf_k<64,128,30,90><<<dim3(6,4,Bc), 256, 0, stream>>>(A, Wp1, bns+0, bns+128, Bb);
        convmf_k<128,128,15,45><<<dim3(3,2,Bc), 256, 0, stream>>>(Bb, Wp2, bns+256, bns+384, C);
        convmf_k<128,64,8,23><<<dim3(2,1,Bc), 256, 0, stream>>>(C, Wp3, bns+512, bns+576,
                                                                F + (size_t)bbase*3072);
    }
    gemmrow_k<256,0><<<48, 256, 0, stream>>>(F, Wx0p, lb0, XP);
    lstm0_k<<<256, 512, 0, stream>>>(XP, Wh0p, h0g);
    gemmrow_k<128,1><<<48, 256, 0, stream>>>(h0g, Wx1p, lb1, ZP1);
    lstm1_k<<<256, 512, 0, stream>>>(ZP1, Wh1p, WoT, bout, out);
}

// Round 17
// 420.016 us; speedup vs baseline: 1.4617x; 1.3714x over previous
//
#include <hip/hip_runtime.h>
#include <hip/hip_bf16.h>
#include <math.h>
#include <stdint.h>

#define EPS 1e-5f
#define LEAK 0.01f
#define NEG_INF (-3.402823e38f)

typedef __attribute__((ext_vector_type(8))) short short8v;
typedef __attribute__((ext_vector_type(4))) float f32x4;

__device__ __forceinline__ float sigm(float x){ return 1.0f/(1.0f + __expf(-x)); }
__device__ __forceinline__ float tanhf_(float x){ return 1.0f - 2.0f/(__expf(2.0f*x)+1.0f); }
__device__ __forceinline__ float bnl(float a, float sc, float sh){
    float v = fmaf(a, sc, sh);
    return v < 0.0f ? LEAK*v : v;
}
__device__ __forceinline__ unsigned short f2bf(float f){
    __hip_bfloat16 h = __float2bfloat16(f);
    return *reinterpret_cast<unsigned short*>(&h);
}
__device__ __forceinline__ float bf2f(unsigned short u){
    return __uint_as_float(((unsigned)u) << 16);
}

// ---------- fused setup: all weight packs + BN folds in ONE launch ----------
// seg0: w1 pack (73728) blocks [0,288)
// seg1: w2 pack (147456) [288,864)
// seg2: w3 pack (73728) [864,1152)
// seg3: Wx0p (131072) [1152,1664)
// seg4: Wh0p (65536) [1664,1920)
// seg5: Wx1p (65536) [1920,2176)
// seg6: Wh1p (65536) [2176,2432)
// seg7: WoT (4736) [2432,2451)
// seg8: bn x4 (448) [2451,2453)
__global__ __launch_bounds__(256) void setup_k(
    const float* __restrict__ w1, const float* __restrict__ w2, const float* __restrict__ w3,
    const float* __restrict__ lW0, const float* __restrict__ lW1, const float* __restrict__ Wout,
    const float* __restrict__ cb0, const float* __restrict__ g0, const float* __restrict__ bb0,
    const float* __restrict__ mm0, const float* __restrict__ mv0,
    const float* __restrict__ cb1, const float* __restrict__ g1, const float* __restrict__ bb1,
    const float* __restrict__ mm1, const float* __restrict__ mv1,
    const float* __restrict__ cb2, const float* __restrict__ g2, const float* __restrict__ bb2,
    const float* __restrict__ mm2, const float* __restrict__ mv2,
    const float* __restrict__ cb3, const float* __restrict__ g3, const float* __restrict__ bb3,
    const float* __restrict__ mm3, const float* __restrict__ mv3,
    unsigned short* __restrict__ Wp1, unsigned short* __restrict__ Wp2, unsigned short* __restrict__ Wp3,
    unsigned short* __restrict__ Wx0p, unsigned short* __restrict__ Wh0p,
    unsigned short* __restrict__ Wx1p, unsigned short* __restrict__ Wh1p,
    unsigned short* __restrict__ WoT, float* __restrict__ bns)
{
    const int bid = blockIdx.x, tid = threadIdx.x;
    if (bid < 864){
        // conv packs
        const float* w; unsigned short* wp; int CIN, COUT, base;
        if (bid < 288){ w = w1; wp = Wp1; CIN=64; COUT=128; base = bid; }
        else if (bid < 864){ w = (bid<864&&bid>=288)? w2:w2; wp = Wp2; CIN=128; COUT=128; base = bid-288; }
        if (bid >= 864){}
        int t = base*256 + tid;
        if (bid >= 288 && bid < 864){ /* seg1 */ }
        int total = 9*CIN*COUT;
        if (t < total){
            int cout = t % COUT, k = t / COUT;
            wp[(size_t)(k>>3)*COUT*8 + (size_t)cout*8 + (k&7)] = f2bf(w[(size_t)k*COUT + cout]);
        }
        return;
    }
    if (bid < 1152){
        int t = (bid-864)*256 + tid;
        if (t < 73728){
            int cout = t % 64, k = t / 64;
            Wp3[(size_t)(k>>3)*64*8 + (size_t)cout*8 + (k&7)] = f2bf(w3[(size_t)k*64 + cout]);
        }
        return;
    }
    if (bid < 2432){
        // LSTM weight packs: dst[(k/8)][512][8]
        const float* src; unsigned short* dst; int base;
        if (bid < 1664){ src = lW0; dst = Wx0p; base = bid-1152; }
        else if (bid < 1920){ src = lW0 + 256*512; dst = Wh0p; base = bid-1664; }
        else if (bid < 2176){ src = lW1; dst = Wx1p; base = bid-1920; }
        else { src = lW1 + 128*512; dst = Wh1p; base = bid-2176; }
        int t = base*256 + tid;
        int k = t >> 9, col = t & 511;
        dst[(size_t)(k>>3)*4096 + col*8 + (k&7)] = f2bf(src[(size_t)k*512 + col]);
        return;
    }
    if (bid < 2451){
        int t = (bid-2432)*256 + tid;
        if (t < 4736){
            int n = t >> 7, k = t & 127;
            WoT[t] = f2bf(Wout[k*37 + n]);
        }
        return;
    }
    // bn folds: 4 layers. layer1->bns[0/128], layer2->bns[256/384], layer3->bns[512/576], layer0->bns[640/704]
    {
        int t = (bid-2451)*256 + tid;   // 0..511
        if (t < 128){
            float s = g1[t]*rsqrtf(mv1[t]+EPS);
            bns[t] = s; bns[128+t] = fmaf(cb1[t]-mm1[t], s, bb1[t]);
        } else if (t < 256){
            int u = t-128;
            float s = g2[u]*rsqrtf(mv2[u]+EPS);
            bns[256+u] = s; bns[384+u] = fmaf(cb2[u]-mm2[u], s, bb2[u]);
        } else if (t < 320){
            int u = t-256;
            float s = g3[u]*rsqrtf(mv3[u]+EPS);
            bns[512+u] = s; bns[576+u] = fmaf(cb3[u]-mm3[u], s, bb3[u]);
        } else if (t < 384){
            int u = t-320;
            float s = g0[u]*rsqrtf(mv0[u]+EPS);
            bns[640+u] = s; bns[704+u] = fmaf(cb0[u]-mm0[u], s, bb0[u]);
        }
        return;
    }
}

// ---------- conv block 0: thread = one pooled px, all 64 couts; weights in LDS ----------
__global__ __launch_bounds__(256) void conv0_k(
    const float* __restrict__ x, const float* __restrict__ w,
    const float* __restrict__ bsc, const float* __restrict__ bsh,
    unsigned short* __restrict__ out, int bbase, int total)
{
    __shared__ float wv[576];
    __shared__ float scs[64], shs[64];
    const int tid = threadIdx.x;
    for (int i=tid;i<576;i+=256) wv[i] = w[i];
    if (tid < 64){ scs[tid]=bsc[tid]; shs[tid]=bsh[tid]; }
    __syncthreads();
    const int id = blockIdx.x*256 + tid;
    if (id >= total) return;
    const int px = id % 90; int r = id / 90; const int py = r % 30; const int b0 = r / 30;
    const float* xb = x + (size_t)(bbase+b0)*10800;
    float p[4][4];
    const int y0 = 2*py-1, xx0 = 2*px-1;
#pragma unroll
    for (int rr=0;rr<4;rr++){
        int yy=y0+rr;
#pragma unroll
        for (int cc=0;cc<4;cc++){
            int xc=xx0+cc;
            p[rr][cc] = (yy>=0&&yy<60&&xc>=0&&xc<180)? xb[yy*180+xc] : 0.f;
        }
    }
    unsigned short* ob = out + (size_t)id*64;
#pragma unroll
    for (int cg=0;cg<8;cg++){
        short8v o8;
#pragma unroll
        for (int j=0;j<8;j++){
            const int co = cg*8+j;
            float s00=0.f,s01=0.f,s10=0.f,s11=0.f;
#pragma unroll
            for (int ky=0;ky<3;ky++)
#pragma unroll
            for (int kx=0;kx<3;kx++){
                float wt = wv[(ky*3+kx)*64+co];
                s00 = fmaf(p[ky][kx],     wt, s00);
                s01 = fmaf(p[ky][kx+1],   wt, s01);
                s10 = fmaf(p[ky+1][kx],   wt, s10);
                s11 = fmaf(p[ky+1][kx+1], wt, s11);
            }
            float sc=scs[co], sh=shs[co];
            float m = fmaxf(fmaxf(bnl(s00,sc,sh),bnl(s01,sc,sh)),
                            fmaxf(bnl(s10,sc,sh),bnl(s11,sc,sh)));
            o8[j] = (short)f2bf(m);
        }
        *(short8v*)&ob[cg*8] = o8;
    }
}

// ---------- MFMA fused conv+BN+leaky+pool (r14 config + setprio) ----------
// Tile: 8 rows x 16 cols x 1 batch. 4 waves = 4 row-pairs, full COUT per wave.
// JIT A-loads, global_load_lds W staging, (256,4) for ~4 waves/SIMD.
template<int CIN,int COUT,int H,int W>
__global__ __launch_bounds__(256,4) void convmf_k(
    const unsigned short* __restrict__ in, const unsigned short* __restrict__ wp,
    const float* __restrict__ bsc, const float* __restrict__ bsh,
    unsigned short* __restrict__ out)
{
    constexpr int PH=(H+1)/2, PW=(W+1)/2;
    constexpr int HALVES = CIN/64;
    constexpr int NIT = 9*HALVES;          // BK=64 iterations
    constexpr int NREP = COUT/16;
    constexpr int CH = (64*COUT)/(256*8);  // 16B chunks per thread per K-tile
    __shared__ alignas(16) unsigned short wls[2][64*COUT];

    const int tid = threadIdx.x;
    const int lane = tid & 63;
    const int wm = tid >> 6;               // row-pair
    const int l15 = lane & 15, l4 = lane >> 4;
    const int x0 = blockIdx.x*16, y0 = blockIdx.y*8;
    const int b = blockIdx.z;
    const unsigned short* inb = in + (size_t)b*H*W*CIN;

    int rowoff[4]; bool rowok[4];
#pragma unroll
    for (int j=0;j<4;j++){
        int gy = y0 + 2*wm - 1 + j;
        rowok[j] = (unsigned)gy < (unsigned)H;
        rowoff[j] = (rowok[j] ? gy : 0) * (W*CIN);
    }
    int coloff[3]; bool colok[3];
#pragma unroll
    for (int kx=0;kx<3;kx++){
        int gx = x0 + l15 + kx - 1;
        colok[kx] = (unsigned)gx < (unsigned)W;
        coloff[kx] = (colok[kx] ? gx : 0) * CIN;
    }

    f32x4 acc[2][NREP];
#pragma unroll
    for (int m=0;m<2;m++)
#pragma unroll
    for (int n=0;n<NREP;n++) acc[m][n] = f32x4{0.f,0.f,0.f,0.f};

    auto stageB = [&](int it, int buf){
        const unsigned short* src = wp + (size_t)(it*8)*(COUT*8);
#pragma unroll
        for (int i=0;i<CH;i++){
            const unsigned short* g = src + (size_t)(tid + i*256)*8;
            unsigned short* l = &wls[buf][((tid & ~63) + i*256)*8];
            __builtin_amdgcn_global_load_lds(
                (const __attribute__((address_space(1))) unsigned int*)(uintptr_t)g,
                (__attribute__((address_space(3))) unsigned int*)(uintptr_t)l,
                16, 0, 0);
        }
    };

    stageB(0, 0);
    __syncthreads();

    for (int it=0; it<NIT; ++it){
        if (it+1 < NIT) stageB(it+1, (it+1)&1);
        const int tap = it / HALVES;
        const int khalf = it - tap*HALVES;
        const int ky = tap/3, kx = tap - ky*3;
        const int cin0 = khalf*64 + l4*8;
        const short8v z8 = short8v{0,0,0,0,0,0,0,0};
        short8v a[2][2];
#pragma unroll
        for (int rf=0;rf<2;rf++){
            const int j = rf + ky;
            const bool ok = rowok[j] && colok[kx];
            const unsigned short* p = inb + rowoff[j] + coloff[kx] + cin0;
#pragma unroll
            for (int ks=0;ks<2;ks++){
                short8v v = *(const short8v*)(p + ks*32);
                a[rf][ks] = ok ? v : z8;
            }
        }
        const unsigned short* wb = &wls[it&1][0];
        __builtin_amdgcn_s_setprio(1);
#pragma unroll
        for (int ks=0; ks<2; ++ks){
#pragma unroll
            for (int nf=0; nf<NREP; ++nf){
                short8v bfr = *(const short8v*)&wb[((ks*4+l4)*COUT + nf*16 + l15)*8];
                acc[0][nf] = __builtin_amdgcn_mfma_f32_16x16x32_bf16(a[0][ks], bfr, acc[0][nf],0,0,0);
                acc[1][nf] = __builtin_amdgcn_mfma_f32_16x16x32_bf16(a[1][ks], bfr, acc[1][nf],0,0,0);
            }
        }
        __builtin_amdgcn_s_setprio(0);
        __syncthreads();
    }

    const int pr = (y0>>1) + wm;
    if (pr < PH){
        const bool r1 = (y0 + 2*wm + 1) < H;
        unsigned short* ob = out + ((size_t)b*PH + pr)*PW*COUT;
#pragma unroll
        for (int nf=0; nf<NREP; ++nf){
            const int co = nf*16 + l15;
            const float scv = bsc[co], shv = bsh[co];
            f32x4 e = acc[0][nf], o = acc[1][nf];
#pragma unroll
            for (int pp=0; pp<2; ++pp){
                const int pc = (x0>>1) + l4*2 + pp;
                if (pc >= PW) continue;
                const int oddcol = x0 + l4*4 + 2*pp + 1;
                float m = bnl(e[2*pp], scv, shv);
                if (oddcol < W) m = fmaxf(m, bnl(e[2*pp+1], scv, shv));
                if (r1){
                    m = fmaxf(m, bnl(o[2*pp], scv, shv));
                    if (oddcol < W) m = fmaxf(m, bnl(o[2*pp+1], scv, shv));
                }
                ob[(size_t)pc*COUT + co] = f2bf(m);
            }
        }
    }
}

// ---------- MFMA row-GEMM: out[3072][512] = A @ W + bias ----------
template<int K, int MODE>
__global__ __launch_bounds__(256) void gemmrow_k(
    const unsigned short* __restrict__ A, const unsigned short* __restrict__ wp,
    const float* __restrict__ bias, float* __restrict__ out)
{
    constexpr int NS = K/32;
    __shared__ alignas(16) unsigned short wls[2][16384];
    const int tid = threadIdx.x, lane = tid & 63, w = tid >> 6;
    const int l15 = lane & 15, l4 = lane >> 4;
    const int r0 = blockIdx.x*64;

    f32x4 acc[4][8];
#pragma unroll
    for (int m=0;m<4;m++)
#pragma unroll
    for (int n=0;n<8;n++) acc[m][n] = f32x4{0.f,0.f,0.f,0.f};

    auto stage = [&](int s, int buf){
        const unsigned short* src = wp + (size_t)s*16384;
#pragma unroll
        for (int i=0;i<8;i++){
            int e = (tid + i*256)*8;
            *(short8v*)&wls[buf][e] = *(const short8v*)&src[e];
        }
    };
    stage(0,0);
    __syncthreads();

    for (int s=0;s<NS;++s){
        const int k0 = s*32 + l4*8;
        short8v af[4];
#pragma unroll
        for (int mf=0;mf<4;++mf){
            const int row = r0 + mf*16 + l15;
            size_t idx;
            if constexpr (MODE == 0){
                const int b = row & 255, t = row >> 8;
                idx = (size_t)b*3072 + (k0>>6)*768 + t*64 + (k0&63);
            } else {
                idx = (size_t)row*K + k0;
            }
            af[mf] = *(const short8v*)&A[idx];
        }
        if (s+1 < NS) stage(s+1,(s+1)&1);
        const unsigned short* wb = &wls[s&1][0];
#pragma unroll
        for (int nf=0;nf<8;++nf){
            const int col = w*128 + nf*16 + l15;
            short8v bfr = *(const short8v*)&wb[(l4*512 + col)*8];
#pragma unroll
            for (int mf=0;mf<4;++mf)
                acc[mf][nf] = __builtin_amdgcn_mfma_f32_16x16x32_bf16(af[mf], bfr, acc[mf][nf], 0,0,0);
        }
        __syncthreads();
    }
#pragma unroll
    for (int nf=0;nf<8;++nf){
        const int col = w*128 + nf*16 + l15;
        const float bv = bias[col];
#pragma unroll
        for (int mf=0;mf<4;++mf){
#pragma unroll
            for (int j=0;j<4;++j){
                const int row = r0 + mf*16 + l4*4 + j;
                out[(size_t)row*512 + col] = acc[mf][nf][j] + bv;
            }
        }
    }
}

// ---------- layer-0 LSTM: Wh0 LDS-resident, 256 blocks x 1 batch ----------
__global__ __launch_bounds__(512) void lstm0_k(
    const float* __restrict__ xp, const unsigned short* __restrict__ wh0p,
    unsigned short* __restrict__ h0g)
{
    __shared__ alignas(16) unsigned short wl[65536];   // 128 KB
    __shared__ alignas(16) float hb[128];
    __shared__ float zs[512];
    const int col = threadIdx.x;
    const int b = blockIdx.x;
#pragma unroll
    for (int i=0;i<16;i++){
        int e = (col + i*512)*8;
        *(short8v*)&wl[e] = *(const short8v*)&wh0p[e];
    }
    if (col < 128) hb[col] = 0.f;
    float c0 = 0.f;
    __syncthreads();

    for (int t=0;t<12;t++){
        float acc = xp[((size_t)t*256 + b)*512 + col];
#pragma unroll 4
        for (int kg=0;kg<16;kg++){
            short8v w8 = *(const short8v*)&wl[(kg*512 + col)*8];
            float4 hlo = *(const float4*)&hb[kg*8];
            float4 hhi = *(const float4*)&hb[kg*8+4];
            acc = fmaf(bf2f((unsigned short)w8[0]), hlo.x, acc);
            acc = fmaf(bf2f((unsigned short)w8[1]), hlo.y, acc);
            acc = fmaf(bf2f((unsigned short)w8[2]), hlo.z, acc);
            acc = fmaf(bf2f((unsigned short)w8[3]), hlo.w, acc);
            acc = fmaf(bf2f((unsigned short)w8[4]), hhi.x, acc);
            acc = fmaf(bf2f((unsigned short)w8[5]), hhi.y, acc);
            acc = fmaf(bf2f((unsigned short)w8[6]), hhi.z, acc);
            acc = fmaf(bf2f((unsigned short)w8[7]), hhi.w, acc);
        }
        zs[col] = acc;
        __syncthreads();
        if (col < 128){
            float zi=zs[col], zj=zs[128+col], zf=zs[256+col], zo=zs[384+col];
            c0 = c0*sigm(zf+1.f) + sigm(zi)*tanhf_(zj);
            float h = tanhf_(c0)*sigm(zo);
            hb[col] = h;
            h0g[((size_t)t*256 + b)*128 + col] = f2bf(h);
        }
        __syncthreads();
    }
}

// ---------- layer-1 LSTM + projection: Wh1 LDS-resident, 256 blocks x 1 batch ----------
__global__ __launch_bounds__(512) void lstm1_k(
    const float* __restrict__ zp1, const unsigned short* __restrict__ wh1p,
    const unsigned short* __restrict__ woT, const float* __restrict__ bout,
    float* __restrict__ out)
{
    __shared__ alignas(16) unsigned short wl[65536];   // 128 KB
    __shared__ alignas(16) float hb[128];
    __shared__ float zs[512];
    __shared__ float red[37][8];
    const int col = threadIdx.x;
    const int b = blockIdx.x;
#pragma unroll
    for (int i=0;i<16;i++){
        int e = (col + i*512)*8;
        *(short8v*)&wl[e] = *(const short8v*)&wh1p[e];
    }
    if (col < 128) hb[col] = 0.f;
    float c1 = 0.f;
    __syncthreads();

    for (int t=0;t<12;t++){
        float acc = zp1[((size_t)t*256 + b)*512 + col];
#pragma unroll 4
        for (int kg=0;kg<16;kg++){
            short8v w8 = *(const short8v*)&wl[(kg*512 + col)*8];
            float4 hlo = *(const float4*)&hb[kg*8];
            float4 hhi = *(const float4*)&hb[kg*8+4];
            acc = fmaf(bf2f((unsigned short)w8[0]), hlo.x, acc);
            acc = fmaf(bf2f((unsigned short)w8[1]), hlo.y, acc);
            acc = fmaf(bf2f((unsigned short)w8[2]), hlo.z, acc);
            acc = fmaf(bf2f((unsigned short)w8[3]), hlo.w, acc);
            acc = fmaf(bf2f((unsigned short)w8[4]), hhi.x, acc);
            acc = fmaf(bf2f((unsigned short)w8[5]), hhi.y, acc);
            acc = fmaf(bf2f((unsigned short)w8[6]), hhi.z, acc);
            acc = fmaf(bf2f((unsigned short)w8[7]), hhi.w, acc);
        }
        zs[col] = acc;
        __syncthreads();
        if (col < 128){
            float zi=zs[col], zj=zs[128+col], zf=zs[256+col], zo=zs[384+col];
            c1 = c1*sigm(zf+1.f) + sigm(zi)*tanhf_(zj);
            hb[col] = tanhf_(c1)*sigm(zo);
        }
        __syncthreads();
        if (col < 296){
            const int n = col >> 3, q = col & 7;
            float p0 = 0.f;
#pragma unroll
            for (int kk=0;kk<16;kk++){
                float wv2 = bf2f(woT[n*128 + q*16 + kk]);
                p0 = fmaf(hb[q*16+kk], wv2, p0);
            }
            red[n][q] = p0;
        }
        __syncthreads();
        if (col < 37){
            float s0 = bout[col];
#pragma unroll
            for (int q=0;q<8;q++) s0 += red[col][q];
            out[((size_t)t*256 + b)*37 + col] = s0;
        }
        __syncthreads();
    }
}

extern "C" void kernel_launch(void* const* d_in, const int* in_sizes, int n_in,
                              void* d_out, int out_size, void* d_ws, size_t ws_size,
                              hipStream_t stream) {
    const float* x = (const float*)d_in[0];
    const float *w_[4], *cb_[4], *g_[4], *bb_[4], *mm_[4], *mv_[4];
    for (int i=0;i<4;i++){
        w_[i]  = (const float*)d_in[1+6*i];
        cb_[i] = (const float*)d_in[2+6*i];
        g_[i]  = (const float*)d_in[3+6*i];
        bb_[i] = (const float*)d_in[4+6*i];
        mm_[i] = (const float*)d_in[5+6*i];
        mv_[i] = (const float*)d_in[6+6*i];
    }
    const float* lW0  = (const float*)d_in[25];
    const float* lb0  = (const float*)d_in[26];
    const float* lW1  = (const float*)d_in[27];
    const float* lb1  = (const float*)d_in[28];
    const float* Wout = (const float*)d_in[29];
    const float* bout = (const float*)d_in[30];
    float* out = (float*)d_out;

    const size_t fixed = 6291456ull + 6291456 + 4096 + 1572864 + 786432
                       + 147456 + 294912 + 147456
                       + 262144 + 131072 + 131072 + 131072 + 9472;
    int Bc = 256;
    while (Bc > 8 && fixed + (size_t)Bc*565504 > ws_size) Bc >>= 1;

    char* cur = (char*)d_ws;
    float* XP  = (float*)cur;                    cur += 6291456;
    float* ZP1 = (float*)cur;                    cur += 6291456;
    float* bns = (float*)cur;                    cur += 4096;
    unsigned short* F    = (unsigned short*)cur; cur += 1572864;
    unsigned short* h0g  = (unsigned short*)cur; cur += 786432;
    unsigned short* Wp1  = (unsigned short*)cur; cur += 147456;
    unsigned short* Wp2  = (unsigned short*)cur; cur += 294912;
    unsigned short* Wp3  = (unsigned short*)cur; cur += 147456;
    unsigned short* Wx0p = (unsigned short*)cur; cur += 262144;
    unsigned short* Wh0p = (unsigned short*)cur; cur += 131072;
    unsigned short* Wx1p = (unsigned short*)cur; cur += 131072;
    unsigned short* Wh1p = (unsigned short*)cur; cur += 131072;
    unsigned short* WoT  = (unsigned short*)cur; cur += 9472;
    unsigned short* A    = (unsigned short*)cur; cur += (size_t)Bc*345600;
    unsigned short* Bb   = (unsigned short*)cur; cur += (size_t)Bc*172800;
    unsigned short* C    = (unsigned short*)cur;

    setup_k<<<2453, 256, 0, stream>>>(
        w_[1], w_[2], w_[3], lW0, lW1, Wout,
        cb_[0],g_[0],bb_[0],mm_[0],mv_[0],
        cb_[1],g_[1],bb_[1],mm_[1],mv_[1],
        cb_[2],g_[2],bb_[2],mm_[2],mv_[2],
        cb_[3],g_[3],bb_[3],mm_[3],mv_[3],
        Wp1, Wp2, Wp3, Wx0p, Wh0p, Wx1p, Wh1p, WoT, bns);

    const int nc = 256 / Bc;
    for (int bc=0; bc<nc; bc++){
        int bbase = bc*Bc;
        conv0_k<<<(Bc*2700+255)/256, 256, 0, stream>>>(x, w_[0], bns+640, bns+704, A, bbase, Bc*2700);
        convmf_k<64,128,30,90><<<dim3(6,4,Bc), 256, 0, stream>>>(A, Wp1, bns+0, bns+128, Bb);
        convmf_k<128,128,15,45><<<dim3(3,2,Bc), 256, 0, stream>>>(Bb, Wp2, bns+256, bns+384, C);
        convmf_k<128,64,8,23><<<dim3(2,1,Bc), 256, 0, stream>>>(C, Wp3, bns+512, bns+576,
                                                                F + (size_t)bbase*3072);
    }
    gemmrow_k<256,0><<<48, 256, 0, stream>>>(F, Wx0p, lb0, XP);
    lstm0_k<<<256, 512, 0, stream>>>(XP, Wh0p, h0g);
    gemmrow_k<128,1><<<48, 256, 0, stream>>>(h0g, Wx1p, lb1, ZP1);
    lstm1_k<<<256, 512, 0, stream>>>(ZP1, Wh1p, WoT, bout, out);
}

// Round 18
// 412.379 us; speedup vs baseline: 1.4888x; 1.0185x over previous
//
#include <hip/hip_runtime.h>
#include <hip/hip_bf16.h>
#include <math.h>
#include <stdint.h>

#define EPS 1e-5f
#define LEAK 0.01f
#define NEG_INF (-3.402823e38f)

typedef __attribute__((ext_vector_type(8))) short short8v;
typedef __attribute__((ext_vector_type(4))) float f32x4;

__device__ __forceinline__ float sigm(float x){ return 1.0f/(1.0f + __expf(-x)); }
__device__ __forceinline__ float tanhf_(float x){ return 1.0f - 2.0f/(__expf(2.0f*x)+1.0f); }
__device__ __forceinline__ float bnl(float a, float sc, float sh){
    float v = fmaf(a, sc, sh);
    return v < 0.0f ? LEAK*v : v;
}
__device__ __forceinline__ unsigned short f2bf(float f){
    __hip_bfloat16 h = __float2bfloat16(f);
    return *reinterpret_cast<unsigned short*>(&h);
}
__device__ __forceinline__ float bf2f(unsigned short u){
    return __uint_as_float(((unsigned)u) << 16);
}

// ---------- fused setup: all weight packs + BN folds in ONE launch ----------
__global__ __launch_bounds__(256) void setup_k(
    const float* __restrict__ w1, const float* __restrict__ w2, const float* __restrict__ w3,
    const float* __restrict__ lW0, const float* __restrict__ lW1, const float* __restrict__ Wout,
    const float* __restrict__ cb0, const float* __restrict__ g0, const float* __restrict__ bb0,
    const float* __restrict__ mm0, const float* __restrict__ mv0,
    const float* __restrict__ cb1, const float* __restrict__ g1, const float* __restrict__ bb1,
    const float* __restrict__ mm1, const float* __restrict__ mv1,
    const float* __restrict__ cb2, const float* __restrict__ g2, const float* __restrict__ bb2,
    const float* __restrict__ mm2, const float* __restrict__ mv2,
    const float* __restrict__ cb3, const float* __restrict__ g3, const float* __restrict__ bb3,
    const float* __restrict__ mm3, const float* __restrict__ mv3,
    unsigned short* __restrict__ Wp1, unsigned short* __restrict__ Wp2, unsigned short* __restrict__ Wp3,
    unsigned short* __restrict__ Wx0p, unsigned short* __restrict__ Wh0p,
    unsigned short* __restrict__ Wx1p, unsigned short* __restrict__ Wh1p,
    unsigned short* __restrict__ WoT, float* __restrict__ bns)
{
    const int bid = blockIdx.x, tid = threadIdx.x;
    if (bid < 864){
        const float* w; unsigned short* wp; int CIN, COUT, base;
        if (bid < 288){ w = w1; wp = Wp1; CIN=64; COUT=128; base = bid; }
        else { w = w2; wp = Wp2; CIN=128; COUT=128; base = bid-288; }
        int t = base*256 + tid;
        int total = 9*CIN*COUT;
        if (t < total){
            int cout = t % COUT, k = t / COUT;
            wp[(size_t)(k>>3)*COUT*8 + (size_t)cout*8 + (k&7)] = f2bf(w[(size_t)k*COUT + cout]);
        }
        return;
    }
    if (bid < 1152){
        int t = (bid-864)*256 + tid;
        if (t < 73728){
            int cout = t % 64, k = t / 64;
            Wp3[(size_t)(k>>3)*64*8 + (size_t)cout*8 + (k&7)] = f2bf(w3[(size_t)k*64 + cout]);
        }
        return;
    }
    if (bid < 2432){
        const float* src; unsigned short* dst; int base;
        if (bid < 1664){ src = lW0; dst = Wx0p; base = bid-1152; }
        else if (bid < 1920){ src = lW0 + 256*512; dst = Wh0p; base = bid-1664; }
        else if (bid < 2176){ src = lW1; dst = Wx1p; base = bid-1920; }
        else { src = lW1 + 128*512; dst = Wh1p; base = bid-2176; }
        int t = base*256 + tid;
        int k = t >> 9, col = t & 511;
        dst[(size_t)(k>>3)*4096 + col*8 + (k&7)] = f2bf(src[(size_t)k*512 + col]);
        return;
    }
    if (bid < 2451){
        int t = (bid-2432)*256 + tid;
        if (t < 4736){
            int n = t >> 7, k = t & 127;
            WoT[t] = f2bf(Wout[k*37 + n]);
        }
        return;
    }
    {
        int t = (bid-2451)*256 + tid;
        if (t < 128){
            float s = g1[t]*rsqrtf(mv1[t]+EPS);
            bns[t] = s; bns[128+t] = fmaf(cb1[t]-mm1[t], s, bb1[t]);
        } else if (t < 256){
            int u = t-128;
            float s = g2[u]*rsqrtf(mv2[u]+EPS);
            bns[256+u] = s; bns[384+u] = fmaf(cb2[u]-mm2[u], s, bb2[u]);
        } else if (t < 320){
            int u = t-256;
            float s = g3[u]*rsqrtf(mv3[u]+EPS);
            bns[512+u] = s; bns[576+u] = fmaf(cb3[u]-mm3[u], s, bb3[u]);
        } else if (t < 384){
            int u = t-320;
            float s = g0[u]*rsqrtf(mv0[u]+EPS);
            bns[640+u] = s; bns[704+u] = fmaf(cb0[u]-mm0[u], s, bb0[u]);
        }
        return;
    }
}

// ---------- conv block 0: thread = one pooled px, all 64 couts; weights in LDS ----------
__global__ __launch_bounds__(256) void conv0_k(
    const float* __restrict__ x, const float* __restrict__ w,
    const float* __restrict__ bsc, const float* __restrict__ bsh,
    unsigned short* __restrict__ out, int bbase, int total)
{
    __shared__ float wv[576];
    __shared__ float scs[64], shs[64];
    const int tid = threadIdx.x;
    for (int i=tid;i<576;i+=256) wv[i] = w[i];
    if (tid < 64){ scs[tid]=bsc[tid]; shs[tid]=bsh[tid]; }
    __syncthreads();
    const int id = blockIdx.x*256 + tid;
    if (id >= total) return;
    const int px = id % 90; int r = id / 90; const int py = r % 30; const int b0 = r / 30;
    const float* xb = x + (size_t)(bbase+b0)*10800;
    float p[4][4];
    const int y0 = 2*py-1, xx0 = 2*px-1;
#pragma unroll
    for (int rr=0;rr<4;rr++){
        int yy=y0+rr;
#pragma unroll
        for (int cc=0;cc<4;cc++){
            int xc=xx0+cc;
            p[rr][cc] = (yy>=0&&yy<60&&xc>=0&&xc<180)? xb[yy*180+xc] : 0.f;
        }
    }
    unsigned short* ob = out + (size_t)id*64;
#pragma unroll
    for (int cg=0;cg<8;cg++){
        short8v o8;
#pragma unroll
        for (int j=0;j<8;j++){
            const int co = cg*8+j;
            float s00=0.f,s01=0.f,s10=0.f,s11=0.f;
#pragma unroll
            for (int ky=0;ky<3;ky++)
#pragma unroll
            for (int kx=0;kx<3;kx++){
                float wt = wv[(ky*3+kx)*64+co];
                s00 = fmaf(p[ky][kx],     wt, s00);
                s01 = fmaf(p[ky][kx+1],   wt, s01);
                s10 = fmaf(p[ky+1][kx],   wt, s10);
                s11 = fmaf(p[ky+1][kx+1], wt, s11);
            }
            float sc=scs[co], sh=shs[co];
            float m = fmaxf(fmaxf(bnl(s00,sc,sh),bnl(s01,sc,sh)),
                            fmaxf(bnl(s10,sc,sh),bnl(s11,sc,sh)));
            o8[j] = (short)f2bf(m);
        }
        *(short8v*)&ob[cg*8] = o8;
    }
}

// ---------- MFMA fused conv+BN+leaky+pool: r14 tile + triple-buffer counted-vmcnt ----------
// Tile: 8 rows x 16 cols x 1 batch. 4 waves = 4 row-pairs, full COUT per wave.
// Triple-buffered DMA weight staging; raw s_barrier (no drain); stage(it+2) stays
// in flight across the barrier — the compiler's precise A-wait completes all older loads.
template<int CIN,int COUT,int H,int W>
__global__ __launch_bounds__(256,4) void convmf_k(
    const unsigned short* __restrict__ in, const unsigned short* __restrict__ wp,
    const float* __restrict__ bsc, const float* __restrict__ bsh,
    unsigned short* __restrict__ out)
{
    constexpr int PH=(H+1)/2, PW=(W+1)/2;
    constexpr int HALVES = CIN/64;
    constexpr int NIT = 9*HALVES;          // BK=64 iterations
    constexpr int NREP = COUT/16;
    constexpr int CH = (64*COUT)/(256*8);  // 16B DMA chunks per thread per K-tile
    __shared__ alignas(16) unsigned short wls[3][64*COUT];

    const int tid = threadIdx.x;
    const int lane = tid & 63;
    const int wm = tid >> 6;               // row-pair
    const int l15 = lane & 15, l4 = lane >> 4;
    const int x0 = blockIdx.x*16, y0 = blockIdx.y*8;
    const int b = blockIdx.z;
    const unsigned short* inb = in + (size_t)b*H*W*CIN;

    int rowoff[4]; bool rowok[4];
#pragma unroll
    for (int j=0;j<4;j++){
        int gy = y0 + 2*wm - 1 + j;
        rowok[j] = (unsigned)gy < (unsigned)H;
        rowoff[j] = (rowok[j] ? gy : 0) * (W*CIN);
    }
    int coloff[3]; bool colok[3];
#pragma unroll
    for (int kx=0;kx<3;kx++){
        int gx = x0 + l15 + kx - 1;
        colok[kx] = (unsigned)gx < (unsigned)W;
        coloff[kx] = (colok[kx] ? gx : 0) * CIN;
    }

    f32x4 acc[2][NREP];
#pragma unroll
    for (int m=0;m<2;m++)
#pragma unroll
    for (int n=0;n<NREP;n++) acc[m][n] = f32x4{0.f,0.f,0.f,0.f};

    auto stageB = [&](int it, int buf){
        const unsigned short* src = wp + (size_t)(it*8)*(COUT*8);
#pragma unroll
        for (int i=0;i<CH;i++){
            const unsigned short* g = src + (size_t)(tid + i*256)*8;
            unsigned short* l = &wls[buf][((tid & ~63) + i*256)*8];
            __builtin_amdgcn_global_load_lds(
                (const __attribute__((address_space(1))) unsigned int*)(uintptr_t)g,
                (__attribute__((address_space(3))) unsigned int*)(uintptr_t)l,
                16, 0, 0);
        }
    };

    // prologue: stage tiles 0 and 1; wait only for tile 0 (tile 1 stays in flight)
    stageB(0, 0);
    if (NIT > 1) stageB(1, 1);
    if constexpr (CH == 4){ asm volatile("s_waitcnt vmcnt(4)" ::: "memory"); }
    else                  { asm volatile("s_waitcnt vmcnt(2)" ::: "memory"); }
    __builtin_amdgcn_sched_barrier(0);
    __builtin_amdgcn_s_barrier();

    for (int it=0; it<NIT; ++it){
        // JIT A-load for this K-tile (issued BEFORE next stage so stage is newest)
        const int tap = it / HALVES;
        const int khalf = it - tap*HALVES;
        const int ky = tap/3, kx = tap - ky*3;
        const int cin0 = khalf*64 + l4*8;
        const short8v z8 = short8v{0,0,0,0,0,0,0,0};
        short8v a[2][2];
#pragma unroll
        for (int rf=0;rf<2;rf++){
            const int j = rf + ky;
            const bool ok = rowok[j] && colok[kx];
            const unsigned short* p = inb + rowoff[j] + coloff[kx] + cin0;
#pragma unroll
            for (int ks=0;ks<2;ks++){
                short8v v = *(const short8v*)(p + ks*32);
                a[rf][ks] = ok ? v : z8;
            }
        }
        __builtin_amdgcn_sched_barrier(0);
        if (it+2 < NIT) stageB(it+2, (it+2)%3);
        __builtin_amdgcn_sched_barrier(0);
        // compiler's pre-MFMA wait for a[] completes stage(it+1) (older) too;
        // stage(it+2) (newest) stays in flight across the barrier.
        const unsigned short* wb = &wls[it%3][0];
        __builtin_amdgcn_s_setprio(1);
#pragma unroll
        for (int ks=0; ks<2; ++ks){
#pragma unroll
            for (int nf=0; nf<NREP; ++nf){
                short8v bfr = *(const short8v*)&wb[((ks*4+l4)*COUT + nf*16 + l15)*8];
                acc[0][nf] = __builtin_amdgcn_mfma_f32_16x16x32_bf16(a[0][ks], bfr, acc[0][nf],0,0,0);
                acc[1][nf] = __builtin_amdgcn_mfma_f32_16x16x32_bf16(a[1][ks], bfr, acc[1][nf],0,0,0);
            }
        }
        __builtin_amdgcn_s_setprio(0);
        __builtin_amdgcn_s_barrier();
    }

    const int pr = (y0>>1) + wm;
    if (pr < PH){
        const bool r1 = (y0 + 2*wm + 1) < H;
        unsigned short* ob = out + ((size_t)b*PH + pr)*PW*COUT;
#pragma unroll
        for (int nf=0; nf<NREP; ++nf){
            const int co = nf*16 + l15;
            const float scv = bsc[co], shv = bsh[co];
            f32x4 e = acc[0][nf], o = acc[1][nf];
#pragma unroll
            for (int pp=0; pp<2; ++pp){
                const int pc = (x0>>1) + l4*2 + pp;
                if (pc >= PW) continue;
                const int oddcol = x0 + l4*4 + 2*pp + 1;
                float m = bnl(e[2*pp], scv, shv);
                if (oddcol < W) m = fmaxf(m, bnl(e[2*pp+1], scv, shv));
                if (r1){
                    m = fmaxf(m, bnl(o[2*pp], scv, shv));
                    if (oddcol < W) m = fmaxf(m, bnl(o[2*pp+1], scv, shv));
                }
                ob[(size_t)pc*COUT + co] = f2bf(m);
            }
        }
    }
}

// ---------- MFMA row-GEMM: out[3072][512] = A @ W + bias ----------
template<int K, int MODE>
__global__ __launch_bounds__(256) void gemmrow_k(
    const unsigned short* __restrict__ A, const unsigned short* __restrict__ wp,
    const float* __restrict__ bias, float* __restrict__ out)
{
    constexpr int NS = K/32;
    __shared__ alignas(16) unsigned short wls[2][16384];
    const int tid = threadIdx.x, lane = tid & 63, w = tid >> 6;
    const int l15 = lane & 15, l4 = lane >> 4;
    const int r0 = blockIdx.x*64;

    f32x4 acc[4][8];
#pragma unroll
    for (int m=0;m<4;m++)
#pragma unroll
    for (int n=0;n<8;n++) acc[m][n] = f32x4{0.f,0.f,0.f,0.f};

    auto stage = [&](int s, int buf){
        const unsigned short* src = wp + (size_t)s*16384;
#pragma unroll
        for (int i=0;i<8;i++){
            int e = (tid + i*256)*8;
            *(short8v*)&wls[buf][e] = *(const short8v*)&src[e];
        }
    };
    stage(0,0);
    __syncthreads();

    for (int s=0;s<NS;++s){
        const int k0 = s*32 + l4*8;
        short8v af[4];
#pragma unroll
        for (int mf=0;mf<4;++mf){
            const int row = r0 + mf*16 + l15;
            size_t idx;
            if constexpr (MODE == 0){
                const int b = row & 255, t = row >> 8;
                idx = (size_t)b*3072 + (k0>>6)*768 + t*64 + (k0&63);
            } else {
                idx = (size_t)row*K + k0;
            }
            af[mf] = *(const short8v*)&A[idx];
        }
        if (s+1 < NS) stage(s+1,(s+1)&1);
        const unsigned short* wb = &wls[s&1][0];
#pragma unroll
        for (int nf=0;nf<8;++nf){
            const int col = w*128 + nf*16 + l15;
            short8v bfr = *(const short8v*)&wb[(l4*512 + col)*8];
#pragma unroll
            for (int mf=0;mf<4;++mf)
                acc[mf][nf] = __builtin_amdgcn_mfma_f32_16x16x32_bf16(af[mf], bfr, acc[mf][nf], 0,0,0);
        }
        __syncthreads();
    }
#pragma unroll
    for (int nf=0;nf<8;++nf){
        const int col = w*128 + nf*16 + l15;
        const float bv = bias[col];
#pragma unroll
        for (int mf=0;mf<4;++mf){
#pragma unroll
            for (int j=0;j<4;++j){
                const int row = r0 + mf*16 + l4*4 + j;
                out[(size_t)row*512 + col] = acc[mf][nf][j] + bv;
            }
        }
    }
}

// ---------- layer-0 LSTM: Wh0 LDS-resident, 256 blocks x 1 batch ----------
__global__ __launch_bounds__(512) void lstm0_k(
    const float* __restrict__ xp, const unsigned short* __restrict__ wh0p,
    unsigned short* __restrict__ h0g)
{
    __shared__ alignas(16) unsigned short wl[65536];   // 128 KB
    __shared__ alignas(16) float hb[128];
    __shared__ float zs[512];
    const int col = threadIdx.x;
    const int b = blockIdx.x;
#pragma unroll
    for (int i=0;i<16;i++){
        int e = (col + i*512)*8;
        *(short8v*)&wl[e] = *(const short8v*)&wh0p[e];
    }
    if (col < 128) hb[col] = 0.f;
    float c0 = 0.f;
    __syncthreads();

    for (int t=0;t<12;t++){
        float acc = xp[((size_t)t*256 + b)*512 + col];
#pragma unroll 4
        for (int kg=0;kg<16;kg++){
            short8v w8 = *(const short8v*)&wl[(kg*512 + col)*8];
            float4 hlo = *(const float4*)&hb[kg*8];
            float4 hhi = *(const float4*)&hb[kg*8+4];
            acc = fmaf(bf2f((unsigned short)w8[0]), hlo.x, acc);
            acc = fmaf(bf2f((unsigned short)w8[1]), hlo.y, acc);
            acc = fmaf(bf2f((unsigned short)w8[2]), hlo.z, acc);
            acc = fmaf(bf2f((unsigned short)w8[3]), hlo.w, acc);
            acc = fmaf(bf2f((unsigned short)w8[4]), hhi.x, acc);
            acc = fmaf(bf2f((unsigned short)w8[5]), hhi.y, acc);
            acc = fmaf(bf2f((unsigned short)w8[6]), hhi.z, acc);
            acc = fmaf(bf2f((unsigned short)w8[7]), hhi.w, acc);
        }
        zs[col] = acc;
        __syncthreads();
        if (col < 128){
            float zi=zs[col], zj=zs[128+col], zf=zs[256+col], zo=zs[384+col];
            c0 = c0*sigm(zf+1.f) + sigm(zi)*tanhf_(zj);
            float h = tanhf_(c0)*sigm(zo);
            hb[col] = h;
            h0g[((size_t)t*256 + b)*128 + col] = f2bf(h);
        }
        __syncthreads();
    }
}

// ---------- layer-1 LSTM + projection: Wh1 LDS-resident, 256 blocks x 1 batch ----------
__global__ __launch_bounds__(512) void lstm1_k(
    const float* __restrict__ zp1, const unsigned short* __restrict__ wh1p,
    const unsigned short* __restrict__ woT, const float* __restrict__ bout,
    float* __restrict__ out)
{
    __shared__ alignas(16) unsigned short wl[65536];   // 128 KB
    __shared__ alignas(16) float hb[128];
    __shared__ float zs[512];
    __shared__ float red[37][8];
    const int col = threadIdx.x;
    const int b = blockIdx.x;
#pragma unroll
    for (int i=0;i<16;i++){
        int e = (col + i*512)*8;
        *(short8v*)&wl[e] = *(const short8v*)&wh1p[e];
    }
    if (col < 128) hb[col] = 0.f;
    float c1 = 0.f;
    __syncthreads();

    for (int t=0;t<12;t++){
        float acc = zp1[((size_t)t*256 + b)*512 + col];
#pragma unroll 4
        for (int kg=0;kg<16;kg++){
            short8v w8 = *(const short8v*)&wl[(kg*512 + col)*8];
            float4 hlo = *(const float4*)&hb[kg*8];
            float4 hhi = *(const float4*)&hb[kg*8+4];
            acc = fmaf(bf2f((unsigned short)w8[0]), hlo.x, acc);
            acc = fmaf(bf2f((unsigned short)w8[1]), hlo.y, acc);
            acc = fmaf(bf2f((unsigned short)w8[2]), hlo.z, acc);
            acc = fmaf(bf2f((unsigned short)w8[3]), hlo.w, acc);
            acc = fmaf(bf2f((unsigned short)w8[4]), hhi.x, acc);
            acc = fmaf(bf2f((unsigned short)w8[5]), hhi.y, acc);
            acc = fmaf(bf2f((unsigned short)w8[6]), hhi.z, acc);
            acc = fmaf(bf2f((unsigned short)w8[7]), hhi.w, acc);
        }
        zs[col] = acc;
        __syncthreads();
        if (col < 128){
            float zi=zs[col], zj=zs[128+col], zf=zs[256+col], zo=zs[384+col];
            c1 = c1*sigm(zf+1.f) + sigm(zi)*tanhf_(zj);
            hb[col] = tanhf_(c1)*sigm(zo);
        }
        __syncthreads();
        if (col < 296){
            const int n = col >> 3, q = col & 7;
            float p0 = 0.f;
#pragma unroll
            for (int kk=0;kk<16;kk++){
                float wv2 = bf2f(woT[n*128 + q*16 + kk]);
                p0 = fmaf(hb[q*16+kk], wv2, p0);
            }
            red[n][q] = p0;
        }
        __syncthreads();
        if (col < 37){
            float s0 = bout[col];
#pragma unroll
            for (int q=0;q<8;q++) s0 += red[col][q];
            out[((size_t)t*256 + b)*37 + col] = s0;
        }
        __syncthreads();
    }
}

extern "C" void kernel_launch(void* const* d_in, const int* in_sizes, int n_in,
                              void* d_out, int out_size, void* d_ws, size_t ws_size,
                              hipStream_t stream) {
    const float* x = (const float*)d_in[0];
    const float *w_[4], *cb_[4], *g_[4], *bb_[4], *mm_[4], *mv_[4];
    for (int i=0;i<4;i++){
        w_[i]  = (const float*)d_in[1+6*i];
        cb_[i] = (const float*)d_in[2+6*i];
        g_[i]  = (const float*)d_in[3+6*i];
        bb_[i] = (const float*)d_in[4+6*i];
        mm_[i] = (const float*)d_in[5+6*i];
        mv_[i] = (const float*)d_in[6+6*i];
    }
    const float* lW0  = (const float*)d_in[25];
    const float* lb0  = (const float*)d_in[26];
    const float* lW1  = (const float*)d_in[27];
    const float* lb1  = (const float*)d_in[28];
    const float* Wout = (const float*)d_in[29];
    const float* bout = (const float*)d_in[30];
    float* out = (float*)d_out;

    const size_t fixed = 6291456ull + 6291456 + 4096 + 1572864 + 786432
                       + 147456 + 294912 + 147456
                       + 262144 + 131072 + 131072 + 131072 + 9472;
    int Bc = 256;
    while (Bc > 8 && fixed + (size_t)Bc*565504 > ws_size) Bc >>= 1;

    char* cur = (char*)d_ws;
    float* XP  = (float*)cur;                    cur += 6291456;
    float* ZP1 = (float*)cur;                    cur += 6291456;
    float* bns = (float*)cur;                    cur += 4096;
    unsigned short* F    = (unsigned short*)cur; cur += 1572864;
    unsigned short* h0g  = (unsigned short*)cur; cur += 786432;
    unsigned short* Wp1  = (unsigned short*)cur; cur += 147456;
    unsigned short* Wp2  = (unsigned short*)cur; cur += 294912;
    unsigned short* Wp3  = (unsigned short*)cur; cur += 147456;
    unsigned short* Wx0p = (unsigned short*)cur; cur += 262144;
    unsigned short* Wh0p = (unsigned short*)cur; cur += 131072;
    unsigned short* Wx1p = (unsigned short*)cur; cur += 131072;
    unsigned short* Wh1p = (unsigned short*)cur; cur += 131072;
    unsigned short* WoT  = (unsigned short*)cur; cur += 9472;
    unsigned short* A    = (unsigned short*)cur; cur += (size_t)Bc*345600;
    unsigned short* Bb   = (unsigned short*)cur; cur += (size_t)Bc*172800;
    unsigned short* C    = (unsigned short*)cur;

    setup_k<<<2453, 256, 0, stream>>>(
        w_[1], w_[2], w_[3], lW0, lW1, Wout,
        cb_[0],g_[0],bb_[0],mm_[0],mv_[0],
        cb_[1],g_[1],bb_[1],mm_[1],mv_[1],
        cb_[2],g_[2],bb_[2],mm_[2],mv_[2],
        cb_[3],g_[3],bb_[3],mm_[3],mv_[3],
        Wp1, Wp2, Wp3, Wx0p, Wh0p, Wx1p, Wh1p, WoT, bns);

    const int nc = 256 / Bc;
    for (int bc=0; bc<nc; bc++){
        int bbase = bc*Bc;
        conv0_k<<<(Bc*2700+255)/256, 256, 0, stream>>>(x, w_[0], bns+640, bns+704, A, bbase, Bc*2700);
        convmf_k<64,128,30,90><<<dim3(6,4,Bc), 256, 0, stream>>>(A, Wp1, bns+0, bns+128, Bb);
        convmf_k<128,128,15,45><<<dim3(3,2,Bc), 256, 0, stream>>>(Bb, Wp2, bns+256, bns+384, C);
        convmf_k<128,64,8,23><<<dim3(2,1,Bc), 256, 0, stream>>>(C, Wp3, bns+512, bns+576,
                                                                F + (size_t)bbase*3072);
    }
    gemmrow_k<256,0><<<48, 256, 0, stream>>>(F, Wx0p, lb0, XP);
    lstm0_k<<<256, 512, 0, stream>>>(XP, Wh0p, h0g);
    gemmrow_k<128,1><<<48, 256, 0, stream>>>(h0g, Wx1p, lb1, ZP1);
    lstm1_k<<<256, 512, 0, stream>>>(ZP1, Wh1p, WoT, bout, out);
}

// Round 19
// 397.793 us; speedup vs baseline: 1.5433x; 1.0367x over previous
//
#include <hip/hip_runtime.h>
#include <hip/hip_bf16.h>
#include <math.h>
#include <stdint.h>

#define EPS 1e-5f
#define LEAK 0.01f
#define NEG_INF (-3.402823e38f)

typedef __attribute__((ext_vector_type(8))) short short8v;
typedef __attribute__((ext_vector_type(4))) float f32x4;

__device__ __forceinline__ float sigm(float x){ return 1.0f/(1.0f + __expf(-x)); }
__device__ __forceinline__ float tanhf_(float x){ return 1.0f - 2.0f/(__expf(2.0f*x)+1.0f); }
__device__ __forceinline__ float bnl(float a, float sc, float sh){
    float v = fmaf(a, sc, sh);
    return v < 0.0f ? LEAK*v : v;
}
__device__ __forceinline__ unsigned short f2bf(float f){
    __hip_bfloat16 h = __float2bfloat16(f);
    return *reinterpret_cast<unsigned short*>(&h);
}
__device__ __forceinline__ float bf2f(unsigned short u){
    return __uint_as_float(((unsigned)u) << 16);
}

// ---------- fused setup: all weight packs + BN folds in ONE launch ----------
__global__ __launch_bounds__(256) void setup_k(
    const float* __restrict__ w1, const float* __restrict__ w2, const float* __restrict__ w3,
    const float* __restrict__ lW0, const float* __restrict__ lW1, const float* __restrict__ Wout,
    const float* __restrict__ cb0, const float* __restrict__ g0, const float* __restrict__ bb0,
    const float* __restrict__ mm0, const float* __restrict__ mv0,
    const float* __restrict__ cb1, const float* __restrict__ g1, const float* __restrict__ bb1,
    const float* __restrict__ mm1, const float* __restrict__ mv1,
    const float* __restrict__ cb2, const float* __restrict__ g2, const float* __restrict__ bb2,
    const float* __restrict__ mm2, const float* __restrict__ mv2,
    const float* __restrict__ cb3, const float* __restrict__ g3, const float* __restrict__ bb3,
    const float* __restrict__ mm3, const float* __restrict__ mv3,
    unsigned short* __restrict__ Wp1, unsigned short* __restrict__ Wp2, unsigned short* __restrict__ Wp3,
    unsigned short* __restrict__ Wx0p, unsigned short* __restrict__ Wh0p,
    unsigned short* __restrict__ Wx1p, unsigned short* __restrict__ Wh1p,
    unsigned short* __restrict__ WoT, float* __restrict__ bns)
{
    const int bid = blockIdx.x, tid = threadIdx.x;
    if (bid < 864){
        const float* w; unsigned short* wp; int CIN, COUT, base;
        if (bid < 288){ w = w1; wp = Wp1; CIN=64; COUT=128; base = bid; }
        else { w = w2; wp = Wp2; CIN=128; COUT=128; base = bid-288; }
        int t = base*256 + tid;
        int total = 9*CIN*COUT;
        if (t < total){
            int cout = t % COUT, k = t / COUT;
            wp[(size_t)(k>>3)*COUT*8 + (size_t)cout*8 + (k&7)] = f2bf(w[(size_t)k*COUT + cout]);
        }
        return;
    }
    if (bid < 1152){
        int t = (bid-864)*256 + tid;
        if (t < 73728){
            int cout = t % 64, k = t / 64;
            Wp3[(size_t)(k>>3)*64*8 + (size_t)cout*8 + (k&7)] = f2bf(w3[(size_t)k*64 + cout]);
        }
        return;
    }
    if (bid < 2432){
        const float* src; unsigned short* dst; int base;
        if (bid < 1664){ src = lW0; dst = Wx0p; base = bid-1152; }
        else if (bid < 1920){ src = lW0 + 256*512; dst = Wh0p; base = bid-1664; }
        else if (bid < 2176){ src = lW1; dst = Wx1p; base = bid-1920; }
        else { src = lW1 + 128*512; dst = Wh1p; base = bid-2176; }
        int t = base*256 + tid;
        int k = t >> 9, col = t & 511;
        dst[(size_t)(k>>3)*4096 + col*8 + (k&7)] = f2bf(src[(size_t)k*512 + col]);
        return;
    }
    if (bid < 2451){
        int t = (bid-2432)*256 + tid;
        if (t < 4736){
            int n = t >> 7, k = t & 127;
            WoT[t] = f2bf(Wout[k*37 + n]);
        }
        return;
    }
    {
        int t = (bid-2451)*256 + tid;
        if (t < 128){
            float s = g1[t]*rsqrtf(mv1[t]+EPS);
            bns[t] = s; bns[128+t] = fmaf(cb1[t]-mm1[t], s, bb1[t]);
        } else if (t < 256){
            int u = t-128;
            float s = g2[u]*rsqrtf(mv2[u]+EPS);
            bns[256+u] = s; bns[384+u] = fmaf(cb2[u]-mm2[u], s, bb2[u]);
        } else if (t < 320){
            int u = t-256;
            float s = g3[u]*rsqrtf(mv3[u]+EPS);
            bns[512+u] = s; bns[576+u] = fmaf(cb3[u]-mm3[u], s, bb3[u]);
        } else if (t < 384){
            int u = t-320;
            float s = g0[u]*rsqrtf(mv0[u]+EPS);
            bns[640+u] = s; bns[704+u] = fmaf(cb0[u]-mm0[u], s, bb0[u]);
        }
        return;
    }
}

// ---------- conv block 0: thread = one pooled px, all 64 couts; weights in LDS ----------
__global__ __launch_bounds__(256) void conv0_k(
    const float* __restrict__ x, const float* __restrict__ w,
    const float* __restrict__ bsc, const float* __restrict__ bsh,
    unsigned short* __restrict__ out, int bbase, int total)
{
    __shared__ float wv[576];
    __shared__ float scs[64], shs[64];
    const int tid = threadIdx.x;
    for (int i=tid;i<576;i+=256) wv[i] = w[i];
    if (tid < 64){ scs[tid]=bsc[tid]; shs[tid]=bsh[tid]; }
    __syncthreads();
    const int id = blockIdx.x*256 + tid;
    if (id >= total) return;
    const int px = id % 90; int r = id / 90; const int py = r % 30; const int b0 = r / 30;
    const float* xb = x + (size_t)(bbase+b0)*10800;
    float p[4][4];
    const int y0 = 2*py-1, xx0 = 2*px-1;
#pragma unroll
    for (int rr=0;rr<4;rr++){
        int yy=y0+rr;
#pragma unroll
        for (int cc=0;cc<4;cc++){
            int xc=xx0+cc;
            p[rr][cc] = (yy>=0&&yy<60&&xc>=0&&xc<180)? xb[yy*180+xc] : 0.f;
        }
    }
    unsigned short* ob = out + (size_t)id*64;
#pragma unroll
    for (int cg=0;cg<8;cg++){
        short8v o8;
#pragma unroll
        for (int j=0;j<8;j++){
            const int co = cg*8+j;
            float s00=0.f,s01=0.f,s10=0.f,s11=0.f;
#pragma unroll
            for (int ky=0;ky<3;ky++)
#pragma unroll
            for (int kx=0;kx<3;kx++){
                float wt = wv[(ky*3+kx)*64+co];
                s00 = fmaf(p[ky][kx],     wt, s00);
                s01 = fmaf(p[ky][kx+1],   wt, s01);
                s10 = fmaf(p[ky+1][kx],   wt, s10);
                s11 = fmaf(p[ky+1][kx+1], wt, s11);
            }
            float sc=scs[co], sh=shs[co];
            float m = fmaxf(fmaxf(bnl(s00,sc,sh),bnl(s01,sc,sh)),
                            fmaxf(bnl(s10,sc,sh),bnl(s11,sc,sh)));
            o8[j] = (short)f2bf(m);
        }
        *(short8v*)&ob[cg*8] = o8;
    }
}

// ---------- MFMA fused conv+BN+leaky+pool: r14 tile + triple-buffer counted-vmcnt ----------
template<int CIN,int COUT,int H,int W>
__global__ __launch_bounds__(256,4) void convmf_k(
    const unsigned short* __restrict__ in, const unsigned short* __restrict__ wp,
    const float* __restrict__ bsc, const float* __restrict__ bsh,
    unsigned short* __restrict__ out)
{
    constexpr int PH=(H+1)/2, PW=(W+1)/2;
    constexpr int HALVES = CIN/64;
    constexpr int NIT = 9*HALVES;          // BK=64 iterations
    constexpr int NREP = COUT/16;
    constexpr int CH = (64*COUT)/(256*8);  // 16B DMA chunks per thread per K-tile
    __shared__ alignas(16) unsigned short wls[3][64*COUT];

    const int tid = threadIdx.x;
    const int lane = tid & 63;
    const int wm = tid >> 6;               // row-pair
    const int l15 = lane & 15, l4 = lane >> 4;
    const int x0 = blockIdx.x*16, y0 = blockIdx.y*8;
    const int b = blockIdx.z;
    const unsigned short* inb = in + (size_t)b*H*W*CIN;

    int rowoff[4]; bool rowok[4];
#pragma unroll
    for (int j=0;j<4;j++){
        int gy = y0 + 2*wm - 1 + j;
        rowok[j] = (unsigned)gy < (unsigned)H;
        rowoff[j] = (rowok[j] ? gy : 0) * (W*CIN);
    }
    int coloff[3]; bool colok[3];
#pragma unroll
    for (int kx=0;kx<3;kx++){
        int gx = x0 + l15 + kx - 1;
        colok[kx] = (unsigned)gx < (unsigned)W;
        coloff[kx] = (colok[kx] ? gx : 0) * CIN;
    }

    f32x4 acc[2][NREP];
#pragma unroll
    for (int m=0;m<2;m++)
#pragma unroll
    for (int n=0;n<NREP;n++) acc[m][n] = f32x4{0.f,0.f,0.f,0.f};

    auto stageB = [&](int it, int buf){
        const unsigned short* src = wp + (size_t)(it*8)*(COUT*8);
#pragma unroll
        for (int i=0;i<CH;i++){
            const unsigned short* g = src + (size_t)(tid + i*256)*8;
            unsigned short* l = &wls[buf][((tid & ~63) + i*256)*8];
            __builtin_amdgcn_global_load_lds(
                (const __attribute__((address_space(1))) unsigned int*)(uintptr_t)g,
                (__attribute__((address_space(3))) unsigned int*)(uintptr_t)l,
                16, 0, 0);
        }
    };

    stageB(0, 0);
    if (NIT > 1) stageB(1, 1);
    if constexpr (CH == 4){ asm volatile("s_waitcnt vmcnt(4)" ::: "memory"); }
    else                  { asm volatile("s_waitcnt vmcnt(2)" ::: "memory"); }
    __builtin_amdgcn_sched_barrier(0);
    __builtin_amdgcn_s_barrier();

    for (int it=0; it<NIT; ++it){
        const int tap = it / HALVES;
        const int khalf = it - tap*HALVES;
        const int ky = tap/3, kx = tap - ky*3;
        const int cin0 = khalf*64 + l4*8;
        const short8v z8 = short8v{0,0,0,0,0,0,0,0};
        short8v a[2][2];
#pragma unroll
        for (int rf=0;rf<2;rf++){
            const int j = rf + ky;
            const bool ok = rowok[j] && colok[kx];
            const unsigned short* p = inb + rowoff[j] + coloff[kx] + cin0;
#pragma unroll
            for (int ks=0;ks<2;ks++){
                short8v v = *(const short8v*)(p + ks*32);
                a[rf][ks] = ok ? v : z8;
            }
        }
        __builtin_amdgcn_sched_barrier(0);
        if (it+2 < NIT) stageB(it+2, (it+2)%3);
        __builtin_amdgcn_sched_barrier(0);
        const unsigned short* wb = &wls[it%3][0];
        __builtin_amdgcn_s_setprio(1);
#pragma unroll
        for (int ks=0; ks<2; ++ks){
#pragma unroll
            for (int nf=0; nf<NREP; ++nf){
                short8v bfr = *(const short8v*)&wb[((ks*4+l4)*COUT + nf*16 + l15)*8];
                acc[0][nf] = __builtin_amdgcn_mfma_f32_16x16x32_bf16(a[0][ks], bfr, acc[0][nf],0,0,0);
                acc[1][nf] = __builtin_amdgcn_mfma_f32_16x16x32_bf16(a[1][ks], bfr, acc[1][nf],0,0,0);
            }
        }
        __builtin_amdgcn_s_setprio(0);
        __builtin_amdgcn_s_barrier();
    }

    const int pr = (y0>>1) + wm;
    if (pr < PH){
        const bool r1 = (y0 + 2*wm + 1) < H;
        unsigned short* ob = out + ((size_t)b*PH + pr)*PW*COUT;
#pragma unroll
        for (int nf=0; nf<NREP; ++nf){
            const int co = nf*16 + l15;
            const float scv = bsc[co], shv = bsh[co];
            f32x4 e = acc[0][nf], o = acc[1][nf];
#pragma unroll
            for (int pp=0; pp<2; ++pp){
                const int pc = (x0>>1) + l4*2 + pp;
                if (pc >= PW) continue;
                const int oddcol = x0 + l4*4 + 2*pp + 1;
                float m = bnl(e[2*pp], scv, shv);
                if (oddcol < W) m = fmaxf(m, bnl(e[2*pp+1], scv, shv));
                if (r1){
                    m = fmaxf(m, bnl(o[2*pp], scv, shv));
                    if (oddcol < W) m = fmaxf(m, bnl(o[2*pp+1], scv, shv));
                }
                ob[(size_t)pc*COUT + co] = f2bf(m);
            }
        }
    }
}

// ---------- MFMA row-GEMM: out[3072][512] = A @ W + bias. 32-row tiles, 96 blocks ----------
template<int K, int MODE>
__global__ __launch_bounds__(256) void gemmrow_k(
    const unsigned short* __restrict__ A, const unsigned short* __restrict__ wp,
    const float* __restrict__ bias, float* __restrict__ out)
{
    constexpr int NS = K/32;
    __shared__ alignas(16) unsigned short wls[2][16384];
    const int tid = threadIdx.x, lane = tid & 63, w = tid >> 6;
    const int l15 = lane & 15, l4 = lane >> 4;
    const int r0 = blockIdx.x*32;

    f32x4 acc[2][8];
#pragma unroll
    for (int m=0;m<2;m++)
#pragma unroll
    for (int n=0;n<8;n++) acc[m][n] = f32x4{0.f,0.f,0.f,0.f};

    auto stage = [&](int s, int buf){
        const unsigned short* src = wp + (size_t)s*16384;
#pragma unroll
        for (int i=0;i<8;i++){
            int e = (tid + i*256)*8;
            *(short8v*)&wls[buf][e] = *(const short8v*)&src[e];
        }
    };
    stage(0,0);
    __syncthreads();

    for (int s=0;s<NS;++s){
        const int k0 = s*32 + l4*8;
        short8v af[2];
#pragma unroll
        for (int mf=0;mf<2;++mf){
            const int row = r0 + mf*16 + l15;
            size_t idx;
            if constexpr (MODE == 0){
                const int b = row & 255, t = row >> 8;
                idx = (size_t)b*3072 + (k0>>6)*768 + t*64 + (k0&63);
            } else {
                idx = (size_t)row*K + k0;
            }
            af[mf] = *(const short8v*)&A[idx];
        }
        if (s+1 < NS) stage(s+1,(s+1)&1);
        const unsigned short* wb = &wls[s&1][0];
#pragma unroll
        for (int nf=0;nf<8;++nf){
            const int col = w*128 + nf*16 + l15;
            short8v bfr = *(const short8v*)&wb[(l4*512 + col)*8];
#pragma unroll
            for (int mf=0;mf<2;++mf)
                acc[mf][nf] = __builtin_amdgcn_mfma_f32_16x16x32_bf16(af[mf], bfr, acc[mf][nf], 0,0,0);
        }
        __syncthreads();
    }
#pragma unroll
    for (int nf=0;nf<8;++nf){
        const int col = w*128 + nf*16 + l15;
        const float bv = bias[col];
#pragma unroll
        for (int mf=0;mf<2;++mf){
#pragma unroll
            for (int j=0;j<4;++j){
                const int row = r0 + mf*16 + l4*4 + j;
                out[(size_t)row*512 + col] = acc[mf][nf][j] + bv;
            }
        }
    }
}

// ---------- layer-0 LSTM: Wh0 LDS-resident, 256 blocks x 1 batch ----------
__global__ __launch_bounds__(512) void lstm0_k(
    const float* __restrict__ xp, const unsigned short* __restrict__ wh0p,
    unsigned short* __restrict__ h0g)
{
    __shared__ alignas(16) unsigned short wl[65536];   // 128 KB
    __shared__ alignas(16) float hb[128];
    __shared__ float zs[512];
    const int col = threadIdx.x;
    const int b = blockIdx.x;
#pragma unroll
    for (int i=0;i<16;i++){
        int e = (col + i*512)*8;
        *(short8v*)&wl[e] = *(const short8v*)&wh0p[e];
    }
    if (col < 128) hb[col] = 0.f;
    float c0 = 0.f;
    __syncthreads();

    for (int t=0;t<12;t++){
        float acc = xp[((size_t)t*256 + b)*512 + col];
#pragma unroll 4
        for (int kg=0;kg<16;kg++){
            short8v w8 = *(const short8v*)&wl[(kg*512 + col)*8];
            float4 hlo = *(const float4*)&hb[kg*8];
            float4 hhi = *(const float4*)&hb[kg*8+4];
            acc = fmaf(bf2f((unsigned short)w8[0]), hlo.x, acc);
            acc = fmaf(bf2f((unsigned short)w8[1]), hlo.y, acc);
            acc = fmaf(bf2f((unsigned short)w8[2]), hlo.z, acc);
            acc = fmaf(bf2f((unsigned short)w8[3]), hlo.w, acc);
            acc = fmaf(bf2f((unsigned short)w8[4]), hhi.x, acc);
            acc = fmaf(bf2f((unsigned short)w8[5]), hhi.y, acc);
            acc = fmaf(bf2f((unsigned short)w8[6]), hhi.z, acc);
            acc = fmaf(bf2f((unsigned short)w8[7]), hhi.w, acc);
        }
        zs[col] = acc;
        __syncthreads();
        if (col < 128){
            float zi=zs[col], zj=zs[128+col], zf=zs[256+col], zo=zs[384+col];
            c0 = c0*sigm(zf+1.f) + sigm(zi)*tanhf_(zj);
            float h = tanhf_(c0)*sigm(zo);
            hb[col] = h;
            h0g[((size_t)t*256 + b)*128 + col] = f2bf(h);
        }
        __syncthreads();
    }
}

// ---------- layer-1 LSTM + projection: Wh1 LDS-resident, 256 blocks x 1 batch ----------
__global__ __launch_bounds__(512) void lstm1_k(
    const float* __restrict__ zp1, const unsigned short* __restrict__ wh1p,
    const unsigned short* __restrict__ woT, const float* __restrict__ bout,
    float* __restrict__ out)
{
    __shared__ alignas(16) unsigned short wl[65536];   // 128 KB
    __shared__ alignas(16) float hb[128];
    __shared__ float zs[512];
    __shared__ float red[37][8];
    const int col = threadIdx.x;
    const int b = blockIdx.x;
#pragma unroll
    for (int i=0;i<16;i++){
        int e = (col + i*512)*8;
        *(short8v*)&wl[e] = *(const short8v*)&wh1p[e];
    }
    if (col < 128) hb[col] = 0.f;
    float c1 = 0.f;
    __syncthreads();

    for (int t=0;t<12;t++){
        float acc = zp1[((size_t)t*256 + b)*512 + col];
#pragma unroll 4
        for (int kg=0;kg<16;kg++){
            short8v w8 = *(const short8v*)&wl[(kg*512 + col)*8];
            float4 hlo = *(const float4*)&hb[kg*8];
            float4 hhi = *(const float4*)&hb[kg*8+4];
            acc = fmaf(bf2f((unsigned short)w8[0]), hlo.x, acc);
            acc = fmaf(bf2f((unsigned short)w8[1]), hlo.y, acc);
            acc = fmaf(bf2f((unsigned short)w8[2]), hlo.z, acc);
            acc = fmaf(bf2f((unsigned short)w8[3]), hlo.w, acc);
            acc = fmaf(bf2f((unsigned short)w8[4]), hhi.x, acc);
            acc = fmaf(bf2f((unsigned short)w8[5]), hhi.y, acc);
            acc = fmaf(bf2f((unsigned short)w8[6]), hhi.z, acc);
            acc = fmaf(bf2f((unsigned short)w8[7]), hhi.w, acc);
        }
        zs[col] = acc;
        __syncthreads();
        if (col < 128){
            float zi=zs[col], zj=zs[128+col], zf=zs[256+col], zo=zs[384+col];
            c1 = c1*sigm(zf+1.f) + sigm(zi)*tanhf_(zj);
            hb[col] = tanhf_(c1)*sigm(zo);
        }
        __syncthreads();
        if (col < 296){
            const int n = col >> 3, q = col & 7;
            float p0 = 0.f;
#pragma unroll
            for (int kk=0;kk<16;kk++){
                float wv2 = bf2f(woT[n*128 + q*16 + kk]);
                p0 = fmaf(hb[q*16+kk], wv2, p0);
            }
            red[n][q] = p0;
        }
        __syncthreads();
        if (col < 37){
            float s0 = bout[col];
#pragma unroll
            for (int q=0;q<8;q++) s0 += red[col][q];
            out[((size_t)t*256 + b)*37 + col] = s0;
        }
        __syncthreads();
    }
}

extern "C" void kernel_launch(void* const* d_in, const int* in_sizes, int n_in,
                              void* d_out, int out_size, void* d_ws, size_t ws_size,
                              hipStream_t stream) {
    const float* x = (const float*)d_in[0];
    const float *w_[4], *cb_[4], *g_[4], *bb_[4], *mm_[4], *mv_[4];
    for (int i=0;i<4;i++){
        w_[i]  = (const float*)d_in[1+6*i];
        cb_[i] = (const float*)d_in[2+6*i];
        g_[i]  = (const float*)d_in[3+6*i];
        bb_[i] = (const float*)d_in[4+6*i];
        mm_[i] = (const float*)d_in[5+6*i];
        mv_[i] = (const float*)d_in[6+6*i];
    }
    const float* lW0  = (const float*)d_in[25];
    const float* lb0  = (const float*)d_in[26];
    const float* lW1  = (const float*)d_in[27];
    const float* lb1  = (const float*)d_in[28];
    const float* Wout = (const float*)d_in[29];
    const float* bout = (const float*)d_in[30];
    float* out = (float*)d_out;

    const size_t fixed = 6291456ull + 6291456 + 4096 + 1572864 + 786432
                       + 147456 + 294912 + 147456
                       + 262144 + 131072 + 131072 + 131072 + 9472;
    int Bc = 256;
    while (Bc > 8 && fixed + (size_t)Bc*565504 > ws_size) Bc >>= 1;

    char* cur = (char*)d_ws;
    float* XP  = (float*)cur;                    cur += 6291456;
    float* ZP1 = (float*)cur;                    cur += 6291456;
    float* bns = (float*)cur;                    cur += 4096;
    unsigned short* F    = (unsigned short*)cur; cur += 1572864;
    unsigned short* h0g  = (unsigned short*)cur; cur += 786432;
    unsigned short* Wp1  = (unsigned short*)cur; cur += 147456;
    unsigned short* Wp2  = (unsigned short*)cur; cur += 294912;
    unsigned short* Wp3  = (unsigned short*)cur; cur += 147456;
    unsigned short* Wx0p = (unsigned short*)cur; cur += 262144;
    unsigned short* Wh0p = (unsigned short*)cur; cur += 131072;
    unsigned short* Wx1p = (unsigned short*)cur; cur += 131072;
    unsigned short* Wh1p = (unsigned short*)cur; cur += 131072;
    unsigned short* WoT  = (unsigned short*)cur; cur += 9472;
    unsigned short* A    = (unsigned short*)cur; cur += (size_t)Bc*345600;
    unsigned short* Bb   = (unsigned short*)cur; cur += (size_t)Bc*172800;
    unsigned short* C    = (unsigned short*)cur;

    setup_k<<<2453, 256, 0, stream>>>(
        w_[1], w_[2], w_[3], lW0, lW1, Wout,
        cb_[0],g_[0],bb_[0],mm_[0],mv_[0],
        cb_[1],g_[1],bb_[1],mm_[1],mv_[1],
        cb_[2],g_[2],bb_[2],mm_[2],mv_[2],
        cb_[3],g_[3],bb_[3],mm_[3],mv_[3],
        Wp1, Wp2, Wp3, Wx0p, Wh0p, Wx1p, Wh1p, WoT, bns);

    const int nc = 256 / Bc;
    for (int bc=0; bc<nc; bc++){
        int bbase = bc*Bc;
        conv0_k<<<(Bc*2700+255)/256, 256, 0, stream>>>(x, w_[0], bns+640, bns+704, A, bbase, Bc*2700);
        convmf_k<64,128,30,90><<<dim3(6,4,Bc), 256, 0, stream>>>(A, Wp1, bns+0, bns+128, Bb);
        convmf_k<128,128,15,45><<<dim3(3,2,Bc), 256, 0, stream>>>(Bb, Wp2, bns+256, bns+384, C);
        convmf_k<128,64,8,23><<<dim3(2,1,Bc), 256, 0, stream>>>(C, Wp3, bns+512, bns+576,
                                                                F + (size_t)bbase*3072);
    }
    gemmrow_k<256,0><<<96, 256, 0, stream>>>(F, Wx0p, lb0, XP);
    lstm0_k<<<256, 512, 0, stream>>>(XP, Wh0p, h0g);
    gemmrow_k<128,1><<<96, 256, 0, stream>>>(h0g, Wx1p, lb1, ZP1);
    lstm1_k<<<256, 512, 0, stream>>>(ZP1, Wh1p, WoT, bout, out);
}

// Round 20
// 373.276 us; speedup vs baseline: 1.6447x; 1.0657x over previous
//
#include <hip/hip_runtime.h>
#include <hip/hip_bf16.h>
#include <math.h>
#include <stdint.h>

#define EPS 1e-5f
#define LEAK 0.01f
#define NEG_INF (-3.402823e38f)

typedef __attribute__((ext_vector_type(8))) short short8v;
typedef __attribute__((ext_vector_type(4))) float f32x4;

__device__ __forceinline__ float sigm(float x){ return 1.0f/(1.0f + __expf(-x)); }
__device__ __forceinline__ float tanhf_(float x){ return 1.0f - 2.0f/(__expf(2.0f*x)+1.0f); }
__device__ __forceinline__ float bnl(float a, float sc, float sh){
    float v = fmaf(a, sc, sh);
    return v < 0.0f ? LEAK*v : v;
}
__device__ __forceinline__ unsigned short f2bf(float f){
    __hip_bfloat16 h = __float2bfloat16(f);
    return *reinterpret_cast<unsigned short*>(&h);
}
__device__ __forceinline__ float bf2f(unsigned short u){
    return __uint_as_float(((unsigned)u) << 16);
}

// ---------- fused setup: all weight packs + BN folds in ONE launch ----------
__global__ __launch_bounds__(256) void setup_k(
    const float* __restrict__ w1, const float* __restrict__ w2, const float* __restrict__ w3,
    const float* __restrict__ lW0, const float* __restrict__ lW1, const float* __restrict__ Wout,
    const float* __restrict__ cb0, const float* __restrict__ g0, const float* __restrict__ bb0,
    const float* __restrict__ mm0, const float* __restrict__ mv0,
    const float* __restrict__ cb1, const float* __restrict__ g1, const float* __restrict__ bb1,
    const float* __restrict__ mm1, const float* __restrict__ mv1,
    const float* __restrict__ cb2, const float* __restrict__ g2, const float* __restrict__ bb2,
    const float* __restrict__ mm2, const float* __restrict__ mv2,
    const float* __restrict__ cb3, const float* __restrict__ g3, const float* __restrict__ bb3,
    const float* __restrict__ mm3, const float* __restrict__ mv3,
    unsigned short* __restrict__ Wp1, unsigned short* __restrict__ Wp2, unsigned short* __restrict__ Wp3,
    unsigned short* __restrict__ Wx0p, unsigned short* __restrict__ Wh0p,
    unsigned short* __restrict__ Wx1p, unsigned short* __restrict__ Wh1p,
    unsigned short* __restrict__ WoT, float* __restrict__ bns)
{
    const int bid = blockIdx.x, tid = threadIdx.x;
    if (bid < 864){
        const float* w; unsigned short* wp; int CIN, COUT, base;
        if (bid < 288){ w = w1; wp = Wp1; CIN=64; COUT=128; base = bid; }
        else { w = w2; wp = Wp2; CIN=128; COUT=128; base = bid-288; }
        int t = base*256 + tid;
        int total = 9*CIN*COUT;
        if (t < total){
            int cout = t % COUT, k = t / COUT;
            wp[(size_t)(k>>3)*COUT*8 + (size_t)cout*8 + (k&7)] = f2bf(w[(size_t)k*COUT + cout]);
        }
        return;
    }
    if (bid < 1152){
        int t = (bid-864)*256 + tid;
        if (t < 73728){
            int cout = t % 64, k = t / 64;
            Wp3[(size_t)(k>>3)*64*8 + (size_t)cout*8 + (k&7)] = f2bf(w3[(size_t)k*64 + cout]);
        }
        return;
    }
    if (bid < 2432){
        const float* src; unsigned short* dst; int base;
        if (bid < 1664){ src = lW0; dst = Wx0p; base = bid-1152; }
        else if (bid < 1920){ src = lW0 + 256*512; dst = Wh0p; base = bid-1664; }
        else if (bid < 2176){ src = lW1; dst = Wx1p; base = bid-1920; }
        else { src = lW1 + 128*512; dst = Wh1p; base = bid-2176; }
        int t = base*256 + tid;
        int k = t >> 9, col = t & 511;
        dst[(size_t)(k>>3)*4096 + col*8 + (k&7)] = f2bf(src[(size_t)k*512 + col]);
        return;
    }
    if (bid < 2451){
        int t = (bid-2432)*256 + tid;
        if (t < 4736){
            int n = t >> 7, k = t & 127;
            WoT[t] = f2bf(Wout[k*37 + n]);
        }
        return;
    }
    {
        int t = (bid-2451)*256 + tid;
        if (t < 128){
            float s = g1[t]*rsqrtf(mv1[t]+EPS);
            bns[t] = s; bns[128+t] = fmaf(cb1[t]-mm1[t], s, bb1[t]);
        } else if (t < 256){
            int u = t-128;
            float s = g2[u]*rsqrtf(mv2[u]+EPS);
            bns[256+u] = s; bns[384+u] = fmaf(cb2[u]-mm2[u], s, bb2[u]);
        } else if (t < 320){
            int u = t-256;
            float s = g3[u]*rsqrtf(mv3[u]+EPS);
            bns[512+u] = s; bns[576+u] = fmaf(cb3[u]-mm3[u], s, bb3[u]);
        } else if (t < 384){
            int u = t-320;
            float s = g0[u]*rsqrtf(mv0[u]+EPS);
            bns[640+u] = s; bns[704+u] = fmaf(cb0[u]-mm0[u], s, bb0[u]);
        }
        return;
    }
}

// ---------- conv block 0: thread = one pooled px, all 64 couts; weights in LDS ----------
__global__ __launch_bounds__(256) void conv0_k(
    const float* __restrict__ x, const float* __restrict__ w,
    const float* __restrict__ bsc, const float* __restrict__ bsh,
    unsigned short* __restrict__ out, int bbase, int total)
{
    __shared__ float wv[576];
    __shared__ float scs[64], shs[64];
    const int tid = threadIdx.x;
    for (int i=tid;i<576;i+=256) wv[i] = w[i];
    if (tid < 64){ scs[tid]=bsc[tid]; shs[tid]=bsh[tid]; }
    __syncthreads();
    const int id = blockIdx.x*256 + tid;
    if (id >= total) return;
    const int px = id % 90; int r = id / 90; const int py = r % 30; const int b0 = r / 30;
    const float* xb = x + (size_t)(bbase+b0)*10800;
    float p[4][4];
    const int y0 = 2*py-1, xx0 = 2*px-1;
#pragma unroll
    for (int rr=0;rr<4;rr++){
        int yy=y0+rr;
#pragma unroll
        for (int cc=0;cc<4;cc++){
            int xc=xx0+cc;
            p[rr][cc] = (yy>=0&&yy<60&&xc>=0&&xc<180)? xb[yy*180+xc] : 0.f;
        }
    }
    unsigned short* ob = out + (size_t)id*64;
#pragma unroll
    for (int cg=0;cg<8;cg++){
        short8v o8;
#pragma unroll
        for (int j=0;j<8;j++){
            const int co = cg*8+j;
            float s00=0.f,s01=0.f,s10=0.f,s11=0.f;
#pragma unroll
            for (int ky=0;ky<3;ky++)
#pragma unroll
            for (int kx=0;kx<3;kx++){
                float wt = wv[(ky*3+kx)*64+co];
                s00 = fmaf(p[ky][kx],     wt, s00);
                s01 = fmaf(p[ky][kx+1],   wt, s01);
                s10 = fmaf(p[ky+1][kx],   wt, s10);
                s11 = fmaf(p[ky+1][kx+1], wt, s11);
            }
            float sc=scs[co], sh=shs[co];
            float m = fmaxf(fmaxf(bnl(s00,sc,sh),bnl(s01,sc,sh)),
                            fmaxf(bnl(s10,sc,sh),bnl(s11,sc,sh)));
            o8[j] = (short)f2bf(m);
        }
        *(short8v*)&ob[cg*8] = o8;
    }
}

// ---------- MFMA fused conv+BN+leaky+pool: A-resident swizzled LDS ----------
// Tile: 8 rows x 16 cols. 4 waves = 4 row-pairs, full COUT per wave.
// A-tile [10][18][CIN] bf16 staged ONCE (XOR-swizzled, zero-padded halo);
// W double-buffered via global_load_lds DMA. Inner loop is LDS+MFMA only.
template<int CIN,int COUT,int H,int W>
__global__ __launch_bounds__(256,2) void convmf_k(
    const unsigned short* __restrict__ in, const unsigned short* __restrict__ wp,
    const float* __restrict__ bsc, const float* __restrict__ bsh,
    unsigned short* __restrict__ out)
{
    constexpr int PH=(H+1)/2, PW=(W+1)/2;
    constexpr int HALVES = CIN/64;
    constexpr int NIT = 9*HALVES;          // BK=64 iterations
    constexpr int NREP = COUT/16;
    constexpr int CH = (64*COUT)/(256*8);  // 16B DMA chunks per thread per K-tile
    constexpr int AR = 10, AC = 18;
    constexpr int AV = AR*AC*(CIN/8);      // 16B vectors in A-tile
    __shared__ alignas(16) unsigned short als[AR*AC*CIN];
    __shared__ alignas(16) unsigned short wls[2][64*COUT];

    const int tid = threadIdx.x;
    const int lane = tid & 63;
    const int wm = tid >> 6;               // row-pair
    const int l15 = lane & 15, l4 = lane >> 4;
    const int x0 = blockIdx.x*16, y0 = blockIdx.y*8;
    const int b = blockIdx.z;
    const unsigned short* inb = in + (size_t)b*H*W*CIN;

    f32x4 acc[2][NREP];
#pragma unroll
    for (int m=0;m<2;m++)
#pragma unroll
    for (int n=0;n<NREP;n++) acc[m][n] = f32x4{0.f,0.f,0.f,0.f};

    auto stageB = [&](int it, int buf){
        const unsigned short* src = wp + (size_t)(it*8)*(COUT*8);
#pragma unroll
        for (int i=0;i<CH;i++){
            const unsigned short* g = src + (size_t)(tid + i*256)*8;
            unsigned short* l = &wls[buf][((tid & ~63) + i*256)*8];
            __builtin_amdgcn_global_load_lds(
                (const __attribute__((address_space(1))) unsigned int*)(uintptr_t)g,
                (__attribute__((address_space(3))) unsigned int*)(uintptr_t)l,
                16, 0, 0);
        }
    };

    // stage W tile 0 (DMA) and the full A-tile (reg-staged, swizzled, zero-padded)
    stageB(0, 0);
    {
        const short8v z8 = short8v{0,0,0,0,0,0,0,0};
        for (int v = tid; v < AV; v += 256){
            const int cin8 = v % (CIN/8);
            const int rc = v / (CIN/8);
            const int col = rc % AC, row = rc / AC;
            const int gy = y0 - 1 + row, gx = x0 - 1 + col;
            short8v val = z8;
            if ((unsigned)gy < (unsigned)H && (unsigned)gx < (unsigned)W)
                val = *(const short8v*)&inb[((size_t)gy*W + gx)*CIN + cin8*8];
            int elem = ((row*AC + col)*CIN + cin8*8) ^ ((col & 7) << 3);
            *(short8v*)&als[elem] = val;
        }
    }
    __syncthreads();

    for (int it=0; it<NIT; ++it){
        if (it+1 < NIT) stageB(it+1, (it+1)&1);
        const int tap = it / HALVES;
        const int khalf = it - tap*HALVES;
        const int ky = tap/3, kx = tap - ky*3;
        short8v a[2][2];
#pragma unroll
        for (int rf=0;rf<2;rf++){
            const int lrow = 2*wm + rf + ky;
            const int col_l = l15 + kx;
            const int base = (lrow*AC + col_l)*CIN + khalf*64 + l4*8;
            const int swz = (col_l & 7) << 3;
#pragma unroll
            for (int ks=0;ks<2;ks++)
                a[rf][ks] = *(const short8v*)&als[(base + ks*32) ^ swz];
        }
        const unsigned short* wb = &wls[it&1][0];
        __builtin_amdgcn_s_setprio(1);
#pragma unroll
        for (int ks=0; ks<2; ++ks){
#pragma unroll
            for (int nf=0; nf<NREP; ++nf){
                short8v bfr = *(const short8v*)&wb[((ks*4+l4)*COUT + nf*16 + l15)*8];
                acc[0][nf] = __builtin_amdgcn_mfma_f32_16x16x32_bf16(a[0][ks], bfr, acc[0][nf],0,0,0);
                acc[1][nf] = __builtin_amdgcn_mfma_f32_16x16x32_bf16(a[1][ks], bfr, acc[1][nf],0,0,0);
            }
        }
        __builtin_amdgcn_s_setprio(0);
        __syncthreads();
    }

    const int pr = (y0>>1) + wm;
    if (pr < PH){
        const bool r1 = (y0 + 2*wm + 1) < H;
        unsigned short* ob = out + ((size_t)b*PH + pr)*PW*COUT;
#pragma unroll
        for (int nf=0; nf<NREP; ++nf){
            const int co = nf*16 + l15;
            const float scv = bsc[co], shv = bsh[co];
            f32x4 e = acc[0][nf], o = acc[1][nf];
#pragma unroll
            for (int pp=0; pp<2; ++pp){
                const int pc = (x0>>1) + l4*2 + pp;
                if (pc >= PW) continue;
                const int oddcol = x0 + l4*4 + 2*pp + 1;
                float m = bnl(e[2*pp], scv, shv);
                if (oddcol < W) m = fmaxf(m, bnl(e[2*pp+1], scv, shv));
                if (r1){
                    m = fmaxf(m, bnl(o[2*pp], scv, shv));
                    if (oddcol < W) m = fmaxf(m, bnl(o[2*pp+1], scv, shv));
                }
                ob[(size_t)pc*COUT + co] = f2bf(m);
            }
        }
    }
}

// ---------- MFMA row-GEMM: out[3072][512] = A @ W + bias. 32-row tiles, 96 blocks ----------
template<int K, int MODE>
__global__ __launch_bounds__(256) void gemmrow_k(
    const unsigned short* __restrict__ A, const unsigned short* __restrict__ wp,
    const float* __restrict__ bias, float* __restrict__ out)
{
    constexpr int NS = K/32;
    __shared__ alignas(16) unsigned short wls[2][16384];
    const int tid = threadIdx.x, lane = tid & 63, w = tid >> 6;
    const int l15 = lane & 15, l4 = lane >> 4;
    const int r0 = blockIdx.x*32;

    f32x4 acc[2][8];
#pragma unroll
    for (int m=0;m<2;m++)
#pragma unroll
    for (int n=0;n<8;n++) acc[m][n] = f32x4{0.f,0.f,0.f,0.f};

    auto stage = [&](int s, int buf){
        const unsigned short* src = wp + (size_t)s*16384;
#pragma unroll
        for (int i=0;i<8;i++){
            int e = (tid + i*256)*8;
            *(short8v*)&wls[buf][e] = *(const short8v*)&src[e];
        }
    };
    stage(0,0);
    __syncthreads();

    for (int s=0;s<NS;++s){
        const int k0 = s*32 + l4*8;
        short8v af[2];
#pragma unroll
        for (int mf=0;mf<2;++mf){
            const int row = r0 + mf*16 + l15;
            size_t idx;
            if constexpr (MODE == 0){
                const int b = row & 255, t = row >> 8;
                idx = (size_t)b*3072 + (k0>>6)*768 + t*64 + (k0&63);
            } else {
                idx = (size_t)row*K + k0;
            }
            af[mf] = *(const short8v*)&A[idx];
        }
        if (s+1 < NS) stage(s+1,(s+1)&1);
        const unsigned short* wb = &wls[s&1][0];
#pragma unroll
        for (int nf=0;nf<8;++nf){
            const int col = w*128 + nf*16 + l15;
            short8v bfr = *(const short8v*)&wb[(l4*512 + col)*8];
#pragma unroll
            for (int mf=0;mf<2;++mf)
                acc[mf][nf] = __builtin_amdgcn_mfma_f32_16x16x32_bf16(af[mf], bfr, acc[mf][nf], 0,0,0);
        }
        __syncthreads();
    }
#pragma unroll
    for (int nf=0;nf<8;++nf){
        const int col = w*128 + nf*16 + l15;
        const float bv = bias[col];
#pragma unroll
        for (int mf=0;mf<2;++mf){
#pragma unroll
            for (int j=0;j<4;++j){
                const int row = r0 + mf*16 + l4*4 + j;
                out[(size_t)row*512 + col] = acc[mf][nf][j] + bv;
            }
        }
    }
}

// ---------- layer-0 LSTM: Wh0 LDS-resident, 256 blocks x 1 batch ----------
__global__ __launch_bounds__(512) void lstm0_k(
    const float* __restrict__ xp, const unsigned short* __restrict__ wh0p,
    unsigned short* __restrict__ h0g)
{
    __shared__ alignas(16) unsigned short wl[65536];   // 128 KB
    __shared__ alignas(16) float hb[128];
    __shared__ float zs[512];
    const int col = threadIdx.x;
    const int b = blockIdx.x;
#pragma unroll
    for (int i=0;i<16;i++){
        int e = (col + i*512)*8;
        *(short8v*)&wl[e] = *(const short8v*)&wh0p[e];
    }
    if (col < 128) hb[col] = 0.f;
    float c0 = 0.f;
    __syncthreads();

    for (int t=0;t<12;t++){
        float acc = xp[((size_t)t*256 + b)*512 + col];
#pragma unroll 4
        for (int kg=0;kg<16;kg++){
            short8v w8 = *(const short8v*)&wl[(kg*512 + col)*8];
            float4 hlo = *(const float4*)&hb[kg*8];
            float4 hhi = *(const float4*)&hb[kg*8+4];
            acc = fmaf(bf2f((unsigned short)w8[0]), hlo.x, acc);
            acc = fmaf(bf2f((unsigned short)w8[1]), hlo.y, acc);
            acc = fmaf(bf2f((unsigned short)w8[2]), hlo.z, acc);
            acc = fmaf(bf2f((unsigned short)w8[3]), hlo.w, acc);
            acc = fmaf(bf2f((unsigned short)w8[4]), hhi.x, acc);
            acc = fmaf(bf2f((unsigned short)w8[5]), hhi.y, acc);
            acc = fmaf(bf2f((unsigned short)w8[6]), hhi.z, acc);
            acc = fmaf(bf2f((unsigned short)w8[7]), hhi.w, acc);
        }
        zs[col] = acc;
        __syncthreads();
        if (col < 128){
            float zi=zs[col], zj=zs[128+col], zf=zs[256+col], zo=zs[384+col];
            c0 = c0*sigm(zf+1.f) + sigm(zi)*tanhf_(zj);
            float h = tanhf_(c0)*sigm(zo);
            hb[col] = h;
            h0g[((size_t)t*256 + b)*128 + col] = f2bf(h);
        }
        __syncthreads();
    }
}

// ---------- layer-1 LSTM + projection: Wh1 LDS-resident, 256 blocks x 1 batch ----------
__global__ __launch_bounds__(512) void lstm1_k(
    const float* __restrict__ zp1, const unsigned short* __restrict__ wh1p,
    const unsigned short* __restrict__ woT, const float* __restrict__ bout,
    float* __restrict__ out)
{
    __shared__ alignas(16) unsigned short wl[65536];   // 128 KB
    __shared__ alignas(16) float hb[128];
    __shared__ float zs[512];
    __shared__ float red[37][8];
    const int col = threadIdx.x;
    const int b = blockIdx.x;
#pragma unroll
    for (int i=0;i<16;i++){
        int e = (col + i*512)*8;
        *(short8v*)&wl[e] = *(const short8v*)&wh1p[e];
    }
    if (col < 128) hb[col] = 0.f;
    float c1 = 0.f;
    __syncthreads();

    for (int t=0;t<12;t++){
        float acc = zp1[((size_t)t*256 + b)*512 + col];
#pragma unroll 4
        for (int kg=0;kg<16;kg++){
            short8v w8 = *(const short8v*)&wl[(kg*512 + col)*8];
            float4 hlo = *(const float4*)&hb[kg*8];
            float4 hhi = *(const float4*)&hb[kg*8+4];
            acc = fmaf(bf2f((unsigned short)w8[0]), hlo.x, acc);
            acc = fmaf(bf2f((unsigned short)w8[1]), hlo.y, acc);
            acc = fmaf(bf2f((unsigned short)w8[2]), hlo.z, acc);
            acc = fmaf(bf2f((unsigned short)w8[3]), hlo.w, acc);
            acc = fmaf(bf2f((unsigned short)w8[4]), hhi.x, acc);
            acc = fmaf(bf2f((unsigned short)w8[5]), hhi.y, acc);
            acc = fmaf(bf2f((unsigned short)w8[6]), hhi.z, acc);
            acc = fmaf(bf2f((unsigned short)w8[7]), hhi.w, acc);
        }
        zs[col] = acc;
        __syncthreads();
        if (col < 128){
            float zi=zs[col], zj=zs[128+col], zf=zs[256+col], zo=zs[384+col];
            c1 = c1*sigm(zf+1.f) + sigm(zi)*tanhf_(zj);
            hb[col] = tanhf_(c1)*sigm(zo);
        }
        __syncthreads();
        if (col < 296){
            const int n = col >> 3, q = col & 7;
            float p0 = 0.f;
#pragma unroll
            for (int kk=0;kk<16;kk++){
                float wv2 = bf2f(woT[n*128 + q*16 + kk]);
                p0 = fmaf(hb[q*16+kk], wv2, p0);
            }
            red[n][q] = p0;
        }
        __syncthreads();
        if (col < 37){
            float s0 = bout[col];
#pragma unroll
            for (int q=0;q<8;q++) s0 += red[col][q];
            out[((size_t)t*256 + b)*37 + col] = s0;
        }
        __syncthreads();
    }
}

extern "C" void kernel_launch(void* const* d_in, const int* in_sizes, int n_in,
                              void* d_out, int out_size, void* d_ws, size_t ws_size,
                              hipStream_t stream) {
    const float* x = (const float*)d_in[0];
    const float *w_[4], *cb_[4], *g_[4], *bb_[4], *mm_[4], *mv_[4];
    for (int i=0;i<4;i++){
        w_[i]  = (const float*)d_in[1+6*i];
        cb_[i] = (const float*)d_in[2+6*i];
        g_[i]  = (const float*)d_in[3+6*i];
        bb_[i] = (const float*)d_in[4+6*i];
        mm_[i] = (const float*)d_in[5+6*i];
        mv_[i] = (const float*)d_in[6+6*i];
    }
    const float* lW0  = (const float*)d_in[25];
    const float* lb0  = (const float*)d_in[26];
    const float* lW1  = (const float*)d_in[27];
    const float* lb1  = (const float*)d_in[28];
    const float* Wout = (const float*)d_in[29];
    const float* bout = (const float*)d_in[30];
    float* out = (float*)d_out;

    const size_t fixed = 6291456ull + 6291456 + 4096 + 1572864 + 786432
                       + 147456 + 294912 + 147456
                       + 262144 + 131072 + 131072 + 131072 + 9472;
    int Bc = 256;
    while (Bc > 8 && fixed + (size_t)Bc*565504 > ws_size) Bc >>= 1;

    char* cur = (char*)d_ws;
    float* XP  = (float*)cur;                    cur += 6291456;
    float* ZP1 = (float*)cur;                    cur += 6291456;
    float* bns = (float*)cur;                    cur += 4096;
    unsigned short* F    = (unsigned short*)cur; cur += 1572864;
    unsigned short* h0g  = (unsigned short*)cur; cur += 786432;
    unsigned short* Wp1  = (unsigned short*)cur; cur += 147456;
    unsigned short* Wp2  = (unsigned short*)cur; cur += 294912;
    unsigned short* Wp3  = (unsigned short*)cur; cur += 147456;
    unsigned short* Wx0p = (unsigned short*)cur; cur += 262144;
    unsigned short* Wh0p = (unsigned short*)cur; cur += 131072;
    unsigned short* Wx1p = (unsigned short*)cur; cur += 131072;
    unsigned short* Wh1p = (unsigned short*)cur; cur += 131072;
    unsigned short* WoT  = (unsigned short*)cur; cur += 9472;
    unsigned short* A    = (unsigned short*)cur; cur += (size_t)Bc*345600;
    unsigned short* Bb   = (unsigned short*)cur; cur += (size_t)Bc*172800;
    unsigned short* C    = (unsigned short*)cur;

    setup_k<<<2453, 256, 0, stream>>>(
        w_[1], w_[2], w_[3], lW0, lW1, Wout,
        cb_[0],g_[0],bb_[0],mm_[0],mv_[0],
        cb_[1],g_[1],bb_[1],mm_[1],mv_[1],
        cb_[2],g_[2],bb_[2],mm_[2],mv_[2],
        cb_[3],g_[3],bb_[3],mm_[3],mv_[3],
        Wp1, Wp2, Wp3, Wx0p, Wh0p, Wx1p, Wh1p, WoT, bns);

    const int nc = 256 / Bc;
    for (int bc=0; bc<nc; bc++){
        int bbase = bc*Bc;
        conv0_k<<<(Bc*2700+255)/256, 256, 0, stream>>>(x, w_[0], bns+640, bns+704, A, bbase, Bc*2700);
        convmf_k<64,128,30,90><<<dim3(6,4,Bc), 256, 0, stream>>>(A, Wp1, bns+0, bns+128, Bb);
        convmf_k<128,128,15,45><<<dim3(3,2,Bc), 256, 0, stream>>>(Bb, Wp2, bns+256, bns+384, C);
        convmf_k<128,64,8,23><<<dim3(2,1,Bc), 256, 0, stream>>>(C, Wp3, bns+512, bns+576,
                                                                F + (size_t)bbase*3072);
    }
    gemmrow_k<256,0><<<96, 256, 0, stream>>>(F, Wx0p, lb0, XP);
    lstm0_k<<<256, 512, 0, stream>>>(XP, Wh0p, h0g);
    gemmrow_k<128,1><<<96, 256, 0, stream>>>(h0g, Wx1p, lb1, ZP1);
    lstm1_k<<<256, 512, 0, stream>>>(ZP1, Wh1p, WoT, bout, out);
}

// Round 21
// 335.023 us; speedup vs baseline: 1.8325x; 1.1142x over previous
//
#include <hip/hip_runtime.h>
#include <hip/hip_bf16.h>
#include <math.h>
#include <stdint.h>

#define EPS 1e-5f
#define LEAK 0.01f
#define NEG_INF (-3.402823e38f)

typedef __attribute__((ext_vector_type(8))) short short8v;
typedef __attribute__((ext_vector_type(4))) float f32x4;

__device__ __forceinline__ float sigm(float x){ return 1.0f/(1.0f + __expf(-x)); }
__device__ __forceinline__ float tanhf_(float x){ return 1.0f - 2.0f/(__expf(2.0f*x)+1.0f); }
__device__ __forceinline__ float bnl(float a, float sc, float sh){
    float v = fmaf(a, sc, sh);
    return v < 0.0f ? LEAK*v : v;
}
__device__ __forceinline__ unsigned short f2bf(float f){
    __hip_bfloat16 h = __float2bfloat16(f);
    return *reinterpret_cast<unsigned short*>(&h);
}
__device__ __forceinline__ float bf2f(unsigned short u){
    return __uint_as_float(((unsigned)u) << 16);
}

// ---------- fused setup: all weight packs + BN folds in ONE launch ----------
__global__ __launch_bounds__(256) void setup_k(
    const float* __restrict__ w1, const float* __restrict__ w2, const float* __restrict__ w3,
    const float* __restrict__ lW0, const float* __restrict__ lW1, const float* __restrict__ Wout,
    const float* __restrict__ cb0, const float* __restrict__ g0, const float* __restrict__ bb0,
    const float* __restrict__ mm0, const float* __restrict__ mv0,
    const float* __restrict__ cb1, const float* __restrict__ g1, const float* __restrict__ bb1,
    const float* __restrict__ mm1, const float* __restrict__ mv1,
    const float* __restrict__ cb2, const float* __restrict__ g2, const float* __restrict__ bb2,
    const float* __restrict__ mm2, const float* __restrict__ mv2,
    const float* __restrict__ cb3, const float* __restrict__ g3, const float* __restrict__ bb3,
    const float* __restrict__ mm3, const float* __restrict__ mv3,
    unsigned short* __restrict__ Wp1, unsigned short* __restrict__ Wp2, unsigned short* __restrict__ Wp3,
    unsigned short* __restrict__ Wx0p, unsigned short* __restrict__ Wh0p,
    unsigned short* __restrict__ Wx1p, unsigned short* __restrict__ Wh1p,
    unsigned short* __restrict__ WoT, float* __restrict__ bns)
{
    const int bid = blockIdx.x, tid = threadIdx.x;
    if (bid < 864){
        const float* w; unsigned short* wp; int CIN, COUT, base;
        if (bid < 288){ w = w1; wp = Wp1; CIN=64; COUT=128; base = bid; }
        else { w = w2; wp = Wp2; CIN=128; COUT=128; base = bid-288; }
        int t = base*256 + tid;
        int total = 9*CIN*COUT;
        if (t < total){
            int cout = t % COUT, k = t / COUT;
            wp[(size_t)(k>>3)*COUT*8 + (size_t)cout*8 + (k&7)] = f2bf(w[(size_t)k*COUT + cout]);
        }
        return;
    }
    if (bid < 1152){
        int t = (bid-864)*256 + tid;
        if (t < 73728){
            int cout = t % 64, k = t / 64;
            Wp3[(size_t)(k>>3)*64*8 + (size_t)cout*8 + (k&7)] = f2bf(w3[(size_t)k*64 + cout]);
        }
        return;
    }
    if (bid < 2432){
        const float* src; unsigned short* dst; int base;
        if (bid < 1664){ src = lW0; dst = Wx0p; base = bid-1152; }
        else if (bid < 1920){ src = lW0 + 256*512; dst = Wh0p; base = bid-1664; }
        else if (bid < 2176){ src = lW1; dst = Wx1p; base = bid-1920; }
        else { src = lW1 + 128*512; dst = Wh1p; base = bid-2176; }
        int t = base*256 + tid;
        int k = t >> 9, col = t & 511;
        dst[(size_t)(k>>3)*4096 + col*8 + (k&7)] = f2bf(src[(size_t)k*512 + col]);
        return;
    }
    if (bid < 2451){
        int t = (bid-2432)*256 + tid;
        if (t < 4736){
            int n = t >> 7, k = t & 127;
            WoT[t] = f2bf(Wout[k*37 + n]);
        }
        return;
    }
    {
        int t = (bid-2451)*256 + tid;
        if (t < 128){
            float s = g1[t]*rsqrtf(mv1[t]+EPS);
            bns[t] = s; bns[128+t] = fmaf(cb1[t]-mm1[t], s, bb1[t]);
        } else if (t < 256){
            int u = t-128;
            float s = g2[u]*rsqrtf(mv2[u]+EPS);
            bns[256+u] = s; bns[384+u] = fmaf(cb2[u]-mm2[u], s, bb2[u]);
        } else if (t < 320){
            int u = t-256;
            float s = g3[u]*rsqrtf(mv3[u]+EPS);
            bns[512+u] = s; bns[576+u] = fmaf(cb3[u]-mm3[u], s, bb3[u]);
        } else if (t < 384){
            int u = t-320;
            float s = g0[u]*rsqrtf(mv0[u]+EPS);
            bns[640+u] = s; bns[704+u] = fmaf(cb0[u]-mm0[u], s, bb0[u]);
        }
        return;
    }
}

// ---------- conv block 0: thread = one pooled px, all 64 couts; weights in LDS ----------
__global__ __launch_bounds__(256) void conv0_k(
    const float* __restrict__ x, const float* __restrict__ w,
    const float* __restrict__ bsc, const float* __restrict__ bsh,
    unsigned short* __restrict__ out, int bbase, int total)
{
    __shared__ float wv[576];
    __shared__ float scs[64], shs[64];
    const int tid = threadIdx.x;
    for (int i=tid;i<576;i+=256) wv[i] = w[i];
    if (tid < 64){ scs[tid]=bsc[tid]; shs[tid]=bsh[tid]; }
    __syncthreads();
    const int id = blockIdx.x*256 + tid;
    if (id >= total) return;
    const int px = id % 90; int r = id / 90; const int py = r % 30; const int b0 = r / 30;
    const float* xb = x + (size_t)(bbase+b0)*10800;
    float p[4][4];
    const int y0 = 2*py-1, xx0 = 2*px-1;
#pragma unroll
    for (int rr=0;rr<4;rr++){
        int yy=y0+rr;
#pragma unroll
        for (int cc=0;cc<4;cc++){
            int xc=xx0+cc;
            p[rr][cc] = (yy>=0&&yy<60&&xc>=0&&xc<180)? xb[yy*180+xc] : 0.f;
        }
    }
    unsigned short* ob = out + (size_t)id*64;
#pragma unroll
    for (int cg=0;cg<8;cg++){
        short8v o8;
#pragma unroll
        for (int j=0;j<8;j++){
            const int co = cg*8+j;
            float s00=0.f,s01=0.f,s10=0.f,s11=0.f;
#pragma unroll
            for (int ky=0;ky<3;ky++)
#pragma unroll
            for (int kx=0;kx<3;kx++){
                float wt = wv[(ky*3+kx)*64+co];
                s00 = fmaf(p[ky][kx],     wt, s00);
                s01 = fmaf(p[ky][kx+1],   wt, s01);
                s10 = fmaf(p[ky+1][kx],   wt, s10);
                s11 = fmaf(p[ky+1][kx+1], wt, s11);
            }
            float sc=scs[co], sh=shs[co];
            float m = fmaxf(fmaxf(bnl(s00,sc,sh),bnl(s01,sc,sh)),
                            fmaxf(bnl(s10,sc,sh),bnl(s11,sc,sh)));
            o8[j] = (short)f2bf(m);
        }
        *(short8v*)&ob[cg*8] = o8;
    }
}

// ---------- MFMA fused conv+BN+leaky+pool: A-resident swizzled LDS, templated BK ----------
// Tile: 8 rows x 16 cols. 4 waves = 4 row-pairs, full COUT per wave.
// A-tile [10][18][CIN] bf16 staged ONCE (XOR-swizzled, zero-padded halo);
// W double-buffered via global_load_lds DMA with BK k-step.
// WPB: min waves/SIMD for launch bounds (4 when LDS<=40KB, else 2).
template<int CIN,int COUT,int H,int W,int BK,int WPB>
__global__ __launch_bounds__(256,WPB) void convmf_k(
    const unsigned short* __restrict__ in, const unsigned short* __restrict__ wp,
    const float* __restrict__ bsc, const float* __restrict__ bsh,
    unsigned short* __restrict__ out)
{
    constexpr int PH=(H+1)/2, PW=(W+1)/2;
    constexpr int NIT = 9*CIN/BK;          // K-step iterations
    constexpr int SPT = CIN/BK;            // steps per tap
    constexpr int KS  = BK/32;             // 32-k sub-steps per iteration
    constexpr int NREP = COUT/16;
    constexpr int CH = (BK*COUT)/(256*8);  // 16B DMA chunks per thread per K-tile
    constexpr int AR = 10, AC = 18;
    constexpr int AV = AR*AC*(CIN/8);
    __shared__ alignas(16) unsigned short als[AR*AC*CIN];
    __shared__ alignas(16) unsigned short wls[2][BK*COUT];

    const int tid = threadIdx.x;
    const int lane = tid & 63;
    const int wm = tid >> 6;               // row-pair
    const int l15 = lane & 15, l4 = lane >> 4;
    const int x0 = blockIdx.x*16, y0 = blockIdx.y*8;
    const int b = blockIdx.z;
    const unsigned short* inb = in + (size_t)b*H*W*CIN;

    f32x4 acc[2][NREP];
#pragma unroll
    for (int m=0;m<2;m++)
#pragma unroll
    for (int n=0;n<NREP;n++) acc[m][n] = f32x4{0.f,0.f,0.f,0.f};

    auto stageB = [&](int it, int buf){
        const unsigned short* src = wp + (size_t)it*BK*COUT;
#pragma unroll
        for (int i=0;i<CH;i++){
            const unsigned short* g = src + (size_t)(tid + i*256)*8;
            unsigned short* l = &wls[buf][((tid & ~63) + i*256)*8];
            __builtin_amdgcn_global_load_lds(
                (const __attribute__((address_space(1))) unsigned int*)(uintptr_t)g,
                (__attribute__((address_space(3))) unsigned int*)(uintptr_t)l,
                16, 0, 0);
        }
    };

    // stage W tile 0 (DMA) and the full A-tile (reg-staged, swizzled, zero-padded)
    stageB(0, 0);
    {
        const short8v z8 = short8v{0,0,0,0,0,0,0,0};
        for (int v = tid; v < AV; v += 256){
            const int cin8 = v % (CIN/8);
            const int rc = v / (CIN/8);
            const int col = rc % AC, row = rc / AC;
            const int gy = y0 - 1 + row, gx = x0 - 1 + col;
            short8v val = z8;
            if ((unsigned)gy < (unsigned)H && (unsigned)gx < (unsigned)W)
                val = *(const short8v*)&inb[((size_t)gy*W + gx)*CIN + cin8*8];
            int elem = ((row*AC + col)*CIN + cin8*8) ^ ((col & 7) << 3);
            *(short8v*)&als[elem] = val;
        }
    }
    __syncthreads();

    for (int it=0; it<NIT; ++it){
        if (it+1 < NIT) stageB(it+1, (it+1)&1);
        const int tap = it / SPT;
        const int kpart = it - tap*SPT;
        const int ky = tap/3, kx = tap - ky*3;
        short8v a[2][KS];
#pragma unroll
        for (int rf=0;rf<2;rf++){
            const int lrow = 2*wm + rf + ky;
            const int col_l = l15 + kx;
            const int base = (lrow*AC + col_l)*CIN + kpart*BK + l4*8;
            const int swz = (col_l & 7) << 3;
#pragma unroll
            for (int ks=0;ks<KS;ks++)
                a[rf][ks] = *(const short8v*)&als[(base + ks*32) ^ swz];
        }
        const unsigned short* wb = &wls[it&1][0];
        __builtin_amdgcn_s_setprio(1);
#pragma unroll
        for (int ks=0; ks<KS; ++ks){
#pragma unroll
            for (int nf=0; nf<NREP; ++nf){
                short8v bfr = *(const short8v*)&wb[((ks*4+l4)*COUT + nf*16 + l15)*8];
                acc[0][nf] = __builtin_amdgcn_mfma_f32_16x16x32_bf16(a[0][ks], bfr, acc[0][nf],0,0,0);
                acc[1][nf] = __builtin_amdgcn_mfma_f32_16x16x32_bf16(a[1][ks], bfr, acc[1][nf],0,0,0);
            }
        }
        __builtin_amdgcn_s_setprio(0);
        __syncthreads();
    }

    const int pr = (y0>>1) + wm;
    if (pr < PH){
        const bool r1 = (y0 + 2*wm + 1) < H;
        unsigned short* ob = out + ((size_t)b*PH + pr)*PW*COUT;
#pragma unroll
        for (int nf=0; nf<NREP; ++nf){
            const int co = nf*16 + l15;
            const float scv = bsc[co], shv = bsh[co];
            f32x4 e = acc[0][nf], o = acc[1][nf];
#pragma unroll
            for (int pp=0; pp<2; ++pp){
                const int pc = (x0>>1) + l4*2 + pp;
                if (pc >= PW) continue;
                const int oddcol = x0 + l4*4 + 2*pp + 1;
                float m = bnl(e[2*pp], scv, shv);
                if (oddcol < W) m = fmaxf(m, bnl(e[2*pp+1], scv, shv));
                if (r1){
                    m = fmaxf(m, bnl(o[2*pp], scv, shv));
                    if (oddcol < W) m = fmaxf(m, bnl(o[2*pp+1], scv, shv));
                }
                ob[(size_t)pc*COUT + co] = f2bf(m);
            }
        }
    }
}

// ---------- MFMA row-GEMM: out[3072][512] = A @ W + bias. 32-row tiles, 96 blocks ----------
template<int K, int MODE>
__global__ __launch_bounds__(256) void gemmrow_k(
    const unsigned short* __restrict__ A, const unsigned short* __restrict__ wp,
    const float* __restrict__ bias, float* __restrict__ out)
{
    constexpr int NS = K/32;
    __shared__ alignas(16) unsigned short wls[2][16384];
    const int tid = threadIdx.x, lane = tid & 63, w = tid >> 6;
    const int l15 = lane & 15, l4 = lane >> 4;
    const int r0 = blockIdx.x*32;

    f32x4 acc[2][8];
#pragma unroll
    for (int m=0;m<2;m++)
#pragma unroll
    for (int n=0;n<8;n++) acc[m][n] = f32x4{0.f,0.f,0.f,0.f};

    auto stage = [&](int s, int buf){
        const unsigned short* src = wp + (size_t)s*16384;
#pragma unroll
        for (int i=0;i<8;i++){
            int e = (tid + i*256)*8;
            *(short8v*)&wls[buf][e] = *(const short8v*)&src[e];
        }
    };
    stage(0,0);
    __syncthreads();

    for (int s=0;s<NS;++s){
        const int k0 = s*32 + l4*8;
        short8v af[2];
#pragma unroll
        for (int mf=0;mf<2;++mf){
            const int row = r0 + mf*16 + l15;
            size_t idx;
            if constexpr (MODE == 0){
                const int b = row & 255, t = row >> 8;
                idx = (size_t)b*3072 + (k0>>6)*768 + t*64 + (k0&63);
            } else {
                idx = (size_t)row*K + k0;
            }
            af[mf] = *(const short8v*)&A[idx];
        }
        if (s+1 < NS) stage(s+1,(s+1)&1);
        const unsigned short* wb = &wls[s&1][0];
#pragma unroll
        for (int nf=0;nf<8;++nf){
            const int col = w*128 + nf*16 + l15;
            short8v bfr = *(const short8v*)&wb[(l4*512 + col)*8];
#pragma unroll
            for (int mf=0;mf<2;++mf)
                acc[mf][nf] = __builtin_amdgcn_mfma_f32_16x16x32_bf16(af[mf], bfr, acc[mf][nf], 0,0,0);
        }
        __syncthreads();
    }
#pragma unroll
    for (int nf=0;nf<8;++nf){
        const int col = w*128 + nf*16 + l15;
        const float bv = bias[col];
#pragma unroll
        for (int mf=0;mf<2;++mf){
#pragma unroll
            for (int j=0;j<4;++j){
                const int row = r0 + mf*16 + l4*4 + j;
                out[(size_t)row*512 + col] = acc[mf][nf][j] + bv;
            }
        }
    }
}

// ---------- layer-0 LSTM: Wh0 LDS-resident, 256 blocks x 1 batch ----------
__global__ __launch_bounds__(512) void lstm0_k(
    const float* __restrict__ xp, const unsigned short* __restrict__ wh0p,
    unsigned short* __restrict__ h0g)
{
    __shared__ alignas(16) unsigned short wl[65536];   // 128 KB
    __shared__ alignas(16) float hb[128];
    __shared__ float zs[512];
    const int col = threadIdx.x;
    const int b = blockIdx.x;
#pragma unroll
    for (int i=0;i<16;i++){
        int e = (col + i*512)*8;
        *(short8v*)&wl[e] = *(const short8v*)&wh0p[e];
    }
    if (col < 128) hb[col] = 0.f;
    float c0 = 0.f;
    __syncthreads();

    for (int t=0;t<12;t++){
        float acc = xp[((size_t)t*256 + b)*512 + col];
#pragma unroll 4
        for (int kg=0;kg<16;kg++){
            short8v w8 = *(const short8v*)&wl[(kg*512 + col)*8];
            float4 hlo = *(const float4*)&hb[kg*8];
            float4 hhi = *(const float4*)&hb[kg*8+4];
            acc = fmaf(bf2f((unsigned short)w8[0]), hlo.x, acc);
            acc = fmaf(bf2f((unsigned short)w8[1]), hlo.y, acc);
            acc = fmaf(bf2f((unsigned short)w8[2]), hlo.z, acc);
            acc = fmaf(bf2f((unsigned short)w8[3]), hlo.w, acc);
            acc = fmaf(bf2f((unsigned short)w8[4]), hhi.x, acc);
            acc = fmaf(bf2f((unsigned short)w8[5]), hhi.y, acc);
            acc = fmaf(bf2f((unsigned short)w8[6]), hhi.z, acc);
            acc = fmaf(bf2f((unsigned short)w8[7]), hhi.w, acc);
        }
        zs[col] = acc;
        __syncthreads();
        if (col < 128){
            float zi=zs[col], zj=zs[128+col], zf=zs[256+col], zo=zs[384+col];
            c0 = c0*sigm(zf+1.f) + sigm(zi)*tanhf_(zj);
            float h = tanhf_(c0)*sigm(zo);
            hb[col] = h;
            h0g[((size_t)t*256 + b)*128 + col] = f2bf(h);
        }
        __syncthreads();
    }
}

// ---------- layer-1 LSTM + projection: Wh1 LDS-resident, 256 blocks x 1 batch ----------
__global__ __launch_bounds__(512) void lstm1_k(
    const float* __restrict__ zp1, const unsigned short* __restrict__ wh1p,
    const unsigned short* __restrict__ woT, const float* __restrict__ bout,
    float* __restrict__ out)
{
    __shared__ alignas(16) unsigned short wl[65536];   // 128 KB
    __shared__ alignas(16) float hb[128];
    __shared__ float zs[512];
    __shared__ float red[37][8];
    const int col = threadIdx.x;
    const int b = blockIdx.x;
#pragma unroll
    for (int i=0;i<16;i++){
        int e = (col + i*512)*8;
        *(short8v*)&wl[e] = *(const short8v*)&wh1p[e];
    }
    if (col < 128) hb[col] = 0.f;
    float c1 = 0.f;
    __syncthreads();

    for (int t=0;t<12;t++){
        float acc = zp1[((size_t)t*256 + b)*512 + col];
#pragma unroll 4
        for (int kg=0;kg<16;kg++){
            short8v w8 = *(const short8v*)&wl[(kg*512 + col)*8];
            float4 hlo = *(const float4*)&hb[kg*8];
            float4 hhi = *(const float4*)&hb[kg*8+4];
            acc = fmaf(bf2f((unsigned short)w8[0]), hlo.x, acc);
            acc = fmaf(bf2f((unsigned short)w8[1]), hlo.y, acc);
            acc = fmaf(bf2f((unsigned short)w8[2]), hlo.z, acc);
            acc = fmaf(bf2f((unsigned short)w8[3]), hlo.w, acc);
            acc = fmaf(bf2f((unsigned short)w8[4]), hhi.x, acc);
            acc = fmaf(bf2f((unsigned short)w8[5]), hhi.y, acc);
            acc = fmaf(bf2f((unsigned short)w8[6]), hhi.z, acc);
            acc = fmaf(bf2f((unsigned short)w8[7]), hhi.w, acc);
        }
        zs[col] = acc;
        __syncthreads();
        if (col < 128){
            float zi=zs[col], zj=zs[128+col], zf=zs[256+col], zo=zs[384+col];
            c1 = c1*sigm(zf+1.f) + sigm(zi)*tanhf_(zj);
            hb[col] = tanhf_(c1)*sigm(zo);
        }
        __syncthreads();
        if (col < 296){
            const int n = col >> 3, q = col & 7;
            float p0 = 0.f;
#pragma unroll
            for (int kk=0;kk<16;kk++){
                float wv2 = bf2f(woT[n*128 + q*16 + kk]);
                p0 = fmaf(hb[q*16+kk], wv2, p0);
            }
            red[n][q] = p0;
        }
        __syncthreads();
        if (col < 37){
            float s0 = bout[col];
#pragma unroll
            for (int q=0;q<8;q++) s0 += red[col][q];
            out[((size_t)t*256 + b)*37 + col] = s0;
        }
        __syncthreads();
    }
}

extern "C" void kernel_launch(void* const* d_in, const int* in_sizes, int n_in,
                              void* d_out, int out_size, void* d_ws, size_t ws_size,
                              hipStream_t stream) {
    const float* x = (const float*)d_in[0];
    const float *w_[4], *cb_[4], *g_[4], *bb_[4], *mm_[4], *mv_[4];
    for (int i=0;i<4;i++){
        w_[i]  = (const float*)d_in[1+6*i];
        cb_[i] = (const float*)d_in[2+6*i];
        g_[i]  = (const float*)d_in[3+6*i];
        bb_[i] = (const float*)d_in[4+6*i];
        mm_[i] = (const float*)d_in[5+6*i];
        mv_[i] = (const float*)d_in[6+6*i];
    }
    const float* lW0  = (const float*)d_in[25];
    const float* lb0  = (const float*)d_in[26];
    const float* lW1  = (const float*)d_in[27];
    const float* lb1  = (const float*)d_in[28];
    const float* Wout = (const float*)d_in[29];
    const float* bout = (const float*)d_in[30];
    float* out = (float*)d_out;

    const size_t fixed = 6291456ull + 6291456 + 4096 + 1572864 + 786432
                       + 147456 + 294912 + 147456
                       + 262144 + 131072 + 131072 + 131072 + 9472;
    int Bc = 256;
    while (Bc > 8 && fixed + (size_t)Bc*565504 > ws_size) Bc >>= 1;

    char* cur = (char*)d_ws;
    float* XP  = (float*)cur;                    cur += 6291456;
    float* ZP1 = (float*)cur;                    cur += 6291456;
    float* bns = (float*)cur;                    cur += 4096;
    unsigned short* F    = (unsigned short*)cur; cur += 1572864;
    unsigned short* h0g  = (unsigned short*)cur; cur += 786432;
    unsigned short* Wp1  = (unsigned short*)cur; cur += 147456;
    unsigned short* Wp2  = (unsigned short*)cur; cur += 294912;
    unsigned short* Wp3  = (unsigned short*)cur; cur += 147456;
    unsigned short* Wx0p = (unsigned short*)cur; cur += 262144;
    unsigned short* Wh0p = (unsigned short*)cur; cur += 131072;
    unsigned short* Wx1p = (unsigned short*)cur; cur += 131072;
    unsigned short* Wh1p = (unsigned short*)cur; cur += 131072;
    unsigned short* WoT  = (unsigned short*)cur; cur += 9472;
    unsigned short* A    = (unsigned short*)cur; cur += (size_t)Bc*345600;
    unsigned short* Bb   = (unsigned short*)cur; cur += (size_t)Bc*172800;
    unsigned short* C    = (unsigned short*)cur;

    setup_k<<<2453, 256, 0, stream>>>(
        w_[1], w_[2], w_[3], lW0, lW1, Wout,
        cb_[0],g_[0],bb_[0],mm_[0],mv_[0],
        cb_[1],g_[1],bb_[1],mm_[1],mv_[1],
        cb_[2],g_[2],bb_[2],mm_[2],mv_[2],
        cb_[3],g_[3],bb_[3],mm_[3],mv_[3],
        Wp1, Wp2, Wp3, Wx0p, Wh0p, Wx1p, Wh1p, WoT, bns);

    const int nc = 256 / Bc;
    for (int bc=0; bc<nc; bc++){
        int bbase = bc*Bc;
        conv0_k<<<(Bc*2700+255)/256, 256, 0, stream>>>(x, w_[0], bns+640, bns+704, A, bbase, Bc*2700);
        // conv1: BK=32 -> LDS 39.4KB -> 4 blocks/CU
        convmf_k<64,128,30,90,32,4><<<dim3(6,4,Bc), 256, 0, stream>>>(A, Wp1, bns+0, bns+128, Bb);
        // conv2/3: BK=64, A-tile 46KB -> 2 blocks/CU
        convmf_k<128,128,15,45,64,2><<<dim3(3,2,Bc), 256, 0, stream>>>(Bb, Wp2, bns+256, bns+384, C);
        convmf_k<128,64,8,23,64,2><<<dim3(2,1,Bc), 256, 0, stream>>>(C, Wp3, bns+512, bns+576,
                                                                     F + (size_t)bbase*3072);
    }
    gemmrow_k<256,0><<<96, 256, 0, stream>>>(F, Wx0p, lb0, XP);
    lstm0_k<<<256, 512, 0, stream>>>(XP, Wh0p, h0g);
    gemmrow_k<128,1><<<96, 256, 0, stream>>>(h0g, Wx1p, lb1, ZP1);
    lstm1_k<<<256, 512, 0, stream>>>(ZP1, Wh1p, WoT, bout, out);
}

// Round 22
// 330.897 us; speedup vs baseline: 1.8554x; 1.0125x over previous
//
#include <hip/hip_runtime.h>
#include <hip/hip_bf16.h>
#include <math.h>
#include <stdint.h>

#define EPS 1e-5f
#define LEAK 0.01f
#define NEG_INF (-3.402823e38f)

typedef __attribute__((ext_vector_type(8))) short short8v;
typedef __attribute__((ext_vector_type(4))) float f32x4;

__device__ __forceinline__ float sigm(float x){ return 1.0f/(1.0f + __expf(-x)); }
__device__ __forceinline__ float tanhf_(float x){ return 1.0f - 2.0f/(__expf(2.0f*x)+1.0f); }
__device__ __forceinline__ float bnl(float a, float sc, float sh){
    float v = fmaf(a, sc, sh);
    return v < 0.0f ? LEAK*v : v;
}
__device__ __forceinline__ unsigned short f2bf(float f){
    __hip_bfloat16 h = __float2bfloat16(f);
    return *reinterpret_cast<unsigned short*>(&h);
}
__device__ __forceinline__ float bf2f(unsigned short u){
    return __uint_as_float(((unsigned)u) << 16);
}

// ---------- fused setup: all weight packs + BN folds in ONE launch ----------
__global__ __launch_bounds__(256) void setup_k(
    const float* __restrict__ w1, const float* __restrict__ w2, const float* __restrict__ w3,
    const float* __restrict__ lW0, const float* __restrict__ lW1, const float* __restrict__ Wout,
    const float* __restrict__ cb0, const float* __restrict__ g0, const float* __restrict__ bb0,
    const float* __restrict__ mm0, const float* __restrict__ mv0,
    const float* __restrict__ cb1, const float* __restrict__ g1, const float* __restrict__ bb1,
    const float* __restrict__ mm1, const float* __restrict__ mv1,
    const float* __restrict__ cb2, const float* __restrict__ g2, const float* __restrict__ bb2,
    const float* __restrict__ mm2, const float* __restrict__ mv2,
    const float* __restrict__ cb3, const float* __restrict__ g3, const float* __restrict__ bb3,
    const float* __restrict__ mm3, const float* __restrict__ mv3,
    unsigned short* __restrict__ Wp1, unsigned short* __restrict__ Wp2, unsigned short* __restrict__ Wp3,
    unsigned short* __restrict__ Wx0p, unsigned short* __restrict__ Wh0p,
    unsigned short* __restrict__ Wx1p, unsigned short* __restrict__ Wh1p,
    unsigned short* __restrict__ WoT, float* __restrict__ bns)
{
    const int bid = blockIdx.x, tid = threadIdx.x;
    if (bid < 864){
        const float* w; unsigned short* wp; int CIN, COUT, base;
        if (bid < 288){ w = w1; wp = Wp1; CIN=64; COUT=128; base = bid; }
        else { w = w2; wp = Wp2; CIN=128; COUT=128; base = bid-288; }
        int t = base*256 + tid;
        int total = 9*CIN*COUT;
        if (t < total){
            int cout = t % COUT, k = t / COUT;
            wp[(size_t)(k>>3)*COUT*8 + (size_t)cout*8 + (k&7)] = f2bf(w[(size_t)k*COUT + cout]);
        }
        return;
    }
    if (bid < 1152){
        int t = (bid-864)*256 + tid;
        if (t < 73728){
            int cout = t % 64, k = t / 64;
            Wp3[(size_t)(k>>3)*64*8 + (size_t)cout*8 + (k&7)] = f2bf(w3[(size_t)k*64 + cout]);
        }
        return;
    }
    if (bid < 2432){
        const float* src; unsigned short* dst; int base;
        if (bid < 1664){ src = lW0; dst = Wx0p; base = bid-1152; }
        else if (bid < 1920){ src = lW0 + 256*512; dst = Wh0p; base = bid-1664; }
        else if (bid < 2176){ src = lW1; dst = Wx1p; base = bid-1920; }
        else { src = lW1 + 128*512; dst = Wh1p; base = bid-2176; }
        int t = base*256 + tid;
        int k = t >> 9, col = t & 511;
        dst[(size_t)(k>>3)*4096 + col*8 + (k&7)] = f2bf(src[(size_t)k*512 + col]);
        return;
    }
    if (bid < 2451){
        int t = (bid-2432)*256 + tid;
        if (t < 4736){
            int n = t >> 7, k = t & 127;
            WoT[t] = f2bf(Wout[k*37 + n]);
        }
        return;
    }
    {
        int t = (bid-2451)*256 + tid;
        if (t < 128){
            float s = g1[t]*rsqrtf(mv1[t]+EPS);
            bns[t] = s; bns[128+t] = fmaf(cb1[t]-mm1[t], s, bb1[t]);
        } else if (t < 256){
            int u = t-128;
            float s = g2[u]*rsqrtf(mv2[u]+EPS);
            bns[256+u] = s; bns[384+u] = fmaf(cb2[u]-mm2[u], s, bb2[u]);
        } else if (t < 320){
            int u = t-256;
            float s = g3[u]*rsqrtf(mv3[u]+EPS);
            bns[512+u] = s; bns[576+u] = fmaf(cb3[u]-mm3[u], s, bb3[u]);
        } else if (t < 384){
            int u = t-320;
            float s = g0[u]*rsqrtf(mv0[u]+EPS);
            bns[640+u] = s; bns[704+u] = fmaf(cb0[u]-mm0[u], s, bb0[u]);
        }
        return;
    }
}

// ---------- conv block 0: thread = one pooled px, all 64 couts; weights in LDS ----------
__global__ __launch_bounds__(256) void conv0_k(
    const float* __restrict__ x, const float* __restrict__ w,
    const float* __restrict__ bsc, const float* __restrict__ bsh,
    unsigned short* __restrict__ out, int bbase, int total)
{
    __shared__ float wv[576];
    __shared__ float scs[64], shs[64];
    const int tid = threadIdx.x;
    for (int i=tid;i<576;i+=256) wv[i] = w[i];
    if (tid < 64){ scs[tid]=bsc[tid]; shs[tid]=bsh[tid]; }
    __syncthreads();
    const int id = blockIdx.x*256 + tid;
    if (id >= total) return;
    const int px = id % 90; int r = id / 90; const int py = r % 30; const int b0 = r / 30;
    const float* xb = x + (size_t)(bbase+b0)*10800;
    float p[4][4];
    const int y0 = 2*py-1, xx0 = 2*px-1;
#pragma unroll
    for (int rr=0;rr<4;rr++){
        int yy=y0+rr;
#pragma unroll
        for (int cc=0;cc<4;cc++){
            int xc=xx0+cc;
            p[rr][cc] = (yy>=0&&yy<60&&xc>=0&&xc<180)? xb[yy*180+xc] : 0.f;
        }
    }
    unsigned short* ob = out + (size_t)id*64;
#pragma unroll
    for (int cg=0;cg<8;cg++){
        short8v o8;
#pragma unroll
        for (int j=0;j<8;j++){
            const int co = cg*8+j;
            float s00=0.f,s01=0.f,s10=0.f,s11=0.f;
#pragma unroll
            for (int ky=0;ky<3;ky++)
#pragma unroll
            for (int kx=0;kx<3;kx++){
                float wt = wv[(ky*3+kx)*64+co];
                s00 = fmaf(p[ky][kx],     wt, s00);
                s01 = fmaf(p[ky][kx+1],   wt, s01);
                s10 = fmaf(p[ky+1][kx],   wt, s10);
                s11 = fmaf(p[ky+1][kx+1], wt, s11);
            }
            float sc=scs[co], sh=shs[co];
            float m = fmaxf(fmaxf(bnl(s00,sc,sh),bnl(s01,sc,sh)),
                            fmaxf(bnl(s10,sc,sh),bnl(s11,sc,sh)));
            o8[j] = (short)f2bf(m);
        }
        *(short8v*)&ob[cg*8] = o8;
    }
}

// ---------- MFMA fused conv+BN+leaky+pool: A-resident swizzled LDS, cout-split waves ----------
// Tile: 8 rows x 16 cols. 4 waves = 2 row-groups(4 rows) x 2 cout-halves.
// A-tile [10][18][CIN] bf16 staged ONCE (XOR-swizzled, zero-padded halo);
// W double-buffered via global_load_lds DMA with BK k-step.
template<int CIN,int COUT,int H,int W,int BK,int WPB>
__global__ __launch_bounds__(256,WPB) void convmf_k(
    const unsigned short* __restrict__ in, const unsigned short* __restrict__ wp,
    const float* __restrict__ bsc, const float* __restrict__ bsh,
    unsigned short* __restrict__ out)
{
    constexpr int PH=(H+1)/2, PW=(W+1)/2;
    constexpr int NIT = 9*CIN/BK;          // K-step iterations
    constexpr int SPT = CIN/BK;            // steps per tap
    constexpr int KS  = BK/32;             // 32-k sub-steps per iteration
    constexpr int COUTW = COUT/2;
    constexpr int NREP = COUTW/16;
    constexpr int CH = (BK*COUT)/(256*8);  // 16B DMA chunks per thread per K-tile
    constexpr int AR = 10, AC = 18;
    constexpr int AV = AR*AC*(CIN/8);
    __shared__ alignas(16) unsigned short als[AR*AC*CIN];
    __shared__ alignas(16) unsigned short wls[2][BK*COUT];

    const int tid = threadIdx.x;
    const int lane = tid & 63;
    const int wv = tid >> 6;
    const int wn  = wv & 1;                // cout-half
    const int wmr = wv >> 1;               // row-group (4 rows)
    const int l15 = lane & 15, l4 = lane >> 4;
    const int x0 = blockIdx.x*16, y0 = blockIdx.y*8;
    const int b = blockIdx.z;
    const unsigned short* inb = in + (size_t)b*H*W*CIN;

    f32x4 acc[4][NREP];
#pragma unroll
    for (int m=0;m<4;m++)
#pragma unroll
    for (int n=0;n<NREP;n++) acc[m][n] = f32x4{0.f,0.f,0.f,0.f};

    auto stageB = [&](int it, int buf){
        const unsigned short* src = wp + (size_t)it*BK*COUT;
#pragma unroll
        for (int i=0;i<CH;i++){
            const unsigned short* g = src + (size_t)(tid + i*256)*8;
            unsigned short* l = &wls[buf][((tid & ~63) + i*256)*8];
            __builtin_amdgcn_global_load_lds(
                (const __attribute__((address_space(1))) unsigned int*)(uintptr_t)g,
                (__attribute__((address_space(3))) unsigned int*)(uintptr_t)l,
                16, 0, 0);
        }
    };

    // stage W tile 0 (DMA) and the full A-tile (reg-staged, swizzled, zero-padded)
    stageB(0, 0);
    {
        const short8v z8 = short8v{0,0,0,0,0,0,0,0};
        for (int v = tid; v < AV; v += 256){
            const int cin8 = v % (CIN/8);
            const int rc = v / (CIN/8);
            const int col = rc % AC, row = rc / AC;
            const int gy = y0 - 1 + row, gx = x0 - 1 + col;
            short8v val = z8;
            if ((unsigned)gy < (unsigned)H && (unsigned)gx < (unsigned)W)
                val = *(const short8v*)&inb[((size_t)gy*W + gx)*CIN + cin8*8];
            int elem = ((row*AC + col)*CIN + cin8*8) ^ ((col & 7) << 3);
            *(short8v*)&als[elem] = val;
        }
    }
    __syncthreads();

    for (int it=0; it<NIT; ++it){
        if (it+1 < NIT) stageB(it+1, (it+1)&1);
        const int tap = it / SPT;
        const int kpart = it - tap*SPT;
        const int ky = tap/3, kx = tap - ky*3;
        short8v a[4][KS];
#pragma unroll
        for (int rf=0;rf<4;rf++){
            const int lrow = 4*wmr + rf + ky;
            const int col_l = l15 + kx;
            const int base = (lrow*AC + col_l)*CIN + kpart*BK + l4*8;
            const int swz = (col_l & 7) << 3;
#pragma unroll
            for (int ks=0;ks<KS;ks++)
                a[rf][ks] = *(const short8v*)&als[(base + ks*32) ^ swz];
        }
        const unsigned short* wb = &wls[it&1][0];
        __builtin_amdgcn_s_setprio(1);
#pragma unroll
        for (int ks=0; ks<KS; ++ks){
#pragma unroll
            for (int nf=0; nf<NREP; ++nf){
                short8v bfr = *(const short8v*)&wb[((ks*4+l4)*COUT + wn*COUTW + nf*16 + l15)*8];
#pragma unroll
                for (int rf=0; rf<4; ++rf)
                    acc[rf][nf] = __builtin_amdgcn_mfma_f32_16x16x32_bf16(a[rf][ks], bfr, acc[rf][nf],0,0,0);
            }
        }
        __builtin_amdgcn_s_setprio(0);
        __syncthreads();
    }

    // epilogue: BN + leaky + 2x2 SAME maxpool + bf16 store
#pragma unroll
    for (int prl=0; prl<2; ++prl){
        const int pr = (y0>>1) + 2*wmr + prl;
        if (pr >= PH) continue;
        const bool r1 = (y0 + 4*wmr + 2*prl + 1) < H;
        unsigned short* ob = out + ((size_t)b*PH + pr)*PW*COUT;
#pragma unroll
        for (int nf=0; nf<NREP; ++nf){
            const int co = wn*COUTW + nf*16 + l15;
            const float scv = bsc[co], shv = bsh[co];
            f32x4 e = acc[2*prl][nf], o = acc[2*prl+1][nf];
#pragma unroll
            for (int pp=0; pp<2; ++pp){
                const int pc = (x0>>1) + l4*2 + pp;
                if (pc >= PW) continue;
                const int oddcol = x0 + l4*4 + 2*pp + 1;
                float m = bnl(e[2*pp], scv, shv);
                if (oddcol < W) m = fmaxf(m, bnl(e[2*pp+1], scv, shv));
                if (r1){
                    m = fmaxf(m, bnl(o[2*pp], scv, shv));
                    if (oddcol < W) m = fmaxf(m, bnl(o[2*pp+1], scv, shv));
                }
                ob[(size_t)pc*COUT + co] = f2bf(m);
            }
        }
    }
}

// ---------- MFMA row-GEMM: out[3072][512] = A @ W + bias. 32-row tiles, 96 blocks ----------
template<int K, int MODE>
__global__ __launch_bounds__(256) void gemmrow_k(
    const unsigned short* __restrict__ A, const unsigned short* __restrict__ wp,
    const float* __restrict__ bias, float* __restrict__ out)
{
    constexpr int NS = K/32;
    __shared__ alignas(16) unsigned short wls[2][16384];
    const int tid = threadIdx.x, lane = tid & 63, w = tid >> 6;
    const int l15 = lane & 15, l4 = lane >> 4;
    const int r0 = blockIdx.x*32;

    f32x4 acc[2][8];
#pragma unroll
    for (int m=0;m<2;m++)
#pragma unroll
    for (int n=0;n<8;n++) acc[m][n] = f32x4{0.f,0.f,0.f,0.f};

    auto stage = [&](int s, int buf){
        const unsigned short* src = wp + (size_t)s*16384;
#pragma unroll
        for (int i=0;i<8;i++){
            int e = (tid + i*256)*8;
            *(short8v*)&wls[buf][e] = *(const short8v*)&src[e];
        }
    };
    stage(0,0);
    __syncthreads();

    for (int s=0;s<NS;++s){
        const int k0 = s*32 + l4*8;
        short8v af[2];
#pragma unroll
        for (int mf=0;mf<2;++mf){
            const int row = r0 + mf*16 + l15;
            size_t idx;
            if constexpr (MODE == 0){
                const int b = row & 255, t = row >> 8;
                idx = (size_t)b*3072 + (k0>>6)*768 + t*64 + (k0&63);
            } else {
                idx = (size_t)row*K + k0;
            }
            af[mf] = *(const short8v*)&A[idx];
        }
        if (s+1 < NS) stage(s+1,(s+1)&1);
        const unsigned short* wb = &wls[s&1][0];
#pragma unroll
        for (int nf=0;nf<8;++nf){
            const int col = w*128 + nf*16 + l15;
            short8v bfr = *(const short8v*)&wb[(l4*512 + col)*8];
#pragma unroll
            for (int mf=0;mf<2;++mf)
                acc[mf][nf] = __builtin_amdgcn_mfma_f32_16x16x32_bf16(af[mf], bfr, acc[mf][nf], 0,0,0);
        }
        __syncthreads();
    }
#pragma unroll
    for (int nf=0;nf<8;++nf){
        const int col = w*128 + nf*16 + l15;
        const float bv = bias[col];
#pragma unroll
        for (int mf=0;mf<2;++mf){
#pragma unroll
            for (int j=0;j<4;++j){
                const int row = r0 + mf*16 + l4*4 + j;
                out[(size_t)row*512 + col] = acc[mf][nf][j] + bv;
            }
        }
    }
}

// ---------- layer-0 LSTM: Wh0 LDS-resident, 256 blocks x 1 batch ----------
__global__ __launch_bounds__(512) void lstm0_k(
    const float* __restrict__ xp, const unsigned short* __restrict__ wh0p,
    unsigned short* __restrict__ h0g)
{
    __shared__ alignas(16) unsigned short wl[65536];   // 128 KB
    __shared__ alignas(16) float hb[128];
    __shared__ float zs[512];
    const int col = threadIdx.x;
    const int b = blockIdx.x;
#pragma unroll
    for (int i=0;i<16;i++){
        int e = (col + i*512)*8;
        *(short8v*)&wl[e] = *(const short8v*)&wh0p[e];
    }
    if (col < 128) hb[col] = 0.f;
    float c0 = 0.f;
    __syncthreads();

    for (int t=0;t<12;t++){
        float acc = xp[((size_t)t*256 + b)*512 + col];
#pragma unroll 4
        for (int kg=0;kg<16;kg++){
            short8v w8 = *(const short8v*)&wl[(kg*512 + col)*8];
            float4 hlo = *(const float4*)&hb[kg*8];
            float4 hhi = *(const float4*)&hb[kg*8+4];
            acc = fmaf(bf2f((unsigned short)w8[0]), hlo.x, acc);
            acc = fmaf(bf2f((unsigned short)w8[1]), hlo.y, acc);
            acc = fmaf(bf2f((unsigned short)w8[2]), hlo.z, acc);
            acc = fmaf(bf2f((unsigned short)w8[3]), hlo.w, acc);
            acc = fmaf(bf2f((unsigned short)w8[4]), hhi.x, acc);
            acc = fmaf(bf2f((unsigned short)w8[5]), hhi.y, acc);
            acc = fmaf(bf2f((unsigned short)w8[6]), hhi.z, acc);
            acc = fmaf(bf2f((unsigned short)w8[7]), hhi.w, acc);
        }
        zs[col] = acc;
        __syncthreads();
        if (col < 128){
            float zi=zs[col], zj=zs[128+col], zf=zs[256+col], zo=zs[384+col];
            c0 = c0*sigm(zf+1.f) + sigm(zi)*tanhf_(zj);
            float h = tanhf_(c0)*sigm(zo);
            hb[col] = h;
            h0g[((size_t)t*256 + b)*128 + col] = f2bf(h);
        }
        __syncthreads();
    }
}

// ---------- layer-1 LSTM + projection: Wh1 LDS-resident, 256 blocks x 1 batch ----------
__global__ __launch_bounds__(512) void lstm1_k(
    const float* __restrict__ zp1, const unsigned short* __restrict__ wh1p,
    const unsigned short* __restrict__ woT, const float* __restrict__ bout,
    float* __restrict__ out)
{
    __shared__ alignas(16) unsigned short wl[65536];   // 128 KB
    __shared__ alignas(16) float hb[128];
    __shared__ float zs[512];
    __shared__ float red[37][8];
    const int col = threadIdx.x;
    const int b = blockIdx.x;
#pragma unroll
    for (int i=0;i<16;i++){
        int e = (col + i*512)*8;
        *(short8v*)&wl[e] = *(const short8v*)&wh1p[e];
    }
    if (col < 128) hb[col] = 0.f;
    float c1 = 0.f;
    __syncthreads();

    for (int t=0;t<12;t++){
        float acc = zp1[((size_t)t*256 + b)*512 + col];
#pragma unroll 4
        for (int kg=0;kg<16;kg++){
            short8v w8 = *(const short8v*)&wl[(kg*512 + col)*8];
            float4 hlo = *(const float4*)&hb[kg*8];
            float4 hhi = *(const float4*)&hb[kg*8+4];
            acc = fmaf(bf2f((unsigned short)w8[0]), hlo.x, acc);
            acc = fmaf(bf2f((unsigned short)w8[1]), hlo.y, acc);
            acc = fmaf(bf2f((unsigned short)w8[2]), hlo.z, acc);
            acc = fmaf(bf2f((unsigned short)w8[3]), hlo.w, acc);
            acc = fmaf(bf2f((unsigned short)w8[4]), hhi.x, acc);
            acc = fmaf(bf2f((unsigned short)w8[5]), hhi.y, acc);
            acc = fmaf(bf2f((unsigned short)w8[6]), hhi.z, acc);
            acc = fmaf(bf2f((unsigned short)w8[7]), hhi.w, acc);
        }
        zs[col] = acc;
        __syncthreads();
        if (col < 128){
            float zi=zs[col], zj=zs[128+col], zf=zs[256+col], zo=zs[384+col];
            c1 = c1*sigm(zf+1.f) + sigm(zi)*tanhf_(zj);
            hb[col] = tanhf_(c1)*sigm(zo);
        }
        __syncthreads();
        if (col < 296){
            const int n = col >> 3, q = col & 7;
            float p0 = 0.f;
#pragma unroll
            for (int kk=0;kk<16;kk++){
                float wv2 = bf2f(woT[n*128 + q*16 + kk]);
                p0 = fmaf(hb[q*16+kk], wv2, p0);
            }
            red[n][q] = p0;
        }
        __syncthreads();
        if (col < 37){
            float s0 = bout[col];
#pragma unroll
            for (int q=0;q<8;q++) s0 += red[col][q];
            out[((size_t)t*256 + b)*37 + col] = s0;
        }
        __syncthreads();
    }
}

extern "C" void kernel_launch(void* const* d_in, const int* in_sizes, int n_in,
                              void* d_out, int out_size, void* d_ws, size_t ws_size,
                              hipStream_t stream) {
    const float* x = (const float*)d_in[0];
    const float *w_[4], *cb_[4], *g_[4], *bb_[4], *mm_[4], *mv_[4];
    for (int i=0;i<4;i++){
        w_[i]  = (const float*)d_in[1+6*i];
        cb_[i] = (const float*)d_in[2+6*i];
        g_[i]  = (const float*)d_in[3+6*i];
        bb_[i] = (const float*)d_in[4+6*i];
        mm_[i] = (const float*)d_in[5+6*i];
        mv_[i] = (const float*)d_in[6+6*i];
    }
    const float* lW0  = (const float*)d_in[25];
    const float* lb0  = (const float*)d_in[26];
    const float* lW1  = (const float*)d_in[27];
    const float* lb1  = (const float*)d_in[28];
    const float* Wout = (const float*)d_in[29];
    const float* bout = (const float*)d_in[30];
    float* out = (float*)d_out;

    const size_t fixed = 6291456ull + 6291456 + 4096 + 1572864 + 786432
                       + 147456 + 294912 + 147456
                       + 262144 + 131072 + 131072 + 131072 + 9472;
    int Bc = 256;
    while (Bc > 8 && fixed + (size_t)Bc*565504 > ws_size) Bc >>= 1;

    char* cur = (char*)d_ws;
    float* XP  = (float*)cur;                    cur += 6291456;
    float* ZP1 = (float*)cur;                    cur += 6291456;
    float* bns = (float*)cur;                    cur += 4096;
    unsigned short* F    = (unsigned short*)cur; cur += 1572864;
    unsigned short* h0g  = (unsigned short*)cur; cur += 786432;
    unsigned short* Wp1  = (unsigned short*)cur; cur += 147456;
    unsigned short* Wp2  = (unsigned short*)cur; cur += 294912;
    unsigned short* Wp3  = (unsigned short*)cur; cur += 147456;
    unsigned short* Wx0p = (unsigned short*)cur; cur += 262144;
    unsigned short* Wh0p = (unsigned short*)cur; cur += 131072;
    unsigned short* Wx1p = (unsigned short*)cur; cur += 131072;
    unsigned short* Wh1p = (unsigned short*)cur; cur += 131072;
    unsigned short* WoT  = (unsigned short*)cur; cur += 9472;
    unsigned short* A    = (unsigned short*)cur; cur += (size_t)Bc*345600;
    unsigned short* Bb   = (unsigned short*)cur; cur += (size_t)Bc*172800;
    unsigned short* C    = (unsigned short*)cur;

    setup_k<<<2453, 256, 0, stream>>>(
        w_[1], w_[2], w_[3], lW0, lW1, Wout,
        cb_[0],g_[0],bb_[0],mm_[0],mv_[0],
        cb_[1],g_[1],bb_[1],mm_[1],mv_[1],
        cb_[2],g_[2],bb_[2],mm_[2],mv_[2],
        cb_[3],g_[3],bb_[3],mm_[3],mv_[3],
        Wp1, Wp2, Wp3, Wx0p, Wh0p, Wx1p, Wh1p, WoT, bns);

    const int nc = 256 / Bc;
    for (int bc=0; bc<nc; bc++){
        int bbase = bc*Bc;
        conv0_k<<<(Bc*2700+255)/256, 256, 0, stream>>>(x, w_[0], bns+640, bns+704, A, bbase, Bc*2700);
        convmf_k<64,128,30,90,32,4><<<dim3(6,4,Bc), 256, 0, stream>>>(A, Wp1, bns+0, bns+128, Bb);
        convmf_k<128,128,15,45,64,2><<<dim3(3,2,Bc), 256, 0, stream>>>(Bb, Wp2, bns+256, bns+384, C);
        convmf_k<128,64,8,23,64,2><<<dim3(2,1,Bc), 256, 0, stream>>>(C, Wp3, bns+512, bns+576,
                                                                     F + (size_t)bbase*3072);
    }
    gemmrow_k<256,0><<<96, 256, 0, stream>>>(F, Wx0p, lb0, XP);
    lstm0_k<<<256, 512, 0, stream>>>(XP, Wh0p, h0g);
    gemmrow_k<128,1><<<96, 256, 0, stream>>>(h0g, Wx1p, lb1, ZP1);
    lstm1_k<<<256, 512, 0, stream>>>(ZP1, Wh1p, WoT, bout, out);
}